// Round 1
// baseline (1293.524 us; speedup 1.0000x reference)
//
#include <hip/hip_runtime.h>
#include <math.h>

#define B_ 16
#define T_ 2048
#define D_ 512
#define DB_ 128
#define K_ 7
#define TOPK_ 16
#define WIN_ 64

static constexpr float SCALE_ = 0.08838834764831845f;   // 128^-0.5
static constexpr float PHI_ = 1.618033988749895f;
static constexpr float PSI_ = -0.6180339887498949f;
static constexpr float INV_DENOM_ = 0.4472135954999579f; // 1/(PHI-PSI)
static constexpr float NEGV = -1e30f;
static constexpr float NEGINF = -3.402823466e38f;

__device__ inline float softplusf(float x){
    return fmaxf(x, 0.f) + log1pf(expf(-fabsf(x)));
}

// ---------------- LayerNorm of X_write -> Xn ----------------
__global__ __launch_bounds__(256) void ln_kernel(const float* __restrict__ X,
                                                 const float* __restrict__ w,
                                                 const float* __restrict__ b,
                                                 float* __restrict__ Xn)
{
    int row = blockIdx.x;                 // 0..32767
    const float* x = X + (size_t)row * D_;
    float2 v = ((const float2*)x)[threadIdx.x];
    float s = v.x + v.y, ss = v.x*v.x + v.y*v.y;
    for (int off = 32; off; off >>= 1) { s += __shfl_down(s, off); ss += __shfl_down(ss, off); }
    __shared__ float sh[8];
    int wid = threadIdx.x >> 6, lane = threadIdx.x & 63;
    if (lane == 0) { sh[wid] = s; sh[4+wid] = ss; }
    __syncthreads();
    if (threadIdx.x == 0) {
        float S = sh[0]+sh[1]+sh[2]+sh[3], SS = sh[4]+sh[5]+sh[6]+sh[7];
        float mu = S / (float)D_;
        float var = SS / (float)D_ - mu*mu;
        sh[0] = mu; sh[1] = rsqrtf(var + 1e-5f);
    }
    __syncthreads();
    float mu = sh[0], rs = sh[1];
    float2 wv = ((const float2*)w)[threadIdx.x];
    float2 bv = ((const float2*)b)[threadIdx.x];
    float2 o;
    o.x = (v.x - mu) * rs * wv.x + bv.x;
    o.y = (v.y - mu) * rs * wv.y + bv.y;
    ((float2*)(Xn + (size_t)row * D_))[threadIdx.x] = o;
}

// ---------------- q_mean over T (two stage) ----------------
__global__ __launch_bounds__(512) void qmean_part_k(const float* __restrict__ Xr, float* __restrict__ part)
{
    int b = blockIdx.x, c = blockIdx.y, d = threadIdx.x;
    const float* base = Xr + ((size_t)b*T_ + (size_t)c*256) * D_ + d;
    float s = 0.f;
    for (int t = 0; t < 256; t++) s += base[(size_t)t * D_];
    part[((size_t)b*8 + c)*D_ + d] = s;
}

__global__ __launch_bounds__(512) void qmean_final_k(const float* __restrict__ part, float* __restrict__ qmean)
{
    int b = blockIdx.x, d = threadIdx.x;
    float s = 0.f;
    for (int c = 0; c < 8; c++) s += part[((size_t)b*8 + c)*D_ + d];
    qmean[(size_t)b*D_ + d] = s * (1.f/2048.f);
}

// ---------------- XW0 = Xn @ W0^T  (f32 tiled GEMM) ----------------
__global__ __launch_bounds__(256) void gemm_xw0(const float* __restrict__ A,
                                                const float* __restrict__ W,
                                                float* __restrict__ C)
{
    __shared__ float As[64][33];
    __shared__ float Bs[64][33];
    int t0 = blockIdx.x * 64, d0 = blockIdx.y * 64;
    int tid = threadIdx.x;
    int tx = tid & 15, ty = tid >> 4;
    float acc[4][4] = {};
    int lr = tid >> 3;            // 0..31
    int lc = (tid & 7) * 4;       // 0..28
    for (int e0 = 0; e0 < D_; e0 += 32) {
        for (int p = 0; p < 2; p++) {
            int r = lr + p*32;
            float4 av = *(const float4*)(A + (size_t)(t0 + r)*D_ + e0 + lc);
            As[r][lc] = av.x; As[r][lc+1] = av.y; As[r][lc+2] = av.z; As[r][lc+3] = av.w;
            float4 bv = *(const float4*)(W + (size_t)(d0 + r)*D_ + e0 + lc);
            Bs[r][lc] = bv.x; Bs[r][lc+1] = bv.y; Bs[r][lc+2] = bv.z; Bs[r][lc+3] = bv.w;
        }
        __syncthreads();
        for (int k = 0; k < 32; k++) {
            float a[4], bb[4];
            #pragma unroll
            for (int i = 0; i < 4; i++) a[i] = As[ty*4+i][k];
            #pragma unroll
            for (int j = 0; j < 4; j++) bb[j] = Bs[tx*4+j][k];
            #pragma unroll
            for (int i = 0; i < 4; i++)
                #pragma unroll
                for (int j = 0; j < 4; j++) acc[i][j] += a[i]*bb[j];
        }
        __syncthreads();
    }
    for (int i = 0; i < 4; i++)
        for (int j = 0; j < 4; j++)
            C[(size_t)(t0 + ty*4 + i)*D_ + d0 + tx*4 + j] = acc[i][j];
}

// ---------------- sal: banded Xn[i] . XW0[j],  j = i-64..i-1 ----------------
__global__ __launch_bounds__(256) void sal_kernel(const float* __restrict__ Xn,
                                                  const float* __restrict__ XW0,
                                                  float* __restrict__ sal)
{
    int b = blockIdx.x;
    int i0 = blockIdx.y * 64;
    __shared__ float Xs[64][65];
    __shared__ float Ws[128][65];
    int tid = threadIdx.x;
    int tx = tid & 15, ty = tid >> 4;
    float acc[4][8] = {};
    const float* XnB = Xn  + (size_t)b*T_*D_;
    const float* XwB = XW0 + (size_t)b*T_*D_;
    int lc = (tid & 15) * 4;   // 0..60
    int lr = tid >> 4;         // 0..15
    for (int d0 = 0; d0 < D_; d0 += 64) {
        for (int p = 0; p < 4; p++) {
            int r = lr + p*16;
            float4 v = *(const float4*)(XnB + (size_t)(i0 + r)*D_ + d0 + lc);
            Xs[r][lc] = v.x; Xs[r][lc+1] = v.y; Xs[r][lc+2] = v.z; Xs[r][lc+3] = v.w;
        }
        for (int p = 0; p < 8; p++) {
            int r = lr + p*16;
            int j = i0 - 64 + r;
            float4 v = make_float4(0.f,0.f,0.f,0.f);
            if (j >= 0) v = *(const float4*)(XwB + (size_t)j*D_ + d0 + lc);
            Ws[r][lc] = v.x; Ws[r][lc+1] = v.y; Ws[r][lc+2] = v.z; Ws[r][lc+3] = v.w;
        }
        __syncthreads();
        for (int k = 0; k < 64; k++) {
            float a[4], bb[8];
            #pragma unroll
            for (int i = 0; i < 4; i++) a[i] = Xs[ty*4+i][k];
            #pragma unroll
            for (int j = 0; j < 8; j++) bb[j] = Ws[j*16+tx][k];
            #pragma unroll
            for (int i = 0; i < 4; i++)
                #pragma unroll
                for (int j = 0; j < 8; j++) acc[i][j] += a[i]*bb[j];
        }
        __syncthreads();
    }
    float* salB = sal + (size_t)b*T_*WIN_;
    for (int i = 0; i < 4; i++) {
        int il = ty*4 + i;
        int ig = i0 + il;
        for (int j = 0; j < 8; j++) {
            int jl = j*16 + tx;
            int o = il - jl + 64;       // offset i - j
            if (o >= 1 && o <= 64) {
                int jg = i0 - 64 + jl;
                float v = (jg >= 0) ? acc[i][j] : NEGV;
                salB[(size_t)ig*WIN_ + (o - 1)] = v;
            }
        }
    }
}

// ---------------- per-batch top-16 ----------------
__global__ __launch_bounds__(256) void topk_kernel(const float* __restrict__ sal,
                                                   int* __restrict__ ti, int* __restrict__ tj,
                                                   float* __restrict__ tv)
{
    int b = blockIdx.x;
    const float* s = sal + (size_t)b * (T_*WIN_);
    float lv[16]; int li[16];
    for (int k = 0; k < 16; k++) { lv[k] = NEGINF; li[k] = 0x7FFFFFFF; }
    for (int p = threadIdx.x; p < T_*WIN_; p += 256) {
        float v = s[p];
        if (v > lv[15]) {
            int k = 15;
            while (k > 0 && lv[k-1] < v) { lv[k] = lv[k-1]; li[k] = li[k-1]; k--; }
            lv[k] = v; li[k] = p;
        }
    }
    __shared__ float sv[4096];
    __shared__ int   si[4096];
    for (int k = 0; k < 16; k++) { sv[threadIdx.x*16+k] = lv[k]; si[threadIdx.x*16+k] = li[k]; }
    __syncthreads();
    __shared__ float rv[256]; __shared__ int ri[256]; __shared__ int rp[256];
    __shared__ float resv[16]; __shared__ int resi[16];
    for (int r = 0; r < 16; r++) {
        float best = NEGINF; int bi = 0x7FFFFFFF; int bp = -1;
        for (int k = 0; k < 16; k++) {
            float v = sv[threadIdx.x*16+k];
            int idx = si[threadIdx.x*16+k];
            if (v > best || (v == best && idx < bi)) { best = v; bi = idx; bp = threadIdx.x*16+k; }
        }
        rv[threadIdx.x] = best; ri[threadIdx.x] = bi; rp[threadIdx.x] = bp;
        __syncthreads();
        for (int st = 128; st > 0; st >>= 1) {
            if (threadIdx.x < st) {
                float v2 = rv[threadIdx.x+st]; int i2 = ri[threadIdx.x+st];
                if (v2 > rv[threadIdx.x] || (v2 == rv[threadIdx.x] && i2 < ri[threadIdx.x])) {
                    rv[threadIdx.x] = v2; ri[threadIdx.x] = i2; rp[threadIdx.x] = rp[threadIdx.x+st];
                }
            }
            __syncthreads();
        }
        if (threadIdx.x == 0) { resv[r] = rv[0]; resi[r] = ri[0]; sv[rp[0]] = NEGINF; }
        __syncthreads();
    }
    if (threadIdx.x < 16) {
        int flat = resi[threadIdx.x];
        int i = flat >> 6;
        int o = (flat & 63) + 1;
        ti[b*16+threadIdx.x] = i;
        tj[b*16+threadIdx.x] = i - o;
        tv[b*16+threadIdx.x] = resv[threadIdx.x];
    }
}

// ---------------- slot pipeline (per batch) ----------------
__global__ __launch_bounds__(256) void slot_kernel(
    const float* __restrict__ Xn, const float* __restrict__ slots_in,
    const int* __restrict__ ti, const int* __restrict__ tj, const float* __restrict__ tv,
    const float* __restrict__ W_V, const float* __restrict__ W_K_slot, const float* __restrict__ skb,
    const float* __restrict__ Wg, const float* __restrict__ Wgb,
    const float* __restrict__ lnw, const float* __restrict__ lnb,
    const float* __restrict__ WsQ, const float* __restrict__ WsK, const float* __restrict__ WsV,
    const float* __restrict__ lambda_, const float* __restrict__ temps,
    float* __restrict__ snws, float* __restrict__ out_slots)
{
    int b = blockIdx.x, tid = threadIdx.x;
    __shared__ float alpha[16];
    __shared__ float y[D_];
    __shared__ float Rt[DB_];
    __shared__ float sl[K_][DB_];
    __shared__ float skv[K_][DB_];
    __shared__ float wR[K_][DB_];
    __shared__ float upd[K_][DB_];
    __shared__ float Bn[K_][DB_];
    __shared__ float qq[K_][DB_], kk2[K_][DB_], vv[K_][DB_];
    __shared__ float swv[K_], compat[K_], mu7[K_], rs7[K_];
    __shared__ float sa[K_][K_];

    if (tid == 0) {
        float m = NEGINF;
        for (int k = 0; k < 16; k++) m = fmaxf(m, tv[b*16+k]);
        float ssum = 0.f;
        for (int k = 0; k < 16; k++) { float e = expf(tv[b*16+k] - m); alpha[k] = e; ssum += e; }
        for (int k = 0; k < 16; k++) alpha[k] /= ssum;
    }
    for (int p = tid; p < K_*DB_; p += 256) sl[p>>7][p&127] = slots_in[(size_t)b*K_*DB_ + p];
    __syncthreads();

    // y[e] = sum_k alpha_k (Xn[i_k,e] - Xn[j_k,e])
    for (int e = tid; e < D_; e += 256) {
        float acc = 0.f;
        for (int k = 0; k < 16; k++) {
            int i = ti[b*16+k], j = tj[b*16+k];
            acc += alpha[k] * (Xn[((size_t)b*T_ + i)*D_ + e] - Xn[((size_t)b*T_ + j)*D_ + e]);
        }
        y[e] = acc;
    }
    __syncthreads();
    // Rt = y @ W_V
    if (tid < DB_) {
        float acc = 0.f;
        for (int e = 0; e < D_; e++) acc += y[e] * W_V[(size_t)e*DB_ + tid];
        Rt[tid] = acc;
    }
    __syncthreads();
    // slot keys * Rt products
    if (tid < DB_) {
        int d = tid;
        for (int k = 0; k < K_; k++) {
            float acc = skb[k*DB_ + d];
            for (int e = 0; e < DB_; e++) acc += sl[k][e] * W_K_slot[(size_t)e*DB_ + d];
            skv[k][d] = acc * Rt[d];
        }
    }
    __syncthreads();
    if (tid < K_) {
        float a = 0.f;
        for (int d = 0; d < DB_; d++) a += skv[tid][d];
        compat[tid] = a * SCALE_ * softplusf(temps[tid]);
    }
    __syncthreads();
    if (tid == 0) {
        float m = compat[0];
        for (int k = 1; k < K_; k++) m = fmaxf(m, compat[k]);
        float ssum = 0.f;
        for (int k = 0; k < K_; k++) { float e = expf(compat[k]-m); swv[k] = e; ssum += e; }
        for (int k = 0; k < K_; k++) swv[k] /= ssum;
    }
    __syncthreads();
    for (int p = tid; p < K_*DB_; p += 256) wR[p>>7][p&127] = swv[p>>7] * Rt[p&127];
    __syncthreads();
    // gate + slots_upd
    if (tid < DB_) {
        int d = tid;
        for (int k = 0; k < K_; k++) {
            float acc = Wgb[d];
            for (int e = 0; e < DB_; e++) acc += sl[k][e] * Wg[(size_t)e*DB_ + d];
            for (int e = 0; e < DB_; e++) acc += wR[k][e] * Wg[(size_t)(DB_+e)*DB_ + d];
            float g = 1.f / (1.f + expf(-acc));
            upd[k][d] = (1.f - g) * sl[k][d] + g * wR[k][d];
        }
    }
    __syncthreads();
    // strand LN
    if (tid < K_) {
        float s = 0.f, ss = 0.f;
        for (int d = 0; d < DB_; d++) { float v = upd[tid][d]; s += v; ss += v*v; }
        float mu = s / (float)DB_;
        mu7[tid] = mu;
        rs7[tid] = rsqrtf(ss/(float)DB_ - mu*mu + 1e-5f);
    }
    __syncthreads();
    for (int p = tid; p < K_*DB_; p += 256) {
        int k = p>>7, d = p&127;
        Bn[k][d] = (upd[k][d] - mu7[k]) * rs7[k] * lnw[d] + lnb[d];
    }
    __syncthreads();
    if (tid < DB_) {
        int d = tid;
        for (int k = 0; k < K_; k++) {
            float aq = 0.f, ak = 0.f, av = 0.f;
            for (int e = 0; e < DB_; e++) {
                float bn = Bn[k][e];
                aq += bn * WsQ[(size_t)e*DB_ + d];
                ak += bn * WsK[(size_t)e*DB_ + d];
                av += bn * WsV[(size_t)e*DB_ + d];
            }
            qq[k][d] = aq; kk2[k][d] = ak; vv[k][d] = av;
        }
    }
    __syncthreads();
    if (tid < K_*K_) {
        int q = tid / K_, j = tid % K_;
        float a = 0.f;
        for (int e = 0; e < DB_; e++) a += qq[q][e] * kk2[j][e];
        sa[q][j] = a * SCALE_;
    }
    __syncthreads();
    if (tid < K_) {
        float m = sa[tid][0];
        for (int j = 1; j < K_; j++) m = fmaxf(m, sa[tid][j]);
        float ssum = 0.f;
        for (int j = 0; j < K_; j++) { float e = expf(sa[tid][j]-m); sa[tid][j] = e; ssum += e; }
        for (int j = 0; j < K_; j++) sa[tid][j] /= ssum;
    }
    __syncthreads();
    if (tid < DB_) {
        int d = tid;
        float lam = tanhf(lambda_[d]);
        lam = fminf(fmaxf(lam, -0.5f), 0.5f);
        for (int k = 0; k < K_; k++) {
            float c = 0.f;
            for (int j = 0; j < K_; j++) c += sa[k][j] * vv[j][d];
            float sn = upd[k][d] + c * lam;
            snws[((size_t)b*K_ + k)*DB_ + d] = sn;
            out_slots[((size_t)b*K_ + k)*DB_ + d] = sn;
        }
    }
}

// ---------------- losses ----------------
__global__ __launch_bounds__(256) void loss_kernel(const float* __restrict__ sn,
                                                   const float* __restrict__ sl0,
                                                   float* __restrict__ out)
{
    __shared__ float sh[8];
    __shared__ float nrm[B_*K_];
    float acc = 0.f;
    for (int p = threadIdx.x; p < B_*K_*DB_; p += 256) { float d = sn[p] - sl0[p]; acc += d*d; }
    for (int off = 32; off; off >>= 1) acc += __shfl_down(acc, off);
    int lane = threadIdx.x & 63, w = threadIdx.x >> 6;
    if (lane == 0) sh[w] = acc;
    __syncthreads();
    if (threadIdx.x == 0) out[0] = (sh[0]+sh[1]+sh[2]+sh[3]) / (float)(B_*K_*DB_);
    if (threadIdx.x < B_*K_) {
        float s = 0.f;
        const float* a = sn + (size_t)threadIdx.x * DB_;
        for (int d = 0; d < DB_; d++) s += a[d]*a[d];
        nrm[threadIdx.x] = fmaxf(sqrtf(s), 1e-12f);
    }
    __syncthreads();
    float acc2 = 0.f;
    for (int p = threadIdx.x; p < B_*K_*K_; p += 256) {
        int bb = p / (K_*K_), r = p % (K_*K_), q = r / K_, j = r % K_;
        if (q != j) {
            const float* a = sn + ((size_t)bb*K_ + q)*DB_;
            const float* c = sn + ((size_t)bb*K_ + j)*DB_;
            float dot = 0.f;
            for (int d = 0; d < DB_; d++) dot += a[d]*c[d];
            float cs = dot / (nrm[bb*K_+q] * nrm[bb*K_+j]);
            acc2 += cs*cs;
        }
    }
    for (int off = 32; off; off >>= 1) acc2 += __shfl_down(acc2, off);
    __syncthreads();
    if (lane == 0) sh[w] = acc2;
    __syncthreads();
    if (threadIdx.x == 0) out[1] = (sh[0]+sh[1]+sh[2]+sh[3]) / (float)(B_*(K_*K_-K_));
}

// ---------------- read prep: basis/gate, kq = k_r @ WQr^T, vg = v_r*gate ----------------
__global__ __launch_bounds__(256) void readprep_kernel(
    const float* __restrict__ qmean, const float* __restrict__ W0, const float* __restrict__ sn,
    const float* __restrict__ rc, const float* __restrict__ WKr, const float* __restrict__ WQr,
    const float* __restrict__ WVr, float* __restrict__ kq, float* __restrict__ vg)
{
    int b = blockIdx.x, tid = threadIdx.x;
    __shared__ float qm[D_];
    __shared__ float sl[K_][DB_];
    __shared__ float kr[K_][DB_];
    __shared__ float rsh[8];
    __shared__ float bas1s, bas2s;
    for (int p = tid; p < D_; p += 256) qm[p] = qmean[(size_t)b*D_ + p];
    for (int p = tid; p < K_*DB_; p += 256) sl[p>>7][p&127] = sn[(size_t)b*K_*DB_ + p];
    __syncthreads();
    float ph = 0.f, ps = 0.f;
    for (int d = tid; d < D_; d += 256) {
        float w0q = 0.f;
        const float* wr = W0 + (size_t)d*D_;
        for (int e = 0; e < D_; e++) w0q += qm[e] * wr[e];
        float phi = (w0q - PSI_*qm[d]) * INV_DENOM_;
        float psi = (PHI_*qm[d] - w0q) * INV_DENOM_;
        ph += phi*phi; ps += psi*psi;
    }
    for (int off = 32; off; off >>= 1) { ph += __shfl_down(ph, off); ps += __shfl_down(ps, off); }
    int lane = tid & 63, w = tid >> 6;
    if (lane == 0) { rsh[w] = ph; rsh[4+w] = ps; }
    __syncthreads();
    if (tid == 0) {
        float P = rsh[0]+rsh[1]+rsh[2]+rsh[3], Q = rsh[4]+rsh[5]+rsh[6]+rsh[7];
        float pm = sqrtf(P), qmag = sqrtf(Q);
        float tot = pm + qmag + 1e-6f;
        bas1s = pm / tot; bas2s = qmag / tot;
    }
    __syncthreads();
    float b1 = bas1s, b2 = bas2s;
    if (tid < DB_) {
        int d = tid;
        for (int k = 0; k < K_; k++) {
            float a = 0.f;
            for (int e = 0; e < DB_; e++) a += sl[k][e] * WKr[(size_t)e*DB_ + d];
            kr[k][d] = a;
        }
    }
    __syncthreads();
    for (int p = tid; p < K_*D_; p += 256) {
        int k = p >> 9, e = p & 511;
        float a = 0.f;
        const float* wq = WQr + (size_t)e*DB_;
        for (int d = 0; d < DB_; d++) a += kr[k][d] * wq[d];
        kq[((size_t)b*K_ + k)*D_ + e] = a;
    }
    for (int p = tid; p < K_*D_; p += 256) {
        int k = p >> 9, dd = p & 511;
        float a = 0.f;
        for (int e = 0; e < DB_; e++) a += sl[k][e] * WVr[(size_t)e*D_ + dd];
        float gpre = rc[((size_t)k*3 + 0)*D_ + dd] + b1*rc[((size_t)k*3 + 1)*D_ + dd] + b2*rc[((size_t)k*3 + 2)*D_ + dd];
        float g = tanhf(gpre);
        g = fminf(fmaxf(g, -0.5f), 0.5f);
        vg[((size_t)b*K_ + k)*D_ + dd] = a * g;
    }
}

// ---------------- z: softmax over 7 slots + weighted combine ----------------
__global__ __launch_bounds__(256) void z_kernel(const float* __restrict__ Xr,
                                                const float* __restrict__ kq,
                                                const float* __restrict__ vg,
                                                float* __restrict__ z)
{
    int b = blockIdx.x;
    int t0 = blockIdx.y * 64;
    __shared__ float kqs[K_][D_];
    __shared__ float vgs[K_][D_];
    int tid = threadIdx.x;
    for (int p = tid; p < K_*D_; p += 256) {
        kqs[p>>9][p&511] = kq[(size_t)b*K_*D_ + p];
        vgs[p>>9][p&511] = vg[(size_t)b*K_*D_ + p];
    }
    __syncthreads();
    int lane = tid & 63, w = tid >> 6;
    for (int it = 0; it < 16; it++) {
        int t = t0 + w*16 + it;
        const float* x = Xr + ((size_t)b*T_ + t)*D_;
        float xr[8];
        float s[K_] = {0,0,0,0,0,0,0};
        #pragma unroll
        for (int r = 0; r < 8; r++) {
            int e = lane + r*64;
            xr[r] = x[e];
            #pragma unroll
            for (int k = 0; k < K_; k++) s[k] += xr[r] * kqs[k][e];
        }
        #pragma unroll
        for (int k = 0; k < K_; k++)
            for (int off = 32; off; off >>= 1) s[k] += __shfl_xor(s[k], off);
        float sc[K_];
        float m = NEGINF;
        #pragma unroll
        for (int k = 0; k < K_; k++) { sc[k] = s[k] * SCALE_; m = fmaxf(m, sc[k]); }
        float p[K_], ssum = 0.f;
        #pragma unroll
        for (int k = 0; k < K_; k++) { p[k] = expf(sc[k] - m); ssum += p[k]; }
        float inv = 1.f / ssum;
        float* zp = z + ((size_t)b*T_ + t)*D_;
        #pragma unroll
        for (int r = 0; r < 8; r++) {
            int e = lane + r*64;
            float a = 0.f;
            #pragma unroll
            for (int k = 0; k < K_; k++) a += p[k] * vgs[k][e];
            zp[e] = a * inv;
        }
    }
}

extern "C" void kernel_launch(void* const* d_in, const int* in_sizes, int n_in,
                              void* d_out, int out_size, void* d_ws, size_t ws_size,
                              hipStream_t stream)
{
    const float* X_write = (const float*)d_in[0];
    const float* X_read  = (const float*)d_in[1];
    const float* slots   = (const float*)d_in[2];
    const float* W0      = (const float*)d_in[3];
    const float* lnw_w   = (const float*)d_in[4];
    const float* lnw_b   = (const float*)d_in[5];
    const float* W_V     = (const float*)d_in[6];
    const float* W_K_slot= (const float*)d_in[7];
    const float* skb     = (const float*)d_in[8];
    const float* Wg      = (const float*)d_in[9];
    const float* Wgb     = (const float*)d_in[10];
    const float* lns_w   = (const float*)d_in[11];
    const float* lns_b   = (const float*)d_in[12];
    const float* WsQ     = (const float*)d_in[13];
    const float* WsK     = (const float*)d_in[14];
    const float* WsV     = (const float*)d_in[15];
    const float* lambda_ = (const float*)d_in[16];
    const float* WQr     = (const float*)d_in[17];
    const float* WKr     = (const float*)d_in[18];
    const float* WVr     = (const float*)d_in[19];
    const float* rc      = (const float*)d_in[20];
    const float* temps   = (const float*)d_in[21];

    float* ws = (float*)d_ws;
    const size_t NXD = (size_t)B_*T_*D_;           // 16777216
    float* Xn    = ws;
    float* XW0   = ws + NXD;
    float* sal   = ws + 2*NXD;                     // +16777216
    float* qpart = sal + (size_t)B_*T_*WIN_;       // +2097152
    float* qmean = qpart + (size_t)B_*8*D_;        // +65536
    float* snws  = qmean + (size_t)B_*D_;          // +8192
    float* kq    = snws + (size_t)B_*K_*DB_;       // +14336
    float* vg    = kq + (size_t)B_*K_*D_;          // +57344
    float* tv    = vg + (size_t)B_*K_*D_;          // +57344
    int*   ti    = (int*)(tv + 256);
    int*   tj    = (int*)(tv + 512);

    float* z_out     = (float*)d_out;
    float* slots_out = z_out + NXD;
    float* loss_out  = slots_out + (size_t)B_*K_*DB_;

    ln_kernel<<<dim3(B_*T_), dim3(256), 0, stream>>>(X_write, lnw_w, lnw_b, Xn);
    qmean_part_k<<<dim3(B_, 8), dim3(512), 0, stream>>>(X_read, qpart);
    qmean_final_k<<<dim3(B_), dim3(512), 0, stream>>>(qpart, qmean);
    gemm_xw0<<<dim3(B_*T_/64, D_/64), dim3(256), 0, stream>>>(Xn, W0, XW0);
    sal_kernel<<<dim3(B_, T_/64), dim3(256), 0, stream>>>(Xn, XW0, sal);
    topk_kernel<<<dim3(B_), dim3(256), 0, stream>>>(sal, ti, tj, tv);
    slot_kernel<<<dim3(B_), dim3(256), 0, stream>>>(Xn, slots, ti, tj, tv,
        W_V, W_K_slot, skb, Wg, Wgb, lns_w, lns_b, WsQ, WsK, WsV, lambda_, temps,
        snws, slots_out);
    loss_kernel<<<dim3(1), dim3(256), 0, stream>>>(snws, slots, loss_out);
    readprep_kernel<<<dim3(B_), dim3(256), 0, stream>>>(qmean, W0, snws, rc, WKr, WQr, WVr, kq, vg);
    z_kernel<<<dim3(B_, T_/64), dim3(256), 0, stream>>>(X_read, kq, vg, z_out);
}

// Round 2
// 817.576 us; speedup vs baseline: 1.5821x; 1.5821x over previous
//
#include <hip/hip_runtime.h>
#include <math.h>

#define B_ 16
#define T_ 2048
#define D_ 512
#define DB_ 128
#define K_ 7
#define TOPK_ 16
#define WIN_ 64

static constexpr float SCALE_ = 0.08838834764831845f;   // 128^-0.5
static constexpr float PHI_ = 1.618033988749895f;
static constexpr float PSI_ = -0.6180339887498949f;
static constexpr float INV_DENOM_ = 0.4472135954999579f; // 1/(PHI-PSI)
static constexpr float NEGV = -1e30f;
static constexpr float NEGINF = -3.402823466e38f;

__device__ inline float softplusf(float x){
    return fmaxf(x, 0.f) + log1pf(expf(-fabsf(x)));
}

// ---------------- LayerNorm of X_write -> Xn ----------------
__global__ __launch_bounds__(256) void ln_kernel(const float* __restrict__ X,
                                                 const float* __restrict__ w,
                                                 const float* __restrict__ b,
                                                 float* __restrict__ Xn)
{
    int row = blockIdx.x;                 // 0..32767
    const float* x = X + (size_t)row * D_;
    float2 v = ((const float2*)x)[threadIdx.x];
    float s = v.x + v.y, ss = v.x*v.x + v.y*v.y;
    for (int off = 32; off; off >>= 1) { s += __shfl_down(s, off); ss += __shfl_down(ss, off); }
    __shared__ float sh[8];
    int wid = threadIdx.x >> 6, lane = threadIdx.x & 63;
    if (lane == 0) { sh[wid] = s; sh[4+wid] = ss; }
    __syncthreads();
    if (threadIdx.x == 0) {
        float S = sh[0]+sh[1]+sh[2]+sh[3], SS = sh[4]+sh[5]+sh[6]+sh[7];
        float mu = S / (float)D_;
        float var = SS / (float)D_ - mu*mu;
        sh[0] = mu; sh[1] = rsqrtf(var + 1e-5f);
    }
    __syncthreads();
    float mu = sh[0], rs = sh[1];
    float2 wv = ((const float2*)w)[threadIdx.x];
    float2 bv = ((const float2*)b)[threadIdx.x];
    float2 o;
    o.x = (v.x - mu) * rs * wv.x + bv.x;
    o.y = (v.y - mu) * rs * wv.y + bv.y;
    ((float2*)(Xn + (size_t)row * D_))[threadIdx.x] = o;
}

// ---------------- q_mean over T (two stage) ----------------
__global__ __launch_bounds__(512) void qmean_part_k(const float* __restrict__ Xr, float* __restrict__ part)
{
    int b = blockIdx.x, c = blockIdx.y, d = threadIdx.x;
    const float* base = Xr + ((size_t)b*T_ + (size_t)c*256) * D_ + d;
    float s = 0.f;
    for (int t = 0; t < 256; t++) s += base[(size_t)t * D_];
    part[((size_t)b*8 + c)*D_ + d] = s;
}

__global__ __launch_bounds__(512) void qmean_final_k(const float* __restrict__ part, float* __restrict__ qmean)
{
    int b = blockIdx.x, d = threadIdx.x;
    float s = 0.f;
    for (int c = 0; c < 8; c++) s += part[((size_t)b*8 + c)*D_ + d];
    qmean[(size_t)b*D_ + d] = s * (1.f/2048.f);
}

// ---------------- XW0 = Xn @ W0^T  (f32 tiled GEMM) ----------------
__global__ __launch_bounds__(256) void gemm_xw0(const float* __restrict__ A,
                                                const float* __restrict__ W,
                                                float* __restrict__ C)
{
    __shared__ float As[64][33];
    __shared__ float Bs[64][33];
    int t0 = blockIdx.x * 64, d0 = blockIdx.y * 64;
    int tid = threadIdx.x;
    int tx = tid & 15, ty = tid >> 4;
    float acc[4][4] = {};
    int lr = tid >> 3;            // 0..31
    int lc = (tid & 7) * 4;       // 0..28
    for (int e0 = 0; e0 < D_; e0 += 32) {
        for (int p = 0; p < 2; p++) {
            int r = lr + p*32;
            float4 av = *(const float4*)(A + (size_t)(t0 + r)*D_ + e0 + lc);
            As[r][lc] = av.x; As[r][lc+1] = av.y; As[r][lc+2] = av.z; As[r][lc+3] = av.w;
            float4 bv = *(const float4*)(W + (size_t)(d0 + r)*D_ + e0 + lc);
            Bs[r][lc] = bv.x; Bs[r][lc+1] = bv.y; Bs[r][lc+2] = bv.z; Bs[r][lc+3] = bv.w;
        }
        __syncthreads();
        for (int k = 0; k < 32; k++) {
            float a[4], bb[4];
            #pragma unroll
            for (int i = 0; i < 4; i++) a[i] = As[ty*4+i][k];
            #pragma unroll
            for (int j = 0; j < 4; j++) bb[j] = Bs[tx*4+j][k];
            #pragma unroll
            for (int i = 0; i < 4; i++)
                #pragma unroll
                for (int j = 0; j < 4; j++) acc[i][j] += a[i]*bb[j];
        }
        __syncthreads();
    }
    for (int i = 0; i < 4; i++)
        for (int j = 0; j < 4; j++)
            C[(size_t)(t0 + ty*4 + i)*D_ + d0 + tx*4 + j] = acc[i][j];
}

// ---------------- sal: banded Xn[i] . XW0[j],  j = i-64..i-1 ----------------
__global__ __launch_bounds__(256) void sal_kernel(const float* __restrict__ Xn,
                                                  const float* __restrict__ XW0,
                                                  float* __restrict__ sal)
{
    int b = blockIdx.x;
    int i0 = blockIdx.y * 64;
    __shared__ float Xs[64][65];
    __shared__ float Ws[128][65];
    int tid = threadIdx.x;
    int tx = tid & 15, ty = tid >> 4;
    float acc[4][8] = {};
    const float* XnB = Xn  + (size_t)b*T_*D_;
    const float* XwB = XW0 + (size_t)b*T_*D_;
    int lc = (tid & 15) * 4;   // 0..60
    int lr = tid >> 4;         // 0..15
    for (int d0 = 0; d0 < D_; d0 += 64) {
        for (int p = 0; p < 4; p++) {
            int r = lr + p*16;
            float4 v = *(const float4*)(XnB + (size_t)(i0 + r)*D_ + d0 + lc);
            Xs[r][lc] = v.x; Xs[r][lc+1] = v.y; Xs[r][lc+2] = v.z; Xs[r][lc+3] = v.w;
        }
        for (int p = 0; p < 8; p++) {
            int r = lr + p*16;
            int j = i0 - 64 + r;
            float4 v = make_float4(0.f,0.f,0.f,0.f);
            if (j >= 0) v = *(const float4*)(XwB + (size_t)j*D_ + d0 + lc);
            Ws[r][lc] = v.x; Ws[r][lc+1] = v.y; Ws[r][lc+2] = v.z; Ws[r][lc+3] = v.w;
        }
        __syncthreads();
        for (int k = 0; k < 64; k++) {
            float a[4], bb[8];
            #pragma unroll
            for (int i = 0; i < 4; i++) a[i] = Xs[ty*4+i][k];
            #pragma unroll
            for (int j = 0; j < 8; j++) bb[j] = Ws[j*16+tx][k];
            #pragma unroll
            for (int i = 0; i < 4; i++)
                #pragma unroll
                for (int j = 0; j < 8; j++) acc[i][j] += a[i]*bb[j];
        }
        __syncthreads();
    }
    float* salB = sal + (size_t)b*T_*WIN_;
    for (int i = 0; i < 4; i++) {
        int il = ty*4 + i;
        int ig = i0 + il;
        for (int j = 0; j < 8; j++) {
            int jl = j*16 + tx;
            int o = il - jl + 64;       // offset i - j
            if (o >= 1 && o <= 64) {
                int jg = i0 - 64 + jl;
                float v = (jg >= 0) ? acc[i][j] : NEGV;
                salB[(size_t)ig*WIN_ + (o - 1)] = v;
            }
        }
    }
}

// ---------------- top-16: stage 1, per (batch, chunk) local top-16 ----------------
// chunk = 2048 contiguous flat-sal elements; 64 chunks per batch.
// Keeps (value desc, index asc) order; dropping beyond local top-16 is safe
// because 16 dominating elements from the same chunk precede any dropped one.
__global__ __launch_bounds__(256) void topk_stage1(const float* __restrict__ sal,
                                                   float* __restrict__ cv, int* __restrict__ ci)
{
    int b = blockIdx.x, c = blockIdx.y;
    const float* s = sal + (size_t)b*(T_*WIN_) + (size_t)c*2048;
    int base = c*2048;
    int tid = threadIdx.x;
    // per-thread sorted list of its 8 elements (value desc, index asc)
    float lv[8]; int li[8];
    #pragma unroll
    for (int k = 0; k < 8; k++) { lv[k] = NEGINF; li[k] = 0x7FFFFFFF; }
    #pragma unroll
    for (int r = 0; r < 8; r++) {
        int p = tid + r*256;
        float v = s[p];
        int idx = base + p;
        if (v > lv[7]) {
            int k = 7;
            while (k > 0 && lv[k-1] < v) { lv[k] = lv[k-1]; li[k] = li[k-1]; k--; }
            lv[k] = v; li[k] = idx;
        }
    }
    __shared__ float rv[256]; __shared__ int ri[256]; __shared__ int rt[256];
    int head = 0;
    float* cvo = cv + ((size_t)b*64 + c)*16;
    int*   cio = ci + ((size_t)b*64 + c)*16;
    for (int r = 0; r < 16; r++) {
        float bv2 = (head < 8) ? lv[head] : NEGINF;
        int   bi2 = (head < 8) ? li[head] : 0x7FFFFFFF;
        rv[tid] = bv2; ri[tid] = bi2; rt[tid] = tid;
        __syncthreads();
        for (int st = 128; st > 0; st >>= 1) {
            if (tid < st) {
                float v2 = rv[tid+st]; int i2 = ri[tid+st];
                if (v2 > rv[tid] || (v2 == rv[tid] && i2 < ri[tid])) {
                    rv[tid] = v2; ri[tid] = i2; rt[tid] = rt[tid+st];
                }
            }
            __syncthreads();
        }
        if (rt[0] == tid) head++;
        if (tid == 0) { cvo[r] = rv[0]; cio[r] = ri[0]; }
        __syncthreads();
    }
}

// ---------------- top-16: stage 2, merge 64*16 candidates per batch ----------------
__global__ __launch_bounds__(256) void topk_stage2(const float* __restrict__ cv,
                                                   const int* __restrict__ ci,
                                                   int* __restrict__ ti, int* __restrict__ tj,
                                                   float* __restrict__ tv)
{
    int b = blockIdx.x, tid = threadIdx.x;
    const float* cvb = cv + (size_t)b*1024;
    const int*   cib = ci + (size_t)b*1024;
    // per-thread sorted top-4 of its 4 candidates (value desc, index asc)
    float lv[4]; int li[4];
    #pragma unroll
    for (int k = 0; k < 4; k++) { lv[k] = NEGINF; li[k] = 0x7FFFFFFF; }
    #pragma unroll
    for (int r = 0; r < 4; r++) {
        int p = tid + r*256;
        float v = cvb[p];
        int idx = cib[p];
        if (v > lv[3] || (v == lv[3] && idx < li[3])) {
            int k = 3;
            while (k > 0 && (lv[k-1] < v || (lv[k-1] == v && li[k-1] > idx))) {
                lv[k] = lv[k-1]; li[k] = li[k-1]; k--;
            }
            lv[k] = v; li[k] = idx;
        }
    }
    __shared__ float rv[256]; __shared__ int ri[256]; __shared__ int rt[256];
    int head = 0;
    for (int r = 0; r < 16; r++) {
        float bv2 = (head < 4) ? lv[head] : NEGINF;
        int   bi2 = (head < 4) ? li[head] : 0x7FFFFFFF;
        rv[tid] = bv2; ri[tid] = bi2; rt[tid] = tid;
        __syncthreads();
        for (int st = 128; st > 0; st >>= 1) {
            if (tid < st) {
                float v2 = rv[tid+st]; int i2 = ri[tid+st];
                if (v2 > rv[tid] || (v2 == rv[tid] && i2 < ri[tid])) {
                    rv[tid] = v2; ri[tid] = i2; rt[tid] = rt[tid+st];
                }
            }
            __syncthreads();
        }
        if (rt[0] == tid) head++;
        if (tid == 0) {
            int flat = ri[0];
            int i = flat >> 6;
            int o = (flat & 63) + 1;
            ti[b*16+r] = i;
            tj[b*16+r] = i - o;
            tv[b*16+r] = rv[0];
        }
        __syncthreads();
    }
}

// ---------------- slot pipeline (per batch) ----------------
__global__ __launch_bounds__(256) void slot_kernel(
    const float* __restrict__ Xn, const float* __restrict__ slots_in,
    const int* __restrict__ ti, const int* __restrict__ tj, const float* __restrict__ tv,
    const float* __restrict__ W_V, const float* __restrict__ W_K_slot, const float* __restrict__ skb,
    const float* __restrict__ Wg, const float* __restrict__ Wgb,
    const float* __restrict__ lnw, const float* __restrict__ lnb,
    const float* __restrict__ WsQ, const float* __restrict__ WsK, const float* __restrict__ WsV,
    const float* __restrict__ lambda_, const float* __restrict__ temps,
    float* __restrict__ snws, float* __restrict__ out_slots)
{
    int b = blockIdx.x, tid = threadIdx.x;
    __shared__ float alpha[16];
    __shared__ float y[D_];
    __shared__ float Rt[DB_];
    __shared__ float sl[K_][DB_];
    __shared__ float skv[K_][DB_];
    __shared__ float wR[K_][DB_];
    __shared__ float upd[K_][DB_];
    __shared__ float Bn[K_][DB_];
    __shared__ float qq[K_][DB_], kk2[K_][DB_], vv[K_][DB_];
    __shared__ float swv[K_], compat[K_], mu7[K_], rs7[K_];
    __shared__ float sa[K_][K_];

    if (tid == 0) {
        float m = NEGINF;
        for (int k = 0; k < 16; k++) m = fmaxf(m, tv[b*16+k]);
        float ssum = 0.f;
        for (int k = 0; k < 16; k++) { float e = expf(tv[b*16+k] - m); alpha[k] = e; ssum += e; }
        for (int k = 0; k < 16; k++) alpha[k] /= ssum;
    }
    for (int p = tid; p < K_*DB_; p += 256) sl[p>>7][p&127] = slots_in[(size_t)b*K_*DB_ + p];
    __syncthreads();

    // y[e] = sum_k alpha_k (Xn[i_k,e] - Xn[j_k,e])
    for (int e = tid; e < D_; e += 256) {
        float acc = 0.f;
        for (int k = 0; k < 16; k++) {
            int i = ti[b*16+k], j = tj[b*16+k];
            acc += alpha[k] * (Xn[((size_t)b*T_ + i)*D_ + e] - Xn[((size_t)b*T_ + j)*D_ + e]);
        }
        y[e] = acc;
    }
    __syncthreads();
    // Rt = y @ W_V
    if (tid < DB_) {
        float acc = 0.f;
        for (int e = 0; e < D_; e++) acc += y[e] * W_V[(size_t)e*DB_ + tid];
        Rt[tid] = acc;
    }
    __syncthreads();
    // slot keys * Rt products
    if (tid < DB_) {
        int d = tid;
        for (int k = 0; k < K_; k++) {
            float acc = skb[k*DB_ + d];
            for (int e = 0; e < DB_; e++) acc += sl[k][e] * W_K_slot[(size_t)e*DB_ + d];
            skv[k][d] = acc * Rt[d];
        }
    }
    __syncthreads();
    if (tid < K_) {
        float a = 0.f;
        for (int d = 0; d < DB_; d++) a += skv[tid][d];
        compat[tid] = a * SCALE_ * softplusf(temps[tid]);
    }
    __syncthreads();
    if (tid == 0) {
        float m = compat[0];
        for (int k = 1; k < K_; k++) m = fmaxf(m, compat[k]);
        float ssum = 0.f;
        for (int k = 0; k < K_; k++) { float e = expf(compat[k]-m); swv[k] = e; ssum += e; }
        for (int k = 0; k < K_; k++) swv[k] /= ssum;
    }
    __syncthreads();
    for (int p = tid; p < K_*DB_; p += 256) wR[p>>7][p&127] = swv[p>>7] * Rt[p&127];
    __syncthreads();
    // gate + slots_upd
    if (tid < DB_) {
        int d = tid;
        for (int k = 0; k < K_; k++) {
            float acc = Wgb[d];
            for (int e = 0; e < DB_; e++) acc += sl[k][e] * Wg[(size_t)e*DB_ + d];
            for (int e = 0; e < DB_; e++) acc += wR[k][e] * Wg[(size_t)(DB_+e)*DB_ + d];
            float g = 1.f / (1.f + expf(-acc));
            upd[k][d] = (1.f - g) * sl[k][d] + g * wR[k][d];
        }
    }
    __syncthreads();
    // strand LN
    if (tid < K_) {
        float s = 0.f, ss = 0.f;
        for (int d = 0; d < DB_; d++) { float v = upd[tid][d]; s += v; ss += v*v; }
        float mu = s / (float)DB_;
        mu7[tid] = mu;
        rs7[tid] = rsqrtf(ss/(float)DB_ - mu*mu + 1e-5f);
    }
    __syncthreads();
    for (int p = tid; p < K_*DB_; p += 256) {
        int k = p>>7, d = p&127;
        Bn[k][d] = (upd[k][d] - mu7[k]) * rs7[k] * lnw[d] + lnb[d];
    }
    __syncthreads();
    if (tid < DB_) {
        int d = tid;
        for (int k = 0; k < K_; k++) {
            float aq = 0.f, ak = 0.f, av = 0.f;
            for (int e = 0; e < DB_; e++) {
                float bn = Bn[k][e];
                aq += bn * WsQ[(size_t)e*DB_ + d];
                ak += bn * WsK[(size_t)e*DB_ + d];
                av += bn * WsV[(size_t)e*DB_ + d];
            }
            qq[k][d] = aq; kk2[k][d] = ak; vv[k][d] = av;
        }
    }
    __syncthreads();
    if (tid < K_*K_) {
        int q = tid / K_, j = tid % K_;
        float a = 0.f;
        for (int e = 0; e < DB_; e++) a += qq[q][e] * kk2[j][e];
        sa[q][j] = a * SCALE_;
    }
    __syncthreads();
    if (tid < K_) {
        float m = sa[tid][0];
        for (int j = 1; j < K_; j++) m = fmaxf(m, sa[tid][j]);
        float ssum = 0.f;
        for (int j = 0; j < K_; j++) { float e = expf(sa[tid][j]-m); sa[tid][j] = e; ssum += e; }
        for (int j = 0; j < K_; j++) sa[tid][j] /= ssum;
    }
    __syncthreads();
    if (tid < DB_) {
        int d = tid;
        float lam = tanhf(lambda_[d]);
        lam = fminf(fmaxf(lam, -0.5f), 0.5f);
        for (int k = 0; k < K_; k++) {
            float c = 0.f;
            for (int j = 0; j < K_; j++) c += sa[k][j] * vv[j][d];
            float sn = upd[k][d] + c * lam;
            snws[((size_t)b*K_ + k)*DB_ + d] = sn;
            out_slots[((size_t)b*K_ + k)*DB_ + d] = sn;
        }
    }
}

// ---------------- losses ----------------
__global__ __launch_bounds__(256) void loss_kernel(const float* __restrict__ sn,
                                                   const float* __restrict__ sl0,
                                                   float* __restrict__ out)
{
    __shared__ float sh[8];
    __shared__ float nrm[B_*K_];
    float acc = 0.f;
    for (int p = threadIdx.x; p < B_*K_*DB_; p += 256) { float d = sn[p] - sl0[p]; acc += d*d; }
    for (int off = 32; off; off >>= 1) acc += __shfl_down(acc, off);
    int lane = threadIdx.x & 63, w = threadIdx.x >> 6;
    if (lane == 0) sh[w] = acc;
    __syncthreads();
    if (threadIdx.x == 0) out[0] = (sh[0]+sh[1]+sh[2]+sh[3]) / (float)(B_*K_*DB_);
    if (threadIdx.x < B_*K_) {
        float s = 0.f;
        const float* a = sn + (size_t)threadIdx.x * DB_;
        for (int d = 0; d < DB_; d++) s += a[d]*a[d];
        nrm[threadIdx.x] = fmaxf(sqrtf(s), 1e-12f);
    }
    __syncthreads();
    float acc2 = 0.f;
    for (int p = threadIdx.x; p < B_*K_*K_; p += 256) {
        int bb = p / (K_*K_), r = p % (K_*K_), q = r / K_, j = r % K_;
        if (q != j) {
            const float* a = sn + ((size_t)bb*K_ + q)*DB_;
            const float* c = sn + ((size_t)bb*K_ + j)*DB_;
            float dot = 0.f;
            for (int d = 0; d < DB_; d++) dot += a[d]*c[d];
            float cs = dot / (nrm[bb*K_+q] * nrm[bb*K_+j]);
            acc2 += cs*cs;
        }
    }
    for (int off = 32; off; off >>= 1) acc2 += __shfl_down(acc2, off);
    __syncthreads();
    if (lane == 0) sh[w] = acc2;
    __syncthreads();
    if (threadIdx.x == 0) out[1] = (sh[0]+sh[1]+sh[2]+sh[3]) / (float)(B_*(K_*K_-K_));
}

// ---------------- read prep: basis/gate, kq = k_r @ WQr^T, vg = v_r*gate ----------------
__global__ __launch_bounds__(256) void readprep_kernel(
    const float* __restrict__ qmean, const float* __restrict__ W0, const float* __restrict__ sn,
    const float* __restrict__ rc, const float* __restrict__ WKr, const float* __restrict__ WQr,
    const float* __restrict__ WVr, float* __restrict__ kq, float* __restrict__ vg)
{
    int b = blockIdx.x, tid = threadIdx.x;
    __shared__ float qm[D_];
    __shared__ float sl[K_][DB_];
    __shared__ float kr[K_][DB_];
    __shared__ float rsh[8];
    __shared__ float bas1s, bas2s;
    for (int p = tid; p < D_; p += 256) qm[p] = qmean[(size_t)b*D_ + p];
    for (int p = tid; p < K_*DB_; p += 256) sl[p>>7][p&127] = sn[(size_t)b*K_*DB_ + p];
    __syncthreads();
    float ph = 0.f, ps = 0.f;
    for (int d = tid; d < D_; d += 256) {
        float w0q = 0.f;
        const float* wr = W0 + (size_t)d*D_;
        for (int e = 0; e < D_; e++) w0q += qm[e] * wr[e];
        float phi = (w0q - PSI_*qm[d]) * INV_DENOM_;
        float psi = (PHI_*qm[d] - w0q) * INV_DENOM_;
        ph += phi*phi; ps += psi*psi;
    }
    for (int off = 32; off; off >>= 1) { ph += __shfl_down(ph, off); ps += __shfl_down(ps, off); }
    int lane = tid & 63, w = tid >> 6;
    if (lane == 0) { rsh[w] = ph; rsh[4+w] = ps; }
    __syncthreads();
    if (tid == 0) {
        float P = rsh[0]+rsh[1]+rsh[2]+rsh[3], Q = rsh[4]+rsh[5]+rsh[6]+rsh[7];
        float pm = sqrtf(P), qmag = sqrtf(Q);
        float tot = pm + qmag + 1e-6f;
        bas1s = pm / tot; bas2s = qmag / tot;
    }
    __syncthreads();
    float b1 = bas1s, b2 = bas2s;
    if (tid < DB_) {
        int d = tid;
        for (int k = 0; k < K_; k++) {
            float a = 0.f;
            for (int e = 0; e < DB_; e++) a += sl[k][e] * WKr[(size_t)e*DB_ + d];
            kr[k][d] = a;
        }
    }
    __syncthreads();
    for (int p = tid; p < K_*D_; p += 256) {
        int k = p >> 9, e = p & 511;
        float a = 0.f;
        const float* wq = WQr + (size_t)e*DB_;
        for (int d = 0; d < DB_; d++) a += kr[k][d] * wq[d];
        kq[((size_t)b*K_ + k)*D_ + e] = a;
    }
    for (int p = tid; p < K_*D_; p += 256) {
        int k = p >> 9, dd = p & 511;
        float a = 0.f;
        for (int e = 0; e < DB_; e++) a += sl[k][e] * WVr[(size_t)e*D_ + dd];
        float gpre = rc[((size_t)k*3 + 0)*D_ + dd] + b1*rc[((size_t)k*3 + 1)*D_ + dd] + b2*rc[((size_t)k*3 + 2)*D_ + dd];
        float g = tanhf(gpre);
        g = fminf(fmaxf(g, -0.5f), 0.5f);
        vg[((size_t)b*K_ + k)*D_ + dd] = a * g;
    }
}

// ---------------- z: softmax over 7 slots + weighted combine ----------------
__global__ __launch_bounds__(256) void z_kernel(const float* __restrict__ Xr,
                                                const float* __restrict__ kq,
                                                const float* __restrict__ vg,
                                                float* __restrict__ z)
{
    int b = blockIdx.x;
    int t0 = blockIdx.y * 64;
    __shared__ float kqs[K_][D_];
    __shared__ float vgs[K_][D_];
    int tid = threadIdx.x;
    for (int p = tid; p < K_*D_; p += 256) {
        kqs[p>>9][p&511] = kq[(size_t)b*K_*D_ + p];
        vgs[p>>9][p&511] = vg[(size_t)b*K_*D_ + p];
    }
    __syncthreads();
    int lane = tid & 63, w = tid >> 6;
    for (int it = 0; it < 16; it++) {
        int t = t0 + w*16 + it;
        const float* x = Xr + ((size_t)b*T_ + t)*D_;
        float xr[8];
        float s[K_] = {0,0,0,0,0,0,0};
        #pragma unroll
        for (int r = 0; r < 8; r++) {
            int e = lane + r*64;
            xr[r] = x[e];
            #pragma unroll
            for (int k = 0; k < K_; k++) s[k] += xr[r] * kqs[k][e];
        }
        #pragma unroll
        for (int k = 0; k < K_; k++)
            for (int off = 32; off; off >>= 1) s[k] += __shfl_xor(s[k], off);
        float sc[K_];
        float m = NEGINF;
        #pragma unroll
        for (int k = 0; k < K_; k++) { sc[k] = s[k] * SCALE_; m = fmaxf(m, sc[k]); }
        float p[K_], ssum = 0.f;
        #pragma unroll
        for (int k = 0; k < K_; k++) { p[k] = expf(sc[k] - m); ssum += p[k]; }
        float inv = 1.f / ssum;
        float* zp = z + ((size_t)b*T_ + t)*D_;
        #pragma unroll
        for (int r = 0; r < 8; r++) {
            int e = lane + r*64;
            float a = 0.f;
            #pragma unroll
            for (int k = 0; k < K_; k++) a += p[k] * vgs[k][e];
            zp[e] = a * inv;
        }
    }
}

extern "C" void kernel_launch(void* const* d_in, const int* in_sizes, int n_in,
                              void* d_out, int out_size, void* d_ws, size_t ws_size,
                              hipStream_t stream)
{
    const float* X_write = (const float*)d_in[0];
    const float* X_read  = (const float*)d_in[1];
    const float* slots   = (const float*)d_in[2];
    const float* W0      = (const float*)d_in[3];
    const float* lnw_w   = (const float*)d_in[4];
    const float* lnw_b   = (const float*)d_in[5];
    const float* W_V     = (const float*)d_in[6];
    const float* W_K_slot= (const float*)d_in[7];
    const float* skb     = (const float*)d_in[8];
    const float* Wg      = (const float*)d_in[9];
    const float* Wgb     = (const float*)d_in[10];
    const float* lns_w   = (const float*)d_in[11];
    const float* lns_b   = (const float*)d_in[12];
    const float* WsQ     = (const float*)d_in[13];
    const float* WsK     = (const float*)d_in[14];
    const float* WsV     = (const float*)d_in[15];
    const float* lambda_ = (const float*)d_in[16];
    const float* WQr     = (const float*)d_in[17];
    const float* WKr     = (const float*)d_in[18];
    const float* WVr     = (const float*)d_in[19];
    const float* rc      = (const float*)d_in[20];
    const float* temps   = (const float*)d_in[21];

    float* ws = (float*)d_ws;
    const size_t NXD = (size_t)B_*T_*D_;           // 16777216
    float* Xn    = ws;
    float* XW0   = ws + NXD;
    float* sal   = ws + 2*NXD;                     // +16777216
    float* qpart = sal + (size_t)B_*T_*WIN_;       // +2097152
    float* qmean = qpart + (size_t)B_*8*D_;        // +65536
    float* snws  = qmean + (size_t)B_*D_;          // +8192
    float* kq    = snws + (size_t)B_*K_*DB_;       // +14336
    float* vg    = kq + (size_t)B_*K_*D_;          // +57344
    float* tv    = vg + (size_t)B_*K_*D_;          // +57344
    int*   ti    = (int*)(tv + 256);
    int*   tj    = (int*)(tv + 512);
    float* cv    = tv + 768;                       // B*64*16 = 16384
    int*   ci    = (int*)(cv + (size_t)B_*64*16);  // B*64*16 = 16384

    float* z_out     = (float*)d_out;
    float* slots_out = z_out + NXD;
    float* loss_out  = slots_out + (size_t)B_*K_*DB_;

    ln_kernel<<<dim3(B_*T_), dim3(256), 0, stream>>>(X_write, lnw_w, lnw_b, Xn);
    qmean_part_k<<<dim3(B_, 8), dim3(512), 0, stream>>>(X_read, qpart);
    qmean_final_k<<<dim3(B_), dim3(512), 0, stream>>>(qpart, qmean);
    gemm_xw0<<<dim3(B_*T_/64, D_/64), dim3(256), 0, stream>>>(Xn, W0, XW0);
    sal_kernel<<<dim3(B_, T_/64), dim3(256), 0, stream>>>(Xn, XW0, sal);
    topk_stage1<<<dim3(B_, 64), dim3(256), 0, stream>>>(sal, cv, ci);
    topk_stage2<<<dim3(B_), dim3(256), 0, stream>>>(cv, ci, ti, tj, tv);
    slot_kernel<<<dim3(B_), dim3(256), 0, stream>>>(Xn, slots, ti, tj, tv,
        W_V, W_K_slot, skb, Wg, Wgb, lns_w, lns_b, WsQ, WsK, WsV, lambda_, temps,
        snws, slots_out);
    loss_kernel<<<dim3(1), dim3(256), 0, stream>>>(snws, slots, loss_out);
    readprep_kernel<<<dim3(B_), dim3(256), 0, stream>>>(qmean, W0, snws, rc, WKr, WQr, WVr, kq, vg);
    z_kernel<<<dim3(B_, T_/64), dim3(256), 0, stream>>>(X_read, kq, vg, z_out);
}

// Round 3
// 516.512 us; speedup vs baseline: 2.5043x; 1.5829x over previous
//
#include <hip/hip_runtime.h>
#include <math.h>

#define B_ 16
#define T_ 2048
#define D_ 512
#define DB_ 128
#define K_ 7
#define TOPK_ 16
#define WIN_ 64

static constexpr float SCALE_ = 0.08838834764831845f;   // 128^-0.5
static constexpr float PHI_ = 1.618033988749895f;
static constexpr float PSI_ = -0.6180339887498949f;
static constexpr float INV_DENOM_ = 0.4472135954999579f; // 1/(PHI-PSI)
static constexpr float NEGV = -1e30f;
static constexpr float NEGINF = -3.402823466e38f;

typedef __attribute__((ext_vector_type(8))) __bf16 bf16x8;
typedef __attribute__((ext_vector_type(8))) unsigned short u16x8;
typedef __attribute__((ext_vector_type(4))) float f32x4;

__device__ inline float softplusf(float x){
    return fmaxf(x, 0.f) + log1pf(expf(-fabsf(x)));
}
__device__ inline unsigned short f2bf(float x){
    unsigned int u = __float_as_uint(x);
    unsigned int r = (u + 0x7FFFu + ((u >> 16) & 1u)) >> 16;
    return (unsigned short)r;
}
__device__ inline float bf2f(unsigned short h){
    return __uint_as_float(((unsigned int)h) << 16);
}
__device__ inline bf16x8 ld_bf8(const unsigned short* p){
    u16x8 r = *(const u16x8*)p;
    return __builtin_bit_cast(bf16x8, r);
}

// ---------------- LayerNorm of X_write -> Xn (bf16 hi/lo split) ----------------
__global__ __launch_bounds__(256) void ln_kernel(const float* __restrict__ X,
                                                 const float* __restrict__ w,
                                                 const float* __restrict__ b,
                                                 unsigned short* __restrict__ Xh,
                                                 unsigned short* __restrict__ Xl)
{
    int row = blockIdx.x;                 // 0..32767
    const float* x = X + (size_t)row * D_;
    float2 v = ((const float2*)x)[threadIdx.x];
    float s = v.x + v.y, ss = v.x*v.x + v.y*v.y;
    for (int off = 32; off; off >>= 1) { s += __shfl_down(s, off); ss += __shfl_down(ss, off); }
    __shared__ float sh[8];
    int wid = threadIdx.x >> 6, lane = threadIdx.x & 63;
    if (lane == 0) { sh[wid] = s; sh[4+wid] = ss; }
    __syncthreads();
    if (threadIdx.x == 0) {
        float S = sh[0]+sh[1]+sh[2]+sh[3], SS = sh[4]+sh[5]+sh[6]+sh[7];
        float mu = S / (float)D_;
        float var = SS / (float)D_ - mu*mu;
        sh[0] = mu; sh[1] = rsqrtf(var + 1e-5f);
    }
    __syncthreads();
    float mu = sh[0], rs = sh[1];
    float2 wv = ((const float2*)w)[threadIdx.x];
    float2 bv = ((const float2*)b)[threadIdx.x];
    float ox = (v.x - mu) * rs * wv.x + bv.x;
    float oy = (v.y - mu) * rs * wv.y + bv.y;
    unsigned short hx = f2bf(ox), hy = f2bf(oy);
    unsigned short lx = f2bf(ox - bf2f(hx)), ly = f2bf(oy - bf2f(hy));
    ((unsigned int*)(Xh + (size_t)row * D_))[threadIdx.x] = (unsigned int)hx | ((unsigned int)hy << 16);
    ((unsigned int*)(Xl + (size_t)row * D_))[threadIdx.x] = (unsigned int)lx | ((unsigned int)ly << 16);
}

// ---------------- W0 -> bf16 hi/lo ----------------
__global__ __launch_bounds__(256) void w0cvt_kernel(const float* __restrict__ W0,
                                                    unsigned short* __restrict__ Wh,
                                                    unsigned short* __restrict__ Wl)
{
    int gid = blockIdx.x * 256 + threadIdx.x;     // 65536 threads * 4 elems
    float4 v = ((const float4*)W0)[gid];
    unsigned short h0 = f2bf(v.x), h1 = f2bf(v.y), h2 = f2bf(v.z), h3 = f2bf(v.w);
    ushort4 hv = make_ushort4(h0, h1, h2, h3);
    ushort4 lv = make_ushort4(f2bf(v.x - bf2f(h0)), f2bf(v.y - bf2f(h1)),
                              f2bf(v.z - bf2f(h2)), f2bf(v.w - bf2f(h3)));
    *(ushort4*)&Wh[(size_t)gid*4] = hv;
    *(ushort4*)&Wl[(size_t)gid*4] = lv;
}

// ---------------- q_mean over T (two stage) ----------------
__global__ __launch_bounds__(512) void qmean_part_k(const float* __restrict__ Xr, float* __restrict__ part)
{
    int b = blockIdx.x, c = blockIdx.y, d = threadIdx.x;
    const float* base = Xr + ((size_t)b*T_ + (size_t)c*256) * D_ + d;
    float s = 0.f;
    for (int t = 0; t < 256; t++) s += base[(size_t)t * D_];
    part[((size_t)b*8 + c)*D_ + d] = s;
}

__global__ __launch_bounds__(512) void qmean_final_k(const float* __restrict__ part, float* __restrict__ qmean)
{
    int b = blockIdx.x, d = threadIdx.x;
    float s = 0.f;
    for (int c = 0; c < 8; c++) s += part[((size_t)b*8 + c)*D_ + d];
    qmean[(size_t)b*D_ + d] = s * (1.f/2048.f);
}

// ---------------- XW0 = Xn @ W0^T  (bf16x3 MFMA), output as bf16 hi/lo ----------------
// A[t][e] hi/lo, W[d][e] hi/lo (both K-contiguous). Tile 128x128, BK=32, 4 waves 2x2.
__global__ __launch_bounds__(256) void gemm_xw0_mfma(const unsigned short* __restrict__ Ah,
                                                     const unsigned short* __restrict__ Al,
                                                     const unsigned short* __restrict__ Wh,
                                                     const unsigned short* __restrict__ Wl,
                                                     unsigned short* __restrict__ Ch,
                                                     unsigned short* __restrict__ Cl)
{
    __shared__ unsigned short sAh[128*40], sAl[128*40], sBh[128*40], sBl[128*40];
    int t0 = blockIdx.x * 128, d0 = blockIdx.y * 128;
    int tid = threadIdx.x;
    int lane = tid & 63, wid = tid >> 6;
    int wr = wid >> 1, wc = wid & 1;
    int fr = lane & 15, kc = (lane >> 4) * 8;

    f32x4 acc[4][4];
    #pragma unroll
    for (int m = 0; m < 4; m++)
        #pragma unroll
        for (int n = 0; n < 4; n++) acc[m][n] = (f32x4){0.f,0.f,0.f,0.f};

    int srow = tid >> 1, skh = (tid & 1) * 16;

    for (int kk = 0; kk < 512; kk += 32) {
        const unsigned short* gAh = Ah + (size_t)(t0 + srow)*512 + kk + skh;
        const unsigned short* gAl = Al + (size_t)(t0 + srow)*512 + kk + skh;
        const unsigned short* gWh = Wh + (size_t)(d0 + srow)*512 + kk + skh;
        const unsigned short* gWl = Wl + (size_t)(d0 + srow)*512 + kk + skh;
        int so = srow*40 + skh;
        *(uint4*)&sAh[so]     = *(const uint4*)(gAh);
        *(uint4*)&sAh[so + 8] = *(const uint4*)(gAh + 8);
        *(uint4*)&sAl[so]     = *(const uint4*)(gAl);
        *(uint4*)&sAl[so + 8] = *(const uint4*)(gAl + 8);
        *(uint4*)&sBh[so]     = *(const uint4*)(gWh);
        *(uint4*)&sBh[so + 8] = *(const uint4*)(gWh + 8);
        *(uint4*)&sBl[so]     = *(const uint4*)(gWl);
        *(uint4*)&sBl[so + 8] = *(const uint4*)(gWl + 8);
        __syncthreads();

        bf16x8 ah[4], al[4], bh[4], bl[4];
        #pragma unroll
        for (int m = 0; m < 4; m++) {
            int r = (wr*64 + m*16 + fr)*40 + kc;
            ah[m] = ld_bf8(&sAh[r]);
            al[m] = ld_bf8(&sAl[r]);
        }
        #pragma unroll
        for (int n = 0; n < 4; n++) {
            int r = (wc*64 + n*16 + fr)*40 + kc;
            bh[n] = ld_bf8(&sBh[r]);
            bl[n] = ld_bf8(&sBl[r]);
        }
        #pragma unroll
        for (int m = 0; m < 4; m++)
            #pragma unroll
            for (int n = 0; n < 4; n++) {
                acc[m][n] = __builtin_amdgcn_mfma_f32_16x16x32_bf16(ah[m], bh[n], acc[m][n], 0, 0, 0);
                acc[m][n] = __builtin_amdgcn_mfma_f32_16x16x32_bf16(ah[m], bl[n], acc[m][n], 0, 0, 0);
                acc[m][n] = __builtin_amdgcn_mfma_f32_16x16x32_bf16(al[m], bh[n], acc[m][n], 0, 0, 0);
            }
        __syncthreads();
    }

    #pragma unroll
    for (int m = 0; m < 4; m++) {
        int row = t0 + wr*64 + m*16 + (lane >> 4)*4;
        #pragma unroll
        for (int n = 0; n < 4; n++) {
            int col = d0 + wc*64 + n*16 + fr;
            #pragma unroll
            for (int r = 0; r < 4; r++) {
                float v = acc[m][n][r];
                unsigned short hi = f2bf(v);
                unsigned short lo = f2bf(v - bf2f(hi));
                Ch[(size_t)(row + r)*512 + col] = hi;
                Cl[(size_t)(row + r)*512 + col] = lo;
            }
        }
    }
}

// ---------------- sal (banded) via bf16x3 MFMA ----------------
// Per block: rows i0..i0+63 of Xn vs rows i0-64..i0+63 of XW0. 4 waves by column.
__global__ __launch_bounds__(256) void sal_mfma(const unsigned short* __restrict__ Xh,
                                                const unsigned short* __restrict__ Xl,
                                                const unsigned short* __restrict__ Wh,
                                                const unsigned short* __restrict__ Wl,
                                                float* __restrict__ sal)
{
    int b = blockIdx.x, i0 = blockIdx.y * 64;
    __shared__ unsigned short sAh[64*40], sAl[64*40], sBh[128*40], sBl[128*40];
    int tid = threadIdx.x;
    int lane = tid & 63, wc = tid >> 6;
    int fr = lane & 15, kc = (lane >> 4) * 8;

    const unsigned short* XhB = Xh + (size_t)b*T_*D_;
    const unsigned short* XlB = Xl + (size_t)b*T_*D_;
    const unsigned short* WhB = Wh + (size_t)b*T_*D_;
    const unsigned short* WlB = Wl + (size_t)b*T_*D_;

    f32x4 acc[4][2];
    #pragma unroll
    for (int m = 0; m < 4; m++) { acc[m][0] = (f32x4){0.f,0.f,0.f,0.f}; acc[m][1] = (f32x4){0.f,0.f,0.f,0.f}; }

    int arow = tid >> 2, akh = (tid & 3) * 8;
    int brow = tid >> 1, bkh = (tid & 1) * 16;
    int jrow = i0 - 64 + brow;
    const uint4 z4 = make_uint4(0,0,0,0);

    for (int kk = 0; kk < 512; kk += 32) {
        *(uint4*)&sAh[arow*40 + akh] = *(const uint4*)(XhB + (size_t)(i0 + arow)*512 + kk + akh);
        *(uint4*)&sAl[arow*40 + akh] = *(const uint4*)(XlB + (size_t)(i0 + arow)*512 + kk + akh);
        int bo = brow*40 + bkh;
        if (jrow >= 0) {
            const unsigned short* gh = WhB + (size_t)jrow*512 + kk + bkh;
            const unsigned short* gl = WlB + (size_t)jrow*512 + kk + bkh;
            *(uint4*)&sBh[bo]     = *(const uint4*)(gh);
            *(uint4*)&sBh[bo + 8] = *(const uint4*)(gh + 8);
            *(uint4*)&sBl[bo]     = *(const uint4*)(gl);
            *(uint4*)&sBl[bo + 8] = *(const uint4*)(gl + 8);
        } else {
            *(uint4*)&sBh[bo] = z4; *(uint4*)&sBh[bo + 8] = z4;
            *(uint4*)&sBl[bo] = z4; *(uint4*)&sBl[bo + 8] = z4;
        }
        __syncthreads();

        bf16x8 ah[4], al[4], bh[2], bl[2];
        #pragma unroll
        for (int m = 0; m < 4; m++) {
            int r = (m*16 + fr)*40 + kc;
            ah[m] = ld_bf8(&sAh[r]);
            al[m] = ld_bf8(&sAl[r]);
        }
        #pragma unroll
        for (int n = 0; n < 2; n++) {
            int r = (wc*32 + n*16 + fr)*40 + kc;
            bh[n] = ld_bf8(&sBh[r]);
            bl[n] = ld_bf8(&sBl[r]);
        }
        #pragma unroll
        for (int m = 0; m < 4; m++)
            #pragma unroll
            for (int n = 0; n < 2; n++) {
                acc[m][n] = __builtin_amdgcn_mfma_f32_16x16x32_bf16(ah[m], bh[n], acc[m][n], 0, 0, 0);
                acc[m][n] = __builtin_amdgcn_mfma_f32_16x16x32_bf16(ah[m], bl[n], acc[m][n], 0, 0, 0);
                acc[m][n] = __builtin_amdgcn_mfma_f32_16x16x32_bf16(al[m], bh[n], acc[m][n], 0, 0, 0);
            }
        __syncthreads();
    }

    float* salB = sal + (size_t)b*T_*WIN_;
    #pragma unroll
    for (int m = 0; m < 4; m++) {
        #pragma unroll
        for (int n = 0; n < 2; n++) {
            int jl = wc*32 + n*16 + fr;
            #pragma unroll
            for (int r = 0; r < 4; r++) {
                int il = m*16 + (lane >> 4)*4 + r;
                int o = il - jl + 64;
                if (o >= 1 && o <= 64) {
                    int jg = i0 - 64 + jl;
                    salB[(size_t)(i0 + il)*WIN_ + (o - 1)] = (jg >= 0) ? acc[m][n][r] : NEGV;
                }
            }
        }
    }
}

// ---------------- top-16: stage 1, per (batch, chunk) local top-16 ----------------
__global__ __launch_bounds__(256) void topk_stage1(const float* __restrict__ sal,
                                                   float* __restrict__ cv, int* __restrict__ ci)
{
    int b = blockIdx.x, c = blockIdx.y;
    const float* s = sal + (size_t)b*(T_*WIN_) + (size_t)c*2048;
    int base = c*2048;
    int tid = threadIdx.x;
    float lv[8]; int li[8];
    #pragma unroll
    for (int k = 0; k < 8; k++) { lv[k] = NEGINF; li[k] = 0x7FFFFFFF; }
    #pragma unroll
    for (int r = 0; r < 8; r++) {
        int p = tid + r*256;
        float v = s[p];
        int idx = base + p;
        if (v > lv[7]) {
            int k = 7;
            while (k > 0 && lv[k-1] < v) { lv[k] = lv[k-1]; li[k] = li[k-1]; k--; }
            lv[k] = v; li[k] = idx;
        }
    }
    __shared__ float rv[256]; __shared__ int ri[256]; __shared__ int rt[256];
    int head = 0;
    float* cvo = cv + ((size_t)b*64 + c)*16;
    int*   cio = ci + ((size_t)b*64 + c)*16;
    for (int r = 0; r < 16; r++) {
        float bv2 = (head < 8) ? lv[head] : NEGINF;
        int   bi2 = (head < 8) ? li[head] : 0x7FFFFFFF;
        rv[tid] = bv2; ri[tid] = bi2; rt[tid] = tid;
        __syncthreads();
        for (int st = 128; st > 0; st >>= 1) {
            if (tid < st) {
                float v2 = rv[tid+st]; int i2 = ri[tid+st];
                if (v2 > rv[tid] || (v2 == rv[tid] && i2 < ri[tid])) {
                    rv[tid] = v2; ri[tid] = i2; rt[tid] = rt[tid+st];
                }
            }
            __syncthreads();
        }
        if (rt[0] == tid) head++;
        if (tid == 0) { cvo[r] = rv[0]; cio[r] = ri[0]; }
        __syncthreads();
    }
}

// ---------------- top-16: stage 2, merge 64*16 candidates per batch ----------------
__global__ __launch_bounds__(256) void topk_stage2(const float* __restrict__ cv,
                                                   const int* __restrict__ ci,
                                                   int* __restrict__ ti, int* __restrict__ tj,
                                                   float* __restrict__ tv)
{
    int b = blockIdx.x, tid = threadIdx.x;
    const float* cvb = cv + (size_t)b*1024;
    const int*   cib = ci + (size_t)b*1024;
    float lv[4]; int li[4];
    #pragma unroll
    for (int k = 0; k < 4; k++) { lv[k] = NEGINF; li[k] = 0x7FFFFFFF; }
    #pragma unroll
    for (int r = 0; r < 4; r++) {
        int p = tid + r*256;
        float v = cvb[p];
        int idx = cib[p];
        if (v > lv[3] || (v == lv[3] && idx < li[3])) {
            int k = 3;
            while (k > 0 && (lv[k-1] < v || (lv[k-1] == v && li[k-1] > idx))) {
                lv[k] = lv[k-1]; li[k] = li[k-1]; k--;
            }
            lv[k] = v; li[k] = idx;
        }
    }
    __shared__ float rv[256]; __shared__ int ri[256]; __shared__ int rt[256];
    int head = 0;
    for (int r = 0; r < 16; r++) {
        float bv2 = (head < 4) ? lv[head] : NEGINF;
        int   bi2 = (head < 4) ? li[head] : 0x7FFFFFFF;
        rv[tid] = bv2; ri[tid] = bi2; rt[tid] = tid;
        __syncthreads();
        for (int st = 128; st > 0; st >>= 1) {
            if (tid < st) {
                float v2 = rv[tid+st]; int i2 = ri[tid+st];
                if (v2 > rv[tid] || (v2 == rv[tid] && i2 < ri[tid])) {
                    rv[tid] = v2; ri[tid] = i2; rt[tid] = rt[tid+st];
                }
            }
            __syncthreads();
        }
        if (rt[0] == tid) head++;
        if (tid == 0) {
            int flat = ri[0];
            int i = flat >> 6;
            int o = (flat & 63) + 1;
            ti[b*16+r] = i;
            tj[b*16+r] = i - o;
            tv[b*16+r] = rv[0];
        }
        __syncthreads();
    }
}

// ---------------- slot pipeline (per batch) ----------------
__global__ __launch_bounds__(256) void slot_kernel(
    const unsigned short* __restrict__ Xh, const unsigned short* __restrict__ Xl,
    const float* __restrict__ slots_in,
    const int* __restrict__ ti, const int* __restrict__ tj, const float* __restrict__ tv,
    const float* __restrict__ W_V, const float* __restrict__ W_K_slot, const float* __restrict__ skb,
    const float* __restrict__ Wg, const float* __restrict__ Wgb,
    const float* __restrict__ lnw, const float* __restrict__ lnb,
    const float* __restrict__ WsQ, const float* __restrict__ WsK, const float* __restrict__ WsV,
    const float* __restrict__ lambda_, const float* __restrict__ temps,
    float* __restrict__ snws, float* __restrict__ out_slots)
{
    int b = blockIdx.x, tid = threadIdx.x;
    __shared__ float alpha[16];
    __shared__ float y[D_];
    __shared__ float Rt[DB_];
    __shared__ float sl[K_][DB_];
    __shared__ float skv[K_][DB_];
    __shared__ float wR[K_][DB_];
    __shared__ float upd[K_][DB_];
    __shared__ float Bn[K_][DB_];
    __shared__ float qq[K_][DB_], kk2[K_][DB_], vv[K_][DB_];
    __shared__ float swv[K_], compat[K_], mu7[K_], rs7[K_];
    __shared__ float sa[K_][K_];

    if (tid == 0) {
        float m = NEGINF;
        for (int k = 0; k < 16; k++) m = fmaxf(m, tv[b*16+k]);
        float ssum = 0.f;
        for (int k = 0; k < 16; k++) { float e = expf(tv[b*16+k] - m); alpha[k] = e; ssum += e; }
        for (int k = 0; k < 16; k++) alpha[k] /= ssum;
    }
    for (int p = tid; p < K_*DB_; p += 256) sl[p>>7][p&127] = slots_in[(size_t)b*K_*DB_ + p];
    __syncthreads();

    for (int e = tid; e < D_; e += 256) {
        float acc = 0.f;
        for (int k = 0; k < 16; k++) {
            int i = ti[b*16+k], j = tj[b*16+k];
            float xi = bf2f(Xh[((size_t)b*T_ + i)*D_ + e]) + bf2f(Xl[((size_t)b*T_ + i)*D_ + e]);
            float xj = bf2f(Xh[((size_t)b*T_ + j)*D_ + e]) + bf2f(Xl[((size_t)b*T_ + j)*D_ + e]);
            acc += alpha[k] * (xi - xj);
        }
        y[e] = acc;
    }
    __syncthreads();
    if (tid < DB_) {
        float acc = 0.f;
        for (int e = 0; e < D_; e++) acc += y[e] * W_V[(size_t)e*DB_ + tid];
        Rt[tid] = acc;
    }
    __syncthreads();
    if (tid < DB_) {
        int d = tid;
        for (int k = 0; k < K_; k++) {
            float acc = skb[k*DB_ + d];
            for (int e = 0; e < DB_; e++) acc += sl[k][e] * W_K_slot[(size_t)e*DB_ + d];
            skv[k][d] = acc * Rt[d];
        }
    }
    __syncthreads();
    if (tid < K_) {
        float a = 0.f;
        for (int d = 0; d < DB_; d++) a += skv[tid][d];
        compat[tid] = a * SCALE_ * softplusf(temps[tid]);
    }
    __syncthreads();
    if (tid == 0) {
        float m = compat[0];
        for (int k = 1; k < K_; k++) m = fmaxf(m, compat[k]);
        float ssum = 0.f;
        for (int k = 0; k < K_; k++) { float e = expf(compat[k]-m); swv[k] = e; ssum += e; }
        for (int k = 0; k < K_; k++) swv[k] /= ssum;
    }
    __syncthreads();
    for (int p = tid; p < K_*DB_; p += 256) wR[p>>7][p&127] = swv[p>>7] * Rt[p&127];
    __syncthreads();
    if (tid < DB_) {
        int d = tid;
        for (int k = 0; k < K_; k++) {
            float acc = Wgb[d];
            for (int e = 0; e < DB_; e++) acc += sl[k][e] * Wg[(size_t)e*DB_ + d];
            for (int e = 0; e < DB_; e++) acc += wR[k][e] * Wg[(size_t)(DB_+e)*DB_ + d];
            float g = 1.f / (1.f + expf(-acc));
            upd[k][d] = (1.f - g) * sl[k][d] + g * wR[k][d];
        }
    }
    __syncthreads();
    if (tid < K_) {
        float s = 0.f, ss = 0.f;
        for (int d = 0; d < DB_; d++) { float v = upd[tid][d]; s += v; ss += v*v; }
        float mu = s / (float)DB_;
        mu7[tid] = mu;
        rs7[tid] = rsqrtf(ss/(float)DB_ - mu*mu + 1e-5f);
    }
    __syncthreads();
    for (int p = tid; p < K_*DB_; p += 256) {
        int k = p>>7, d = p&127;
        Bn[k][d] = (upd[k][d] - mu7[k]) * rs7[k] * lnw[d] + lnb[d];
    }
    __syncthreads();
    if (tid < DB_) {
        int d = tid;
        for (int k = 0; k < K_; k++) {
            float aq = 0.f, ak = 0.f, av = 0.f;
            for (int e = 0; e < DB_; e++) {
                float bn = Bn[k][e];
                aq += bn * WsQ[(size_t)e*DB_ + d];
                ak += bn * WsK[(size_t)e*DB_ + d];
                av += bn * WsV[(size_t)e*DB_ + d];
            }
            qq[k][d] = aq; kk2[k][d] = ak; vv[k][d] = av;
        }
    }
    __syncthreads();
    if (tid < K_*K_) {
        int q = tid / K_, j = tid % K_;
        float a = 0.f;
        for (int e = 0; e < DB_; e++) a += qq[q][e] * kk2[j][e];
        sa[q][j] = a * SCALE_;
    }
    __syncthreads();
    if (tid < K_) {
        float m = sa[tid][0];
        for (int j = 1; j < K_; j++) m = fmaxf(m, sa[tid][j]);
        float ssum = 0.f;
        for (int j = 0; j < K_; j++) { float e = expf(sa[tid][j]-m); sa[tid][j] = e; ssum += e; }
        for (int j = 0; j < K_; j++) sa[tid][j] /= ssum;
    }
    __syncthreads();
    if (tid < DB_) {
        int d = tid;
        float lam = tanhf(lambda_[d]);
        lam = fminf(fmaxf(lam, -0.5f), 0.5f);
        for (int k = 0; k < K_; k++) {
            float c = 0.f;
            for (int j = 0; j < K_; j++) c += sa[k][j] * vv[j][d];
            float sn = upd[k][d] + c * lam;
            snws[((size_t)b*K_ + k)*DB_ + d] = sn;
            out_slots[((size_t)b*K_ + k)*DB_ + d] = sn;
        }
    }
}

// ---------------- losses ----------------
__global__ __launch_bounds__(256) void loss_kernel(const float* __restrict__ sn,
                                                   const float* __restrict__ sl0,
                                                   float* __restrict__ out)
{
    __shared__ float sh[8];
    __shared__ float nrm[B_*K_];
    float acc = 0.f;
    for (int p = threadIdx.x; p < B_*K_*DB_; p += 256) { float d = sn[p] - sl0[p]; acc += d*d; }
    for (int off = 32; off; off >>= 1) acc += __shfl_down(acc, off);
    int lane = threadIdx.x & 63, w = threadIdx.x >> 6;
    if (lane == 0) sh[w] = acc;
    __syncthreads();
    if (threadIdx.x == 0) out[0] = (sh[0]+sh[1]+sh[2]+sh[3]) / (float)(B_*K_*DB_);
    if (threadIdx.x < B_*K_) {
        float s = 0.f;
        const float* a = sn + (size_t)threadIdx.x * DB_;
        for (int d = 0; d < DB_; d++) s += a[d]*a[d];
        nrm[threadIdx.x] = fmaxf(sqrtf(s), 1e-12f);
    }
    __syncthreads();
    float acc2 = 0.f;
    for (int p = threadIdx.x; p < B_*K_*K_; p += 256) {
        int bb = p / (K_*K_), r = p % (K_*K_), q = r / K_, j = r % K_;
        if (q != j) {
            const float* a = sn + ((size_t)bb*K_ + q)*DB_;
            const float* c = sn + ((size_t)bb*K_ + j)*DB_;
            float dot = 0.f;
            for (int d = 0; d < DB_; d++) dot += a[d]*c[d];
            float cs = dot / (nrm[bb*K_+q] * nrm[bb*K_+j]);
            acc2 += cs*cs;
        }
    }
    for (int off = 32; off; off >>= 1) acc2 += __shfl_down(acc2, off);
    __syncthreads();
    if (lane == 0) sh[w] = acc2;
    __syncthreads();
    if (threadIdx.x == 0) out[1] = (sh[0]+sh[1]+sh[2]+sh[3]) / (float)(B_*(K_*K_-K_));
}

// ---------------- read prep ----------------
__global__ __launch_bounds__(256) void readprep_kernel(
    const float* __restrict__ qmean, const float* __restrict__ W0, const float* __restrict__ sn,
    const float* __restrict__ rc, const float* __restrict__ WKr, const float* __restrict__ WQr,
    const float* __restrict__ WVr, float* __restrict__ kq, float* __restrict__ vg)
{
    int b = blockIdx.x, tid = threadIdx.x;
    __shared__ float qm[D_];
    __shared__ float sl[K_][DB_];
    __shared__ float kr[K_][DB_];
    __shared__ float rsh[8];
    __shared__ float bas1s, bas2s;
    for (int p = tid; p < D_; p += 256) qm[p] = qmean[(size_t)b*D_ + p];
    for (int p = tid; p < K_*DB_; p += 256) sl[p>>7][p&127] = sn[(size_t)b*K_*DB_ + p];
    __syncthreads();
    float ph = 0.f, ps = 0.f;
    for (int d = tid; d < D_; d += 256) {
        float w0q = 0.f;
        const float* wr = W0 + (size_t)d*D_;
        for (int e = 0; e < D_; e++) w0q += qm[e] * wr[e];
        float phi = (w0q - PSI_*qm[d]) * INV_DENOM_;
        float psi = (PHI_*qm[d] - w0q) * INV_DENOM_;
        ph += phi*phi; ps += psi*psi;
    }
    for (int off = 32; off; off >>= 1) { ph += __shfl_down(ph, off); ps += __shfl_down(ps, off); }
    int lane = tid & 63, w = tid >> 6;
    if (lane == 0) { rsh[w] = ph; rsh[4+w] = ps; }
    __syncthreads();
    if (tid == 0) {
        float P = rsh[0]+rsh[1]+rsh[2]+rsh[3], Q = rsh[4]+rsh[5]+rsh[6]+rsh[7];
        float pm = sqrtf(P), qmag = sqrtf(Q);
        float tot = pm + qmag + 1e-6f;
        bas1s = pm / tot; bas2s = qmag / tot;
    }
    __syncthreads();
    float b1 = bas1s, b2 = bas2s;
    if (tid < DB_) {
        int d = tid;
        for (int k = 0; k < K_; k++) {
            float a = 0.f;
            for (int e = 0; e < DB_; e++) a += sl[k][e] * WKr[(size_t)e*DB_ + d];
            kr[k][d] = a;
        }
    }
    __syncthreads();
    for (int p = tid; p < K_*D_; p += 256) {
        int k = p >> 9, e = p & 511;
        float a = 0.f;
        const float* wq = WQr + (size_t)e*DB_;
        for (int d = 0; d < DB_; d++) a += kr[k][d] * wq[d];
        kq[((size_t)b*K_ + k)*D_ + e] = a;
    }
    for (int p = tid; p < K_*D_; p += 256) {
        int k = p >> 9, dd = p & 511;
        float a = 0.f;
        for (int e = 0; e < DB_; e++) a += sl[k][e] * WVr[(size_t)e*D_ + dd];
        float gpre = rc[((size_t)k*3 + 0)*D_ + dd] + b1*rc[((size_t)k*3 + 1)*D_ + dd] + b2*rc[((size_t)k*3 + 2)*D_ + dd];
        float g = tanhf(gpre);
        g = fminf(fmaxf(g, -0.5f), 0.5f);
        vg[((size_t)b*K_ + k)*D_ + dd] = a * g;
    }
}

// ---------------- z: softmax over 7 slots + weighted combine ----------------
__global__ __launch_bounds__(256) void z_kernel(const float* __restrict__ Xr,
                                                const float* __restrict__ kq,
                                                const float* __restrict__ vg,
                                                float* __restrict__ z)
{
    int b = blockIdx.x;
    int t0 = blockIdx.y * 64;
    __shared__ float kqs[K_][D_];
    __shared__ float vgs[K_][D_];
    int tid = threadIdx.x;
    for (int p = tid; p < K_*D_; p += 256) {
        kqs[p>>9][p&511] = kq[(size_t)b*K_*D_ + p];
        vgs[p>>9][p&511] = vg[(size_t)b*K_*D_ + p];
    }
    __syncthreads();
    int lane = tid & 63, w = tid >> 6;
    for (int it = 0; it < 16; it++) {
        int t = t0 + w*16 + it;
        const float* x = Xr + ((size_t)b*T_ + t)*D_;
        float xr[8];
        float s[K_] = {0,0,0,0,0,0,0};
        #pragma unroll
        for (int r = 0; r < 8; r++) {
            int e = lane + r*64;
            xr[r] = x[e];
            #pragma unroll
            for (int k = 0; k < K_; k++) s[k] += xr[r] * kqs[k][e];
        }
        #pragma unroll
        for (int k = 0; k < K_; k++)
            for (int off = 32; off; off >>= 1) s[k] += __shfl_xor(s[k], off);
        float sc[K_];
        float m = NEGINF;
        #pragma unroll
        for (int k = 0; k < K_; k++) { sc[k] = s[k] * SCALE_; m = fmaxf(m, sc[k]); }
        float p[K_], ssum = 0.f;
        #pragma unroll
        for (int k = 0; k < K_; k++) { p[k] = expf(sc[k] - m); ssum += p[k]; }
        float inv = 1.f / ssum;
        float* zp = z + ((size_t)b*T_ + t)*D_;
        #pragma unroll
        for (int r = 0; r < 8; r++) {
            int e = lane + r*64;
            float a = 0.f;
            #pragma unroll
            for (int k = 0; k < K_; k++) a += p[k] * vgs[k][e];
            zp[e] = a * inv;
        }
    }
}

extern "C" void kernel_launch(void* const* d_in, const int* in_sizes, int n_in,
                              void* d_out, int out_size, void* d_ws, size_t ws_size,
                              hipStream_t stream)
{
    const float* X_write = (const float*)d_in[0];
    const float* X_read  = (const float*)d_in[1];
    const float* slots   = (const float*)d_in[2];
    const float* W0      = (const float*)d_in[3];
    const float* lnw_w   = (const float*)d_in[4];
    const float* lnw_b   = (const float*)d_in[5];
    const float* W_V     = (const float*)d_in[6];
    const float* W_K_slot= (const float*)d_in[7];
    const float* skb     = (const float*)d_in[8];
    const float* Wg      = (const float*)d_in[9];
    const float* Wgb     = (const float*)d_in[10];
    const float* lns_w   = (const float*)d_in[11];
    const float* lns_b   = (const float*)d_in[12];
    const float* WsQ     = (const float*)d_in[13];
    const float* WsK     = (const float*)d_in[14];
    const float* WsV     = (const float*)d_in[15];
    const float* lambda_ = (const float*)d_in[16];
    const float* WQr     = (const float*)d_in[17];
    const float* WKr     = (const float*)d_in[18];
    const float* WVr     = (const float*)d_in[19];
    const float* rc      = (const float*)d_in[20];
    const float* temps   = (const float*)d_in[21];

    const size_t NXD = (size_t)B_*T_*D_;           // 16777216
    unsigned short* Xh  = (unsigned short*)d_ws;
    unsigned short* Xl  = Xh + NXD;
    unsigned short* Ch  = Xl + NXD;                // XW0 hi
    unsigned short* Cl  = Ch + NXD;                // XW0 lo
    unsigned short* W0h = Cl + NXD;                // 262144
    unsigned short* W0l = W0h + (size_t)D_*D_;
    float* fscr  = (float*)(W0l + (size_t)D_*D_);
    float* qpart = fscr;                           // B*8*D = 65536
    float* qmean = qpart + (size_t)B_*8*D_;        // 8192
    float* snws  = qmean + (size_t)B_*D_;          // 14336
    float* kq    = snws + (size_t)B_*K_*DB_;       // 57344
    float* vg    = kq + (size_t)B_*K_*D_;          // 57344
    float* tv    = vg + (size_t)B_*K_*D_;          // 256
    int*   ti    = (int*)(tv + 256);
    int*   tj    = (int*)(tv + 512);
    float* cv    = tv + 768;                       // B*64*16 = 16384
    int*   ci    = (int*)(cv + (size_t)B_*64*16);  // 16384

    float* z_out     = (float*)d_out;
    float* slots_out = z_out + NXD;
    float* loss_out  = slots_out + (size_t)B_*K_*DB_;
    float* sal       = z_out;    // scratch inside z region; consumed before z_kernel writes

    ln_kernel<<<dim3(B_*T_), dim3(256), 0, stream>>>(X_write, lnw_w, lnw_b, Xh, Xl);
    w0cvt_kernel<<<dim3(256), dim3(256), 0, stream>>>(W0, W0h, W0l);
    qmean_part_k<<<dim3(B_, 8), dim3(512), 0, stream>>>(X_read, qpart);
    qmean_final_k<<<dim3(B_), dim3(512), 0, stream>>>(qpart, qmean);
    gemm_xw0_mfma<<<dim3(B_*T_/128, D_/128), dim3(256), 0, stream>>>(Xh, Xl, W0h, W0l, Ch, Cl);
    sal_mfma<<<dim3(B_, T_/64), dim3(256), 0, stream>>>(Xh, Xl, Ch, Cl, sal);
    topk_stage1<<<dim3(B_, 64), dim3(256), 0, stream>>>(sal, cv, ci);
    topk_stage2<<<dim3(B_), dim3(256), 0, stream>>>(cv, ci, ti, tj, tv);
    slot_kernel<<<dim3(B_), dim3(256), 0, stream>>>(Xh, Xl, slots, ti, tj, tv,
        W_V, W_K_slot, skb, Wg, Wgb, lns_w, lns_b, WsQ, WsK, WsV, lambda_, temps,
        snws, slots_out);
    loss_kernel<<<dim3(1), dim3(256), 0, stream>>>(snws, slots, loss_out);
    readprep_kernel<<<dim3(B_), dim3(256), 0, stream>>>(qmean, W0, snws, rc, WKr, WQr, WVr, kq, vg);
    z_kernel<<<dim3(B_, T_/64), dim3(256), 0, stream>>>(X_read, kq, vg, z_out);
}

// Round 4
// 419.346 us; speedup vs baseline: 3.0846x; 1.2317x over previous
//
#include <hip/hip_runtime.h>
#include <math.h>

#define B_ 16
#define T_ 2048
#define D_ 512
#define DB_ 128
#define K_ 7
#define TOPK_ 16
#define WIN_ 64

static constexpr float SCALE_ = 0.08838834764831845f;   // 128^-0.5
static constexpr float PHI_ = 1.618033988749895f;
static constexpr float PSI_ = -0.6180339887498949f;
static constexpr float INV_DENOM_ = 0.4472135954999579f; // 1/(PHI-PSI)
static constexpr float NEGV = -1e30f;
static constexpr float NEGINF = -3.402823466e38f;

typedef __attribute__((ext_vector_type(8))) __bf16 bf16x8;
typedef __attribute__((ext_vector_type(8))) unsigned short u16x8;
typedef __attribute__((ext_vector_type(4))) float f32x4;

__device__ inline float softplusf(float x){
    return fmaxf(x, 0.f) + log1pf(expf(-fabsf(x)));
}
__device__ inline unsigned short f2bf(float x){
    unsigned int u = __float_as_uint(x);
    unsigned int r = (u + 0x7FFFu + ((u >> 16) & 1u)) >> 16;
    return (unsigned short)r;
}
__device__ inline float bf2f(unsigned short h){
    return __uint_as_float(((unsigned int)h) << 16);
}
__device__ inline bf16x8 ld_bf8(const unsigned short* p){
    u16x8 r = *(const u16x8*)p;
    return __builtin_bit_cast(bf16x8, r);
}

// ---------------- LayerNorm of X_write -> Xn (bf16 hi/lo split) ----------------
__global__ __launch_bounds__(256) void ln_kernel(const float* __restrict__ X,
                                                 const float* __restrict__ w,
                                                 const float* __restrict__ b,
                                                 unsigned short* __restrict__ Xh,
                                                 unsigned short* __restrict__ Xl)
{
    int row = blockIdx.x;                 // 0..32767
    const float* x = X + (size_t)row * D_;
    float2 v = ((const float2*)x)[threadIdx.x];
    float s = v.x + v.y, ss = v.x*v.x + v.y*v.y;
    for (int off = 32; off; off >>= 1) { s += __shfl_down(s, off); ss += __shfl_down(ss, off); }
    __shared__ float sh[8];
    int wid = threadIdx.x >> 6, lane = threadIdx.x & 63;
    if (lane == 0) { sh[wid] = s; sh[4+wid] = ss; }
    __syncthreads();
    if (threadIdx.x == 0) {
        float S = sh[0]+sh[1]+sh[2]+sh[3], SS = sh[4]+sh[5]+sh[6]+sh[7];
        float mu = S / (float)D_;
        float var = SS / (float)D_ - mu*mu;
        sh[0] = mu; sh[1] = rsqrtf(var + 1e-5f);
    }
    __syncthreads();
    float mu = sh[0], rs = sh[1];
    float2 wv = ((const float2*)w)[threadIdx.x];
    float2 bv = ((const float2*)b)[threadIdx.x];
    float ox = (v.x - mu) * rs * wv.x + bv.x;
    float oy = (v.y - mu) * rs * wv.y + bv.y;
    unsigned short hx = f2bf(ox), hy = f2bf(oy);
    unsigned short lx = f2bf(ox - bf2f(hx)), ly = f2bf(oy - bf2f(hy));
    ((unsigned int*)(Xh + (size_t)row * D_))[threadIdx.x] = (unsigned int)hx | ((unsigned int)hy << 16);
    ((unsigned int*)(Xl + (size_t)row * D_))[threadIdx.x] = (unsigned int)lx | ((unsigned int)ly << 16);
}

// ---------------- W0 -> bf16 hi/lo ----------------
__global__ __launch_bounds__(256) void w0cvt_kernel(const float* __restrict__ W0,
                                                    unsigned short* __restrict__ Wh,
                                                    unsigned short* __restrict__ Wl)
{
    int gid = blockIdx.x * 256 + threadIdx.x;     // 65536 threads * 4 elems
    float4 v = ((const float4*)W0)[gid];
    unsigned short h0 = f2bf(v.x), h1 = f2bf(v.y), h2 = f2bf(v.z), h3 = f2bf(v.w);
    ushort4 hv = make_ushort4(h0, h1, h2, h3);
    ushort4 lv = make_ushort4(f2bf(v.x - bf2f(h0)), f2bf(v.y - bf2f(h1)),
                              f2bf(v.z - bf2f(h2)), f2bf(v.w - bf2f(h3)));
    *(ushort4*)&Wh[(size_t)gid*4] = hv;
    *(ushort4*)&Wl[(size_t)gid*4] = lv;
}

// ---------------- q_mean over T (two stage) ----------------
__global__ __launch_bounds__(512) void qmean_part_k(const float* __restrict__ Xr, float* __restrict__ part)
{
    int b = blockIdx.x, c = blockIdx.y, d = threadIdx.x;
    const float* base = Xr + ((size_t)b*T_ + (size_t)c*256) * D_ + d;
    float s = 0.f;
    for (int t = 0; t < 256; t++) s += base[(size_t)t * D_];
    part[((size_t)b*8 + c)*D_ + d] = s;
}

__global__ __launch_bounds__(512) void qmean_final_k(const float* __restrict__ part, float* __restrict__ qmean)
{
    int b = blockIdx.x, d = threadIdx.x;
    float s = 0.f;
    for (int c = 0; c < 8; c++) s += part[((size_t)b*8 + c)*D_ + d];
    qmean[(size_t)b*D_ + d] = s * (1.f/2048.f);
}

// ---------------- XW0 = Xn @ W0^T  (bf16x3 MFMA), output as bf16 hi/lo ----------------
__global__ __launch_bounds__(256) void gemm_xw0_mfma(const unsigned short* __restrict__ Ah,
                                                     const unsigned short* __restrict__ Al,
                                                     const unsigned short* __restrict__ Wh,
                                                     const unsigned short* __restrict__ Wl,
                                                     unsigned short* __restrict__ Ch,
                                                     unsigned short* __restrict__ Cl)
{
    __shared__ unsigned short sAh[128*40], sAl[128*40], sBh[128*40], sBl[128*40];
    int t0 = blockIdx.x * 128, d0 = blockIdx.y * 128;
    int tid = threadIdx.x;
    int lane = tid & 63, wid = tid >> 6;
    int wr = wid >> 1, wc = wid & 1;
    int fr = lane & 15, kc = (lane >> 4) * 8;

    f32x4 acc[4][4];
    #pragma unroll
    for (int m = 0; m < 4; m++)
        #pragma unroll
        for (int n = 0; n < 4; n++) acc[m][n] = (f32x4){0.f,0.f,0.f,0.f};

    int srow = tid >> 1, skh = (tid & 1) * 16;

    for (int kk = 0; kk < 512; kk += 32) {
        const unsigned short* gAh = Ah + (size_t)(t0 + srow)*512 + kk + skh;
        const unsigned short* gAl = Al + (size_t)(t0 + srow)*512 + kk + skh;
        const unsigned short* gWh = Wh + (size_t)(d0 + srow)*512 + kk + skh;
        const unsigned short* gWl = Wl + (size_t)(d0 + srow)*512 + kk + skh;
        int so = srow*40 + skh;
        *(uint4*)&sAh[so]     = *(const uint4*)(gAh);
        *(uint4*)&sAh[so + 8] = *(const uint4*)(gAh + 8);
        *(uint4*)&sAl[so]     = *(const uint4*)(gAl);
        *(uint4*)&sAl[so + 8] = *(const uint4*)(gAl + 8);
        *(uint4*)&sBh[so]     = *(const uint4*)(gWh);
        *(uint4*)&sBh[so + 8] = *(const uint4*)(gWh + 8);
        *(uint4*)&sBl[so]     = *(const uint4*)(gWl);
        *(uint4*)&sBl[so + 8] = *(const uint4*)(gWl + 8);
        __syncthreads();

        bf16x8 ah[4], al[4], bh[4], bl[4];
        #pragma unroll
        for (int m = 0; m < 4; m++) {
            int r = (wr*64 + m*16 + fr)*40 + kc;
            ah[m] = ld_bf8(&sAh[r]);
            al[m] = ld_bf8(&sAl[r]);
        }
        #pragma unroll
        for (int n = 0; n < 4; n++) {
            int r = (wc*64 + n*16 + fr)*40 + kc;
            bh[n] = ld_bf8(&sBh[r]);
            bl[n] = ld_bf8(&sBl[r]);
        }
        #pragma unroll
        for (int m = 0; m < 4; m++)
            #pragma unroll
            for (int n = 0; n < 4; n++) {
                acc[m][n] = __builtin_amdgcn_mfma_f32_16x16x32_bf16(ah[m], bh[n], acc[m][n], 0, 0, 0);
                acc[m][n] = __builtin_amdgcn_mfma_f32_16x16x32_bf16(ah[m], bl[n], acc[m][n], 0, 0, 0);
                acc[m][n] = __builtin_amdgcn_mfma_f32_16x16x32_bf16(al[m], bh[n], acc[m][n], 0, 0, 0);
            }
        __syncthreads();
    }

    #pragma unroll
    for (int m = 0; m < 4; m++) {
        int row = t0 + wr*64 + m*16 + (lane >> 4)*4;
        #pragma unroll
        for (int n = 0; n < 4; n++) {
            int col = d0 + wc*64 + n*16 + fr;
            #pragma unroll
            for (int r = 0; r < 4; r++) {
                float v = acc[m][n][r];
                unsigned short hi = f2bf(v);
                unsigned short lo = f2bf(v - bf2f(hi));
                Ch[(size_t)(row + r)*512 + col] = hi;
                Cl[(size_t)(row + r)*512 + col] = lo;
            }
        }
    }
}

// ---------------- sal (banded) via bf16x3 MFMA ----------------
__global__ __launch_bounds__(256) void sal_mfma(const unsigned short* __restrict__ Xh,
                                                const unsigned short* __restrict__ Xl,
                                                const unsigned short* __restrict__ Wh,
                                                const unsigned short* __restrict__ Wl,
                                                float* __restrict__ sal)
{
    int b = blockIdx.x, i0 = blockIdx.y * 64;
    __shared__ unsigned short sAh[64*40], sAl[64*40], sBh[128*40], sBl[128*40];
    int tid = threadIdx.x;
    int lane = tid & 63, wc = tid >> 6;
    int fr = lane & 15, kc = (lane >> 4) * 8;

    const unsigned short* XhB = Xh + (size_t)b*T_*D_;
    const unsigned short* XlB = Xl + (size_t)b*T_*D_;
    const unsigned short* WhB = Wh + (size_t)b*T_*D_;
    const unsigned short* WlB = Wl + (size_t)b*T_*D_;

    f32x4 acc[4][2];
    #pragma unroll
    for (int m = 0; m < 4; m++) { acc[m][0] = (f32x4){0.f,0.f,0.f,0.f}; acc[m][1] = (f32x4){0.f,0.f,0.f,0.f}; }

    int arow = tid >> 2, akh = (tid & 3) * 8;
    int brow = tid >> 1, bkh = (tid & 1) * 16;
    int jrow = i0 - 64 + brow;
    const uint4 z4 = make_uint4(0,0,0,0);

    for (int kk = 0; kk < 512; kk += 32) {
        *(uint4*)&sAh[arow*40 + akh] = *(const uint4*)(XhB + (size_t)(i0 + arow)*512 + kk + akh);
        *(uint4*)&sAl[arow*40 + akh] = *(const uint4*)(XlB + (size_t)(i0 + arow)*512 + kk + akh);
        int bo = brow*40 + bkh;
        if (jrow >= 0) {
            const unsigned short* gh = WhB + (size_t)jrow*512 + kk + bkh;
            const unsigned short* gl = WlB + (size_t)jrow*512 + kk + bkh;
            *(uint4*)&sBh[bo]     = *(const uint4*)(gh);
            *(uint4*)&sBh[bo + 8] = *(const uint4*)(gh + 8);
            *(uint4*)&sBl[bo]     = *(const uint4*)(gl);
            *(uint4*)&sBl[bo + 8] = *(const uint4*)(gl + 8);
        } else {
            *(uint4*)&sBh[bo] = z4; *(uint4*)&sBh[bo + 8] = z4;
            *(uint4*)&sBl[bo] = z4; *(uint4*)&sBl[bo + 8] = z4;
        }
        __syncthreads();

        bf16x8 ah[4], al[4], bh[2], bl[2];
        #pragma unroll
        for (int m = 0; m < 4; m++) {
            int r = (m*16 + fr)*40 + kc;
            ah[m] = ld_bf8(&sAh[r]);
            al[m] = ld_bf8(&sAl[r]);
        }
        #pragma unroll
        for (int n = 0; n < 2; n++) {
            int r = (wc*32 + n*16 + fr)*40 + kc;
            bh[n] = ld_bf8(&sBh[r]);
            bl[n] = ld_bf8(&sBl[r]);
        }
        #pragma unroll
        for (int m = 0; m < 4; m++)
            #pragma unroll
            for (int n = 0; n < 2; n++) {
                acc[m][n] = __builtin_amdgcn_mfma_f32_16x16x32_bf16(ah[m], bh[n], acc[m][n], 0, 0, 0);
                acc[m][n] = __builtin_amdgcn_mfma_f32_16x16x32_bf16(ah[m], bl[n], acc[m][n], 0, 0, 0);
                acc[m][n] = __builtin_amdgcn_mfma_f32_16x16x32_bf16(al[m], bh[n], acc[m][n], 0, 0, 0);
            }
        __syncthreads();
    }

    float* salB = sal + (size_t)b*T_*WIN_;
    #pragma unroll
    for (int m = 0; m < 4; m++) {
        #pragma unroll
        for (int n = 0; n < 2; n++) {
            int jl = wc*32 + n*16 + fr;
            #pragma unroll
            for (int r = 0; r < 4; r++) {
                int il = m*16 + (lane >> 4)*4 + r;
                int o = il - jl + 64;
                if (o >= 1 && o <= 64) {
                    int jg = i0 - 64 + jl;
                    salB[(size_t)(i0 + il)*WIN_ + (o - 1)] = (jg >= 0) ? acc[m][n][r] : NEGV;
                }
            }
        }
    }
}

// ---------------- top-16: stage 1 ----------------
__global__ __launch_bounds__(256) void topk_stage1(const float* __restrict__ sal,
                                                   float* __restrict__ cv, int* __restrict__ ci)
{
    int b = blockIdx.x, c = blockIdx.y;
    const float* s = sal + (size_t)b*(T_*WIN_) + (size_t)c*2048;
    int base = c*2048;
    int tid = threadIdx.x;
    float lv[8]; int li[8];
    #pragma unroll
    for (int k = 0; k < 8; k++) { lv[k] = NEGINF; li[k] = 0x7FFFFFFF; }
    #pragma unroll
    for (int r = 0; r < 8; r++) {
        int p = tid + r*256;
        float v = s[p];
        int idx = base + p;
        if (v > lv[7]) {
            int k = 7;
            while (k > 0 && lv[k-1] < v) { lv[k] = lv[k-1]; li[k] = li[k-1]; k--; }
            lv[k] = v; li[k] = idx;
        }
    }
    __shared__ float rv[256]; __shared__ int ri[256]; __shared__ int rt[256];
    int head = 0;
    float* cvo = cv + ((size_t)b*64 + c)*16;
    int*   cio = ci + ((size_t)b*64 + c)*16;
    for (int r = 0; r < 16; r++) {
        float bv2 = (head < 8) ? lv[head] : NEGINF;
        int   bi2 = (head < 8) ? li[head] : 0x7FFFFFFF;
        rv[tid] = bv2; ri[tid] = bi2; rt[tid] = tid;
        __syncthreads();
        for (int st = 128; st > 0; st >>= 1) {
            if (tid < st) {
                float v2 = rv[tid+st]; int i2 = ri[tid+st];
                if (v2 > rv[tid] || (v2 == rv[tid] && i2 < ri[tid])) {
                    rv[tid] = v2; ri[tid] = i2; rt[tid] = rt[tid+st];
                }
            }
            __syncthreads();
        }
        if (rt[0] == tid) head++;
        if (tid == 0) { cvo[r] = rv[0]; cio[r] = ri[0]; }
        __syncthreads();
    }
}

// ---------------- top-16: stage 2 ----------------
__global__ __launch_bounds__(256) void topk_stage2(const float* __restrict__ cv,
                                                   const int* __restrict__ ci,
                                                   int* __restrict__ ti, int* __restrict__ tj,
                                                   float* __restrict__ tv)
{
    int b = blockIdx.x, tid = threadIdx.x;
    const float* cvb = cv + (size_t)b*1024;
    const int*   cib = ci + (size_t)b*1024;
    float lv[4]; int li[4];
    #pragma unroll
    for (int k = 0; k < 4; k++) { lv[k] = NEGINF; li[k] = 0x7FFFFFFF; }
    #pragma unroll
    for (int r = 0; r < 4; r++) {
        int p = tid + r*256;
        float v = cvb[p];
        int idx = cib[p];
        if (v > lv[3] || (v == lv[3] && idx < li[3])) {
            int k = 3;
            while (k > 0 && (lv[k-1] < v || (lv[k-1] == v && li[k-1] > idx))) {
                lv[k] = lv[k-1]; li[k] = li[k-1]; k--;
            }
            lv[k] = v; li[k] = idx;
        }
    }
    __shared__ float rv[256]; __shared__ int ri[256]; __shared__ int rt[256];
    int head = 0;
    for (int r = 0; r < 16; r++) {
        float bv2 = (head < 4) ? lv[head] : NEGINF;
        int   bi2 = (head < 4) ? li[head] : 0x7FFFFFFF;
        rv[tid] = bv2; ri[tid] = bi2; rt[tid] = tid;
        __syncthreads();
        for (int st = 128; st > 0; st >>= 1) {
            if (tid < st) {
                float v2 = rv[tid+st]; int i2 = ri[tid+st];
                if (v2 > rv[tid] || (v2 == rv[tid] && i2 < ri[tid])) {
                    rv[tid] = v2; ri[tid] = i2; rt[tid] = rt[tid+st];
                }
            }
            __syncthreads();
        }
        if (rt[0] == tid) head++;
        if (tid == 0) {
            int flat = ri[0];
            int i = flat >> 6;
            int o = (flat & 63) + 1;
            ti[b*16+r] = i;
            tj[b*16+r] = i - o;
            tv[b*16+r] = rv[0];
        }
        __syncthreads();
    }
}

// ---------------- slot pipeline (per batch) ----------------
__global__ __launch_bounds__(256) void slot_kernel(
    const unsigned short* __restrict__ Xh, const unsigned short* __restrict__ Xl,
    const float* __restrict__ slots_in,
    const int* __restrict__ ti, const int* __restrict__ tj, const float* __restrict__ tv,
    const float* __restrict__ W_V, const float* __restrict__ W_K_slot, const float* __restrict__ skb,
    const float* __restrict__ Wg, const float* __restrict__ Wgb,
    const float* __restrict__ lnw, const float* __restrict__ lnb,
    const float* __restrict__ WsQ, const float* __restrict__ WsK, const float* __restrict__ WsV,
    const float* __restrict__ lambda_, const float* __restrict__ temps,
    float* __restrict__ snws, float* __restrict__ out_slots)
{
    int b = blockIdx.x, tid = threadIdx.x;
    __shared__ float alpha[16];
    __shared__ float y[D_];
    __shared__ float Rt[DB_];
    __shared__ float sl[K_][DB_];
    __shared__ float skv[K_][DB_];
    __shared__ float wR[K_][DB_];
    __shared__ float upd[K_][DB_];
    __shared__ float Bn[K_][DB_];
    __shared__ float qq[K_][DB_], kk2[K_][DB_], vv[K_][DB_];
    __shared__ float swv[K_], compat[K_], mu7[K_], rs7[K_];
    __shared__ float sa[K_][K_];

    if (tid == 0) {
        float m = NEGINF;
        for (int k = 0; k < 16; k++) m = fmaxf(m, tv[b*16+k]);
        float ssum = 0.f;
        for (int k = 0; k < 16; k++) { float e = expf(tv[b*16+k] - m); alpha[k] = e; ssum += e; }
        for (int k = 0; k < 16; k++) alpha[k] /= ssum;
    }
    for (int p = tid; p < K_*DB_; p += 256) sl[p>>7][p&127] = slots_in[(size_t)b*K_*DB_ + p];
    __syncthreads();

    for (int e = tid; e < D_; e += 256) {
        float acc = 0.f;
        for (int k = 0; k < 16; k++) {
            int i = ti[b*16+k], j = tj[b*16+k];
            float xi = bf2f(Xh[((size_t)b*T_ + i)*D_ + e]) + bf2f(Xl[((size_t)b*T_ + i)*D_ + e]);
            float xj = bf2f(Xh[((size_t)b*T_ + j)*D_ + e]) + bf2f(Xl[((size_t)b*T_ + j)*D_ + e]);
            acc += alpha[k] * (xi - xj);
        }
        y[e] = acc;
    }
    __syncthreads();
    if (tid < DB_) {
        float acc = 0.f;
        for (int e = 0; e < D_; e++) acc += y[e] * W_V[(size_t)e*DB_ + tid];
        Rt[tid] = acc;
    }
    __syncthreads();
    if (tid < DB_) {
        int d = tid;
        for (int k = 0; k < K_; k++) {
            float acc = skb[k*DB_ + d];
            for (int e = 0; e < DB_; e++) acc += sl[k][e] * W_K_slot[(size_t)e*DB_ + d];
            skv[k][d] = acc * Rt[d];
        }
    }
    __syncthreads();
    if (tid < K_) {
        float a = 0.f;
        for (int d = 0; d < DB_; d++) a += skv[tid][d];
        compat[tid] = a * SCALE_ * softplusf(temps[tid]);
    }
    __syncthreads();
    if (tid == 0) {
        float m = compat[0];
        for (int k = 1; k < K_; k++) m = fmaxf(m, compat[k]);
        float ssum = 0.f;
        for (int k = 0; k < K_; k++) { float e = expf(compat[k]-m); swv[k] = e; ssum += e; }
        for (int k = 0; k < K_; k++) swv[k] /= ssum;
    }
    __syncthreads();
    for (int p = tid; p < K_*DB_; p += 256) wR[p>>7][p&127] = swv[p>>7] * Rt[p&127];
    __syncthreads();
    if (tid < DB_) {
        int d = tid;
        for (int k = 0; k < K_; k++) {
            float acc = Wgb[d];
            for (int e = 0; e < DB_; e++) acc += sl[k][e] * Wg[(size_t)e*DB_ + d];
            for (int e = 0; e < DB_; e++) acc += wR[k][e] * Wg[(size_t)(DB_+e)*DB_ + d];
            float g = 1.f / (1.f + expf(-acc));
            upd[k][d] = (1.f - g) * sl[k][d] + g * wR[k][d];
        }
    }
    __syncthreads();
    if (tid < K_) {
        float s = 0.f, ss = 0.f;
        for (int d = 0; d < DB_; d++) { float v = upd[tid][d]; s += v; ss += v*v; }
        float mu = s / (float)DB_;
        mu7[tid] = mu;
        rs7[tid] = rsqrtf(ss/(float)DB_ - mu*mu + 1e-5f);
    }
    __syncthreads();
    for (int p = tid; p < K_*DB_; p += 256) {
        int k = p>>7, d = p&127;
        Bn[k][d] = (upd[k][d] - mu7[k]) * rs7[k] * lnw[d] + lnb[d];
    }
    __syncthreads();
    if (tid < DB_) {
        int d = tid;
        for (int k = 0; k < K_; k++) {
            float aq = 0.f, ak = 0.f, av = 0.f;
            for (int e = 0; e < DB_; e++) {
                float bn = Bn[k][e];
                aq += bn * WsQ[(size_t)e*DB_ + d];
                ak += bn * WsK[(size_t)e*DB_ + d];
                av += bn * WsV[(size_t)e*DB_ + d];
            }
            qq[k][d] = aq; kk2[k][d] = ak; vv[k][d] = av;
        }
    }
    __syncthreads();
    if (tid < K_*K_) {
        int q = tid / K_, j = tid % K_;
        float a = 0.f;
        for (int e = 0; e < DB_; e++) a += qq[q][e] * kk2[j][e];
        sa[q][j] = a * SCALE_;
    }
    __syncthreads();
    if (tid < K_) {
        float m = sa[tid][0];
        for (int j = 1; j < K_; j++) m = fmaxf(m, sa[tid][j]);
        float ssum = 0.f;
        for (int j = 0; j < K_; j++) { float e = expf(sa[tid][j]-m); sa[tid][j] = e; ssum += e; }
        for (int j = 0; j < K_; j++) sa[tid][j] /= ssum;
    }
    __syncthreads();
    if (tid < DB_) {
        int d = tid;
        float lam = tanhf(lambda_[d]);
        lam = fminf(fmaxf(lam, -0.5f), 0.5f);
        for (int k = 0; k < K_; k++) {
            float c = 0.f;
            for (int j = 0; j < K_; j++) c += sa[k][j] * vv[j][d];
            float sn = upd[k][d] + c * lam;
            snws[((size_t)b*K_ + k)*DB_ + d] = sn;
            out_slots[((size_t)b*K_ + k)*DB_ + d] = sn;
        }
    }
}

// ---------------- losses ----------------
__global__ __launch_bounds__(256) void loss_kernel(const float* __restrict__ sn,
                                                   const float* __restrict__ sl0,
                                                   float* __restrict__ out)
{
    __shared__ float sh[8];
    __shared__ float nrm[B_*K_];
    float acc = 0.f;
    for (int p = threadIdx.x; p < B_*K_*DB_; p += 256) { float d = sn[p] - sl0[p]; acc += d*d; }
    for (int off = 32; off; off >>= 1) acc += __shfl_down(acc, off);
    int lane = threadIdx.x & 63, w = threadIdx.x >> 6;
    if (lane == 0) sh[w] = acc;
    __syncthreads();
    if (threadIdx.x == 0) out[0] = (sh[0]+sh[1]+sh[2]+sh[3]) / (float)(B_*K_*DB_);
    if (threadIdx.x < B_*K_) {
        float s = 0.f;
        const float* a = sn + (size_t)threadIdx.x * DB_;
        for (int d = 0; d < DB_; d++) s += a[d]*a[d];
        nrm[threadIdx.x] = fmaxf(sqrtf(s), 1e-12f);
    }
    __syncthreads();
    float acc2 = 0.f;
    for (int p = threadIdx.x; p < B_*K_*K_; p += 256) {
        int bb = p / (K_*K_), r = p % (K_*K_), q = r / K_, j = r % K_;
        if (q != j) {
            const float* a = sn + ((size_t)bb*K_ + q)*DB_;
            const float* c = sn + ((size_t)bb*K_ + j)*DB_;
            float dot = 0.f;
            for (int d = 0; d < DB_; d++) dot += a[d]*c[d];
            float cs = dot / (nrm[bb*K_+q] * nrm[bb*K_+j]);
            acc2 += cs*cs;
        }
    }
    for (int off = 32; off; off >>= 1) acc2 += __shfl_down(acc2, off);
    __syncthreads();
    if (lane == 0) sh[w] = acc2;
    __syncthreads();
    if (threadIdx.x == 0) out[1] = (sh[0]+sh[1]+sh[2]+sh[3]) / (float)(B_*(K_*K_-K_));
}

// ---------------- w0q + phi/psi partials: grid (B, 8), one wave per W0 row ----------------
__global__ __launch_bounds__(256) void w0q_part_kernel(const float* __restrict__ qmean,
                                                       const float* __restrict__ W0,
                                                       float* __restrict__ part)
{
    int b = blockIdx.x, c = blockIdx.y, tid = threadIdx.x;
    __shared__ float qm[D_];
    for (int p = tid; p < D_; p += 256) qm[p] = qmean[(size_t)b*D_ + p];
    __syncthreads();
    int w = tid >> 6, lane = tid & 63;
    float ph = 0.f, ps = 0.f;
    for (int r = 0; r < 16; r++) {
        int d = c*64 + w*16 + r;
        const float* wr = W0 + (size_t)d*D_;
        float s = 0.f;
        #pragma unroll
        for (int q = 0; q < 8; q++) s += qm[lane + q*64] * wr[lane + q*64];
        #pragma unroll
        for (int off = 32; off; off >>= 1) s += __shfl_xor(s, off);
        float phi = (s - PSI_*qm[d]) * INV_DENOM_;
        float psi = (PHI_*qm[d] - s) * INV_DENOM_;
        ph += phi*phi; ps += psi*psi;
    }
    __shared__ float shp[4], shs[4];
    if (lane == 0) { shp[w] = ph; shs[w] = ps; }
    __syncthreads();
    if (tid == 0) {
        part[((size_t)b*8 + c)*2 + 0] = shp[0]+shp[1]+shp[2]+shp[3];
        part[((size_t)b*8 + c)*2 + 1] = shs[0]+shs[1]+shs[2]+shs[3];
    }
}

// ---------------- basis: reduce partials -> (b1, b2) per batch ----------------
__global__ __launch_bounds__(64) void basis_kernel(const float* __restrict__ part,
                                                   float* __restrict__ basis)
{
    int b = threadIdx.x;
    if (b < B_) {
        float P = 0.f, Q = 0.f;
        for (int c = 0; c < 8; c++) {
            P += part[((size_t)b*8 + c)*2 + 0];
            Q += part[((size_t)b*8 + c)*2 + 1];
        }
        float pm = sqrtf(P), qm = sqrtf(Q);
        float tot = pm + qm + 1e-6f;
        basis[b*2 + 0] = pm / tot;
        basis[b*2 + 1] = qm / tot;
    }
}

// ---------------- kq & vg: grid (B, K) ----------------
__global__ __launch_bounds__(256) void kqvg_kernel(
    const float* __restrict__ sn, const float* __restrict__ WKr,
    const float* __restrict__ WQr, const float* __restrict__ WVr,
    const float* __restrict__ rc, const float* __restrict__ basis,
    float* __restrict__ kq, float* __restrict__ vg)
{
    int b = blockIdx.x, k = blockIdx.y, tid = threadIdx.x;
    __shared__ float sl[DB_], kr[DB_];
    if (tid < DB_) sl[tid] = sn[((size_t)b*K_ + k)*DB_ + tid];
    __syncthreads();
    if (tid < DB_) {
        float a = 0.f;
        for (int e = 0; e < DB_; e++) a += sl[e] * WKr[(size_t)e*DB_ + tid];
        kr[tid] = a;
    }
    __syncthreads();
    float b1 = basis[b*2 + 0], b2 = basis[b*2 + 1];
    #pragma unroll
    for (int rep = 0; rep < 2; rep++) {
        int e = tid + rep*256;
        float a = 0.f;
        const float* wq = WQr + (size_t)e*DB_;
        for (int d = 0; d < DB_; d++) a += kr[d] * wq[d];
        kq[((size_t)b*K_ + k)*D_ + e] = a;
    }
    #pragma unroll
    for (int rep = 0; rep < 2; rep++) {
        int dd = tid + rep*256;
        float a = 0.f;
        for (int e = 0; e < DB_; e++) a += sl[e] * WVr[(size_t)e*D_ + dd];
        float gpre = rc[((size_t)k*3 + 0)*D_ + dd] + b1*rc[((size_t)k*3 + 1)*D_ + dd] + b2*rc[((size_t)k*3 + 2)*D_ + dd];
        float g = tanhf(gpre);
        g = fminf(fmaxf(g, -0.5f), 0.5f);
        vg[((size_t)b*K_ + k)*D_ + dd] = a * g;
    }
}

// ---------------- z: softmax over 7 slots + weighted combine ----------------
__global__ __launch_bounds__(256) void z_kernel(const float* __restrict__ Xr,
                                                const float* __restrict__ kq,
                                                const float* __restrict__ vg,
                                                float* __restrict__ z)
{
    int b = blockIdx.x;
    int t0 = blockIdx.y * 64;
    __shared__ float kqs[K_][D_];
    __shared__ float vgs[K_][D_];
    int tid = threadIdx.x;
    for (int p = tid; p < K_*D_; p += 256) {
        kqs[p>>9][p&511] = kq[(size_t)b*K_*D_ + p];
        vgs[p>>9][p&511] = vg[(size_t)b*K_*D_ + p];
    }
    __syncthreads();
    int lane = tid & 63, w = tid >> 6;
    for (int it = 0; it < 16; it++) {
        int t = t0 + w*16 + it;
        const float* x = Xr + ((size_t)b*T_ + t)*D_;
        float xr[8];
        float s[K_] = {0,0,0,0,0,0,0};
        #pragma unroll
        for (int r = 0; r < 8; r++) {
            int e = lane + r*64;
            xr[r] = x[e];
            #pragma unroll
            for (int k = 0; k < K_; k++) s[k] += xr[r] * kqs[k][e];
        }
        #pragma unroll
        for (int k = 0; k < K_; k++)
            for (int off = 32; off; off >>= 1) s[k] += __shfl_xor(s[k], off);
        float sc[K_];
        float m = NEGINF;
        #pragma unroll
        for (int k = 0; k < K_; k++) { sc[k] = s[k] * SCALE_; m = fmaxf(m, sc[k]); }
        float p[K_], ssum = 0.f;
        #pragma unroll
        for (int k = 0; k < K_; k++) { p[k] = expf(sc[k] - m); ssum += p[k]; }
        float inv = 1.f / ssum;
        float* zp = z + ((size_t)b*T_ + t)*D_;
        #pragma unroll
        for (int r = 0; r < 8; r++) {
            int e = lane + r*64;
            float a = 0.f;
            #pragma unroll
            for (int k = 0; k < K_; k++) a += p[k] * vgs[k][e];
            zp[e] = a * inv;
        }
    }
}

extern "C" void kernel_launch(void* const* d_in, const int* in_sizes, int n_in,
                              void* d_out, int out_size, void* d_ws, size_t ws_size,
                              hipStream_t stream)
{
    const float* X_write = (const float*)d_in[0];
    const float* X_read  = (const float*)d_in[1];
    const float* slots   = (const float*)d_in[2];
    const float* W0      = (const float*)d_in[3];
    const float* lnw_w   = (const float*)d_in[4];
    const float* lnw_b   = (const float*)d_in[5];
    const float* W_V     = (const float*)d_in[6];
    const float* W_K_slot= (const float*)d_in[7];
    const float* skb     = (const float*)d_in[8];
    const float* Wg      = (const float*)d_in[9];
    const float* Wgb     = (const float*)d_in[10];
    const float* lns_w   = (const float*)d_in[11];
    const float* lns_b   = (const float*)d_in[12];
    const float* WsQ     = (const float*)d_in[13];
    const float* WsK     = (const float*)d_in[14];
    const float* WsV     = (const float*)d_in[15];
    const float* lambda_ = (const float*)d_in[16];
    const float* WQr     = (const float*)d_in[17];
    const float* WKr     = (const float*)d_in[18];
    const float* WVr     = (const float*)d_in[19];
    const float* rc      = (const float*)d_in[20];
    const float* temps   = (const float*)d_in[21];

    const size_t NXD = (size_t)B_*T_*D_;           // 16777216
    unsigned short* Xh  = (unsigned short*)d_ws;
    unsigned short* Xl  = Xh + NXD;
    unsigned short* Ch  = Xl + NXD;                // XW0 hi
    unsigned short* Cl  = Ch + NXD;                // XW0 lo
    unsigned short* W0h = Cl + NXD;                // 262144
    unsigned short* W0l = W0h + (size_t)D_*D_;
    float* fscr  = (float*)(W0l + (size_t)D_*D_);
    float* qpart = fscr;                           // B*8*D = 65536
    float* qmean = qpart + (size_t)B_*8*D_;        // 8192
    float* snws  = qmean + (size_t)B_*D_;          // 14336
    float* kq    = snws + (size_t)B_*K_*DB_;       // 57344
    float* vg    = kq + (size_t)B_*K_*D_;          // 57344
    float* tv    = vg + (size_t)B_*K_*D_;          // 256
    int*   ti    = (int*)(tv + 256);
    int*   tj    = (int*)(tv + 512);
    float* cv    = tv + 768;                       // B*64*16 = 16384
    int*   ci    = (int*)(cv + (size_t)B_*64*16);  // 16384
    float* w0p   = (float*)(ci + (size_t)B_*64*16);// B*8*2 = 256
    float* basis = w0p + 256;                      // B*2 = 32

    float* z_out     = (float*)d_out;
    float* slots_out = z_out + NXD;
    float* loss_out  = slots_out + (size_t)B_*K_*DB_;
    float* sal       = z_out;    // scratch inside z region; consumed before z_kernel writes

    ln_kernel<<<dim3(B_*T_), dim3(256), 0, stream>>>(X_write, lnw_w, lnw_b, Xh, Xl);
    w0cvt_kernel<<<dim3(256), dim3(256), 0, stream>>>(W0, W0h, W0l);
    qmean_part_k<<<dim3(B_, 8), dim3(512), 0, stream>>>(X_read, qpart);
    qmean_final_k<<<dim3(B_), dim3(512), 0, stream>>>(qpart, qmean);
    gemm_xw0_mfma<<<dim3(B_*T_/128, D_/128), dim3(256), 0, stream>>>(Xh, Xl, W0h, W0l, Ch, Cl);
    sal_mfma<<<dim3(B_, T_/64), dim3(256), 0, stream>>>(Xh, Xl, Ch, Cl, sal);
    topk_stage1<<<dim3(B_, 64), dim3(256), 0, stream>>>(sal, cv, ci);
    topk_stage2<<<dim3(B_), dim3(256), 0, stream>>>(cv, ci, ti, tj, tv);
    slot_kernel<<<dim3(B_), dim3(256), 0, stream>>>(Xh, Xl, slots, ti, tj, tv,
        W_V, W_K_slot, skb, Wg, Wgb, lns_w, lns_b, WsQ, WsK, WsV, lambda_, temps,
        snws, slots_out);
    loss_kernel<<<dim3(1), dim3(256), 0, stream>>>(snws, slots, loss_out);
    w0q_part_kernel<<<dim3(B_, 8), dim3(256), 0, stream>>>(qmean, W0, w0p);
    basis_kernel<<<dim3(1), dim3(64), 0, stream>>>(w0p, basis);
    kqvg_kernel<<<dim3(B_, K_), dim3(256), 0, stream>>>(snws, WKr, WQr, WVr, rc, basis, kq, vg);
    z_kernel<<<dim3(B_, T_/64), dim3(256), 0, stream>>>(X_read, kq, vg, z_out);
}

// Round 5
// 348.014 us; speedup vs baseline: 3.7169x; 1.2050x over previous
//
#include <hip/hip_runtime.h>
#include <math.h>

#define B_ 16
#define T_ 2048
#define D_ 512
#define DB_ 128
#define K_ 7
#define TOPK_ 16
#define WIN_ 64

static constexpr float SCALE_ = 0.08838834764831845f;   // 128^-0.5
static constexpr float PHI_ = 1.618033988749895f;
static constexpr float PSI_ = -0.6180339887498949f;
static constexpr float INV_DENOM_ = 0.4472135954999579f; // 1/(PHI-PSI)
static constexpr float NEGV = -1e30f;
static constexpr float NEGINF = -3.402823466e38f;

typedef __attribute__((ext_vector_type(8))) __bf16 bf16x8;
typedef __attribute__((ext_vector_type(8))) unsigned short u16x8;
typedef __attribute__((ext_vector_type(4))) float f32x4;

__device__ inline float softplusf(float x){
    return fmaxf(x, 0.f) + log1pf(expf(-fabsf(x)));
}
__device__ inline unsigned short f2bf(float x){
    unsigned int u = __float_as_uint(x);
    unsigned int r = (u + 0x7FFFu + ((u >> 16) & 1u)) >> 16;
    return (unsigned short)r;
}
__device__ inline float bf2f(unsigned short h){
    return __uint_as_float(((unsigned int)h) << 16);
}
__device__ inline bf16x8 ld_bf8(const unsigned short* p){
    u16x8 r = *(const u16x8*)p;
    return __builtin_bit_cast(bf16x8, r);
}

// ---------------- LayerNorm of X_write -> Xn (bf16 hi/lo split) ----------------
__global__ __launch_bounds__(256) void ln_kernel(const float* __restrict__ X,
                                                 const float* __restrict__ w,
                                                 const float* __restrict__ b,
                                                 unsigned short* __restrict__ Xh,
                                                 unsigned short* __restrict__ Xl)
{
    int row = blockIdx.x;                 // 0..32767
    const float* x = X + (size_t)row * D_;
    float2 v = ((const float2*)x)[threadIdx.x];
    float s = v.x + v.y, ss = v.x*v.x + v.y*v.y;
    for (int off = 32; off; off >>= 1) { s += __shfl_down(s, off); ss += __shfl_down(ss, off); }
    __shared__ float sh[8];
    int wid = threadIdx.x >> 6, lane = threadIdx.x & 63;
    if (lane == 0) { sh[wid] = s; sh[4+wid] = ss; }
    __syncthreads();
    if (threadIdx.x == 0) {
        float S = sh[0]+sh[1]+sh[2]+sh[3], SS = sh[4]+sh[5]+sh[6]+sh[7];
        float mu = S / (float)D_;
        float var = SS / (float)D_ - mu*mu;
        sh[0] = mu; sh[1] = rsqrtf(var + 1e-5f);
    }
    __syncthreads();
    float mu = sh[0], rs = sh[1];
    float2 wv = ((const float2*)w)[threadIdx.x];
    float2 bv = ((const float2*)b)[threadIdx.x];
    float ox = (v.x - mu) * rs * wv.x + bv.x;
    float oy = (v.y - mu) * rs * wv.y + bv.y;
    unsigned short hx = f2bf(ox), hy = f2bf(oy);
    unsigned short lx = f2bf(ox - bf2f(hx)), ly = f2bf(oy - bf2f(hy));
    ((unsigned int*)(Xh + (size_t)row * D_))[threadIdx.x] = (unsigned int)hx | ((unsigned int)hy << 16);
    ((unsigned int*)(Xl + (size_t)row * D_))[threadIdx.x] = (unsigned int)lx | ((unsigned int)ly << 16);
}

// ---------------- W0 -> bf16 hi/lo ----------------
__global__ __launch_bounds__(256) void w0cvt_kernel(const float* __restrict__ W0,
                                                    unsigned short* __restrict__ Wh,
                                                    unsigned short* __restrict__ Wl)
{
    int gid = blockIdx.x * 256 + threadIdx.x;     // 65536 threads * 4 elems
    float4 v = ((const float4*)W0)[gid];
    unsigned short h0 = f2bf(v.x), h1 = f2bf(v.y), h2 = f2bf(v.z), h3 = f2bf(v.w);
    ushort4 hv = make_ushort4(h0, h1, h2, h3);
    ushort4 lv = make_ushort4(f2bf(v.x - bf2f(h0)), f2bf(v.y - bf2f(h1)),
                              f2bf(v.z - bf2f(h2)), f2bf(v.w - bf2f(h3)));
    *(ushort4*)&Wh[(size_t)gid*4] = hv;
    *(ushort4*)&Wl[(size_t)gid*4] = lv;
}

// ---------------- q_mean over T (two stage) ----------------
__global__ __launch_bounds__(512) void qmean_part_k(const float* __restrict__ Xr, float* __restrict__ part)
{
    int b = blockIdx.x, c = blockIdx.y, d = threadIdx.x;
    const float* base = Xr + ((size_t)b*T_ + (size_t)c*256) * D_ + d;
    float s = 0.f;
    for (int t = 0; t < 256; t++) s += base[(size_t)t * D_];
    part[((size_t)b*8 + c)*D_ + d] = s;
}

__global__ __launch_bounds__(512) void qmean_final_k(const float* __restrict__ part, float* __restrict__ qmean)
{
    int b = blockIdx.x, d = threadIdx.x;
    float s = 0.f;
    for (int c = 0; c < 8; c++) s += part[((size_t)b*8 + c)*D_ + d];
    qmean[(size_t)b*D_ + d] = s * (1.f/2048.f);
}

// ---------------- XW0 = Xn @ W0^T  (bf16x3 MFMA), output as bf16 hi/lo ----------------
__global__ __launch_bounds__(256) void gemm_xw0_mfma(const unsigned short* __restrict__ Ah,
                                                     const unsigned short* __restrict__ Al,
                                                     const unsigned short* __restrict__ Wh,
                                                     const unsigned short* __restrict__ Wl,
                                                     unsigned short* __restrict__ Ch,
                                                     unsigned short* __restrict__ Cl)
{
    __shared__ unsigned short sAh[128*40], sAl[128*40], sBh[128*40], sBl[128*40];
    int t0 = blockIdx.x * 128, d0 = blockIdx.y * 128;
    int tid = threadIdx.x;
    int lane = tid & 63, wid = tid >> 6;
    int wr = wid >> 1, wc = wid & 1;
    int fr = lane & 15, kc = (lane >> 4) * 8;

    f32x4 acc[4][4];
    #pragma unroll
    for (int m = 0; m < 4; m++)
        #pragma unroll
        for (int n = 0; n < 4; n++) acc[m][n] = (f32x4){0.f,0.f,0.f,0.f};

    int srow = tid >> 1, skh = (tid & 1) * 16;

    for (int kk = 0; kk < 512; kk += 32) {
        const unsigned short* gAh = Ah + (size_t)(t0 + srow)*512 + kk + skh;
        const unsigned short* gAl = Al + (size_t)(t0 + srow)*512 + kk + skh;
        const unsigned short* gWh = Wh + (size_t)(d0 + srow)*512 + kk + skh;
        const unsigned short* gWl = Wl + (size_t)(d0 + srow)*512 + kk + skh;
        int so = srow*40 + skh;
        *(uint4*)&sAh[so]     = *(const uint4*)(gAh);
        *(uint4*)&sAh[so + 8] = *(const uint4*)(gAh + 8);
        *(uint4*)&sAl[so]     = *(const uint4*)(gAl);
        *(uint4*)&sAl[so + 8] = *(const uint4*)(gAl + 8);
        *(uint4*)&sBh[so]     = *(const uint4*)(gWh);
        *(uint4*)&sBh[so + 8] = *(const uint4*)(gWh + 8);
        *(uint4*)&sBl[so]     = *(const uint4*)(gWl);
        *(uint4*)&sBl[so + 8] = *(const uint4*)(gWl + 8);
        __syncthreads();

        bf16x8 ah[4], al[4], bh[4], bl[4];
        #pragma unroll
        for (int m = 0; m < 4; m++) {
            int r = (wr*64 + m*16 + fr)*40 + kc;
            ah[m] = ld_bf8(&sAh[r]);
            al[m] = ld_bf8(&sAl[r]);
        }
        #pragma unroll
        for (int n = 0; n < 4; n++) {
            int r = (wc*64 + n*16 + fr)*40 + kc;
            bh[n] = ld_bf8(&sBh[r]);
            bl[n] = ld_bf8(&sBl[r]);
        }
        #pragma unroll
        for (int m = 0; m < 4; m++)
            #pragma unroll
            for (int n = 0; n < 4; n++) {
                acc[m][n] = __builtin_amdgcn_mfma_f32_16x16x32_bf16(ah[m], bh[n], acc[m][n], 0, 0, 0);
                acc[m][n] = __builtin_amdgcn_mfma_f32_16x16x32_bf16(ah[m], bl[n], acc[m][n], 0, 0, 0);
                acc[m][n] = __builtin_amdgcn_mfma_f32_16x16x32_bf16(al[m], bh[n], acc[m][n], 0, 0, 0);
            }
        __syncthreads();
    }

    #pragma unroll
    for (int m = 0; m < 4; m++) {
        int row = t0 + wr*64 + m*16 + (lane >> 4)*4;
        #pragma unroll
        for (int n = 0; n < 4; n++) {
            int col = d0 + wc*64 + n*16 + fr;
            #pragma unroll
            for (int r = 0; r < 4; r++) {
                float v = acc[m][n][r];
                unsigned short hi = f2bf(v);
                unsigned short lo = f2bf(v - bf2f(hi));
                Ch[(size_t)(row + r)*512 + col] = hi;
                Cl[(size_t)(row + r)*512 + col] = lo;
            }
        }
    }
}

// ---------------- sal (banded) via bf16x3 MFMA ----------------
__global__ __launch_bounds__(256) void sal_mfma(const unsigned short* __restrict__ Xh,
                                                const unsigned short* __restrict__ Xl,
                                                const unsigned short* __restrict__ Wh,
                                                const unsigned short* __restrict__ Wl,
                                                float* __restrict__ sal)
{
    int b = blockIdx.x, i0 = blockIdx.y * 64;
    __shared__ unsigned short sAh[64*40], sAl[64*40], sBh[128*40], sBl[128*40];
    int tid = threadIdx.x;
    int lane = tid & 63, wc = tid >> 6;
    int fr = lane & 15, kc = (lane >> 4) * 8;

    const unsigned short* XhB = Xh + (size_t)b*T_*D_;
    const unsigned short* XlB = Xl + (size_t)b*T_*D_;
    const unsigned short* WhB = Wh + (size_t)b*T_*D_;
    const unsigned short* WlB = Wl + (size_t)b*T_*D_;

    f32x4 acc[4][2];
    #pragma unroll
    for (int m = 0; m < 4; m++) { acc[m][0] = (f32x4){0.f,0.f,0.f,0.f}; acc[m][1] = (f32x4){0.f,0.f,0.f,0.f}; }

    int arow = tid >> 2, akh = (tid & 3) * 8;
    int brow = tid >> 1, bkh = (tid & 1) * 16;
    int jrow = i0 - 64 + brow;
    const uint4 z4 = make_uint4(0,0,0,0);

    for (int kk = 0; kk < 512; kk += 32) {
        *(uint4*)&sAh[arow*40 + akh] = *(const uint4*)(XhB + (size_t)(i0 + arow)*512 + kk + akh);
        *(uint4*)&sAl[arow*40 + akh] = *(const uint4*)(XlB + (size_t)(i0 + arow)*512 + kk + akh);
        int bo = brow*40 + bkh;
        if (jrow >= 0) {
            const unsigned short* gh = WhB + (size_t)jrow*512 + kk + bkh;
            const unsigned short* gl = WlB + (size_t)jrow*512 + kk + bkh;
            *(uint4*)&sBh[bo]     = *(const uint4*)(gh);
            *(uint4*)&sBh[bo + 8] = *(const uint4*)(gh + 8);
            *(uint4*)&sBl[bo]     = *(const uint4*)(gl);
            *(uint4*)&sBl[bo + 8] = *(const uint4*)(gl + 8);
        } else {
            *(uint4*)&sBh[bo] = z4; *(uint4*)&sBh[bo + 8] = z4;
            *(uint4*)&sBl[bo] = z4; *(uint4*)&sBl[bo + 8] = z4;
        }
        __syncthreads();

        bf16x8 ah[4], al[4], bh[2], bl[2];
        #pragma unroll
        for (int m = 0; m < 4; m++) {
            int r = (m*16 + fr)*40 + kc;
            ah[m] = ld_bf8(&sAh[r]);
            al[m] = ld_bf8(&sAl[r]);
        }
        #pragma unroll
        for (int n = 0; n < 2; n++) {
            int r = (wc*32 + n*16 + fr)*40 + kc;
            bh[n] = ld_bf8(&sBh[r]);
            bl[n] = ld_bf8(&sBl[r]);
        }
        #pragma unroll
        for (int m = 0; m < 4; m++)
            #pragma unroll
            for (int n = 0; n < 2; n++) {
                acc[m][n] = __builtin_amdgcn_mfma_f32_16x16x32_bf16(ah[m], bh[n], acc[m][n], 0, 0, 0);
                acc[m][n] = __builtin_amdgcn_mfma_f32_16x16x32_bf16(ah[m], bl[n], acc[m][n], 0, 0, 0);
                acc[m][n] = __builtin_amdgcn_mfma_f32_16x16x32_bf16(al[m], bh[n], acc[m][n], 0, 0, 0);
            }
        __syncthreads();
    }

    float* salB = sal + (size_t)b*T_*WIN_;
    #pragma unroll
    for (int m = 0; m < 4; m++) {
        #pragma unroll
        for (int n = 0; n < 2; n++) {
            int jl = wc*32 + n*16 + fr;
            #pragma unroll
            for (int r = 0; r < 4; r++) {
                int il = m*16 + (lane >> 4)*4 + r;
                int o = il - jl + 64;
                if (o >= 1 && o <= 64) {
                    int jg = i0 - 64 + jl;
                    salB[(size_t)(i0 + il)*WIN_ + (o - 1)] = (jg >= 0) ? acc[m][n][r] : NEGV;
                }
            }
        }
    }
}

// ---------------- top-16: stage 1 ----------------
__global__ __launch_bounds__(256) void topk_stage1(const float* __restrict__ sal,
                                                   float* __restrict__ cv, int* __restrict__ ci)
{
    int b = blockIdx.x, c = blockIdx.y;
    const float* s = sal + (size_t)b*(T_*WIN_) + (size_t)c*2048;
    int base = c*2048;
    int tid = threadIdx.x;
    float lv[8]; int li[8];
    #pragma unroll
    for (int k = 0; k < 8; k++) { lv[k] = NEGINF; li[k] = 0x7FFFFFFF; }
    #pragma unroll
    for (int r = 0; r < 8; r++) {
        int p = tid + r*256;
        float v = s[p];
        int idx = base + p;
        if (v > lv[7]) {
            int k = 7;
            while (k > 0 && lv[k-1] < v) { lv[k] = lv[k-1]; li[k] = li[k-1]; k--; }
            lv[k] = v; li[k] = idx;
        }
    }
    __shared__ float rv[256]; __shared__ int ri[256]; __shared__ int rt[256];
    int head = 0;
    float* cvo = cv + ((size_t)b*64 + c)*16;
    int*   cio = ci + ((size_t)b*64 + c)*16;
    for (int r = 0; r < 16; r++) {
        float bv2 = (head < 8) ? lv[head] : NEGINF;
        int   bi2 = (head < 8) ? li[head] : 0x7FFFFFFF;
        rv[tid] = bv2; ri[tid] = bi2; rt[tid] = tid;
        __syncthreads();
        for (int st = 128; st > 0; st >>= 1) {
            if (tid < st) {
                float v2 = rv[tid+st]; int i2 = ri[tid+st];
                if (v2 > rv[tid] || (v2 == rv[tid] && i2 < ri[tid])) {
                    rv[tid] = v2; ri[tid] = i2; rt[tid] = rt[tid+st];
                }
            }
            __syncthreads();
        }
        if (rt[0] == tid) head++;
        if (tid == 0) { cvo[r] = rv[0]; cio[r] = ri[0]; }
        __syncthreads();
    }
}

// ---------------- top-16: stage 2 ----------------
__global__ __launch_bounds__(256) void topk_stage2(const float* __restrict__ cv,
                                                   const int* __restrict__ ci,
                                                   int* __restrict__ ti, int* __restrict__ tj,
                                                   float* __restrict__ tv)
{
    int b = blockIdx.x, tid = threadIdx.x;
    const float* cvb = cv + (size_t)b*1024;
    const int*   cib = ci + (size_t)b*1024;
    float lv[4]; int li[4];
    #pragma unroll
    for (int k = 0; k < 4; k++) { lv[k] = NEGINF; li[k] = 0x7FFFFFFF; }
    #pragma unroll
    for (int r = 0; r < 4; r++) {
        int p = tid + r*256;
        float v = cvb[p];
        int idx = cib[p];
        if (v > lv[3] || (v == lv[3] && idx < li[3])) {
            int k = 3;
            while (k > 0 && (lv[k-1] < v || (lv[k-1] == v && li[k-1] > idx))) {
                lv[k] = lv[k-1]; li[k] = li[k-1]; k--;
            }
            lv[k] = v; li[k] = idx;
        }
    }
    __shared__ float rv[256]; __shared__ int ri[256]; __shared__ int rt[256];
    int head = 0;
    for (int r = 0; r < 16; r++) {
        float bv2 = (head < 4) ? lv[head] : NEGINF;
        int   bi2 = (head < 4) ? li[head] : 0x7FFFFFFF;
        rv[tid] = bv2; ri[tid] = bi2; rt[tid] = tid;
        __syncthreads();
        for (int st = 128; st > 0; st >>= 1) {
            if (tid < st) {
                float v2 = rv[tid+st]; int i2 = ri[tid+st];
                if (v2 > rv[tid] || (v2 == rv[tid] && i2 < ri[tid])) {
                    rv[tid] = v2; ri[tid] = i2; rt[tid] = rt[tid+st];
                }
            }
            __syncthreads();
        }
        if (rt[0] == tid) head++;
        if (tid == 0) {
            int flat = ri[0];
            int i = flat >> 6;
            int o = (flat & 63) + 1;
            ti[b*16+r] = i;
            tj[b*16+r] = i - o;
            tv[b*16+r] = rv[0];
        }
        __syncthreads();
    }
}

// ---------------- slot pipeline (per batch, 1024 threads / 16 waves) ----------------
__global__ __launch_bounds__(1024) void slot_kernel(
    const unsigned short* __restrict__ Xh, const unsigned short* __restrict__ Xl,
    const float* __restrict__ slots_in,
    const int* __restrict__ ti, const int* __restrict__ tj, const float* __restrict__ tv,
    const float* __restrict__ W_V, const float* __restrict__ W_K_slot, const float* __restrict__ skb,
    const float* __restrict__ Wg, const float* __restrict__ Wgb,
    const float* __restrict__ lnw, const float* __restrict__ lnb,
    const float* __restrict__ WsQ, const float* __restrict__ WsK, const float* __restrict__ WsV,
    const float* __restrict__ lambda_, const float* __restrict__ temps,
    float* __restrict__ snws, float* __restrict__ out_slots)
{
    int b = blockIdx.x, tid = threadIdx.x;
    int lane = tid & 63, wvi = tid >> 6;        // 16 waves
    __shared__ float alpha[16];
    __shared__ int   tis[16], tjs[16];
    __shared__ float y[D_];
    __shared__ float part[8][DB_];
    __shared__ float Rt[DB_];
    __shared__ float sl[K_][DB_];
    __shared__ float upd[K_][DB_];
    __shared__ float Bn[K_][DB_];
    __shared__ float qq[K_][DB_], kk2[K_][DB_], vv[K_][DB_];
    __shared__ float swv[K_], compat[K_], mu7[K_], rs7[K_];
    __shared__ float sa[K_][K_];

    for (int p = tid; p < K_*DB_; p += 1024) sl[p>>7][p&127] = slots_in[(size_t)b*K_*DB_ + p];
    if (tid < 16) {
        float v = tv[b*16 + tid];
        tis[tid] = ti[b*16 + tid];
        tjs[tid] = tj[b*16 + tid];
        float m = v;
        #pragma unroll
        for (int off = 8; off; off >>= 1) m = fmaxf(m, __shfl_xor(m, off, 16));
        float e = expf(v - m);
        float s = e;
        #pragma unroll
        for (int off = 8; off; off >>= 1) s += __shfl_xor(s, off, 16);
        alpha[tid] = e / s;
    }
    __syncthreads();

    // y[e] = sum_k alpha_k (Xn[i_k,e] - Xn[j_k,e]) ; 512 threads
    if (tid < D_) {
        float acc = 0.f;
        #pragma unroll
        for (int k = 0; k < 16; k++) {
            int i = tis[k], j = tjs[k];
            float xi = bf2f(Xh[((size_t)b*T_ + i)*D_ + tid]) + bf2f(Xl[((size_t)b*T_ + i)*D_ + tid]);
            float xj = bf2f(Xh[((size_t)b*T_ + j)*D_ + tid]) + bf2f(Xl[((size_t)b*T_ + j)*D_ + tid]);
            acc += alpha[k] * (xi - xj);
        }
        y[tid] = acc;
    }
    __syncthreads();

    // Rt = y @ W_V : 8 groups x 128 threads, 64-slice each
    {
        int g = tid >> 7, d = tid & 127;
        float acc = 0.f;
        int e0 = g * 64;
        for (int e = e0; e < e0 + 64; e++) acc += y[e] * W_V[(size_t)e*DB_ + d];
        part[g][d] = acc;
    }
    __syncthreads();
    if (tid < DB_) {
        float acc = 0.f;
        #pragma unroll
        for (int g = 0; g < 8; g++) acc += part[g][tid];
        Rt[tid] = acc;
    }
    __syncthreads();

    // slot keys * Rt (into qq as scratch): thread = (k,d)
    if (tid < K_*DB_) {
        int k = tid >> 7, d = tid & 127;
        float acc = skb[k*DB_ + d];
        for (int e = 0; e < DB_; e++) acc += sl[k][e] * W_K_slot[(size_t)e*DB_ + d];
        qq[k][d] = acc * Rt[d];
    }
    __syncthreads();
    // compat: wave k reduces 128
    if (wvi < K_) {
        float acc = qq[wvi][lane] + qq[wvi][lane + 64];
        #pragma unroll
        for (int off = 32; off; off >>= 1) acc += __shfl_xor(acc, off);
        if (lane == 0) compat[wvi] = acc * SCALE_ * softplusf(temps[wvi]);
    }
    __syncthreads();
    if (tid == 0) {
        float m = compat[0];
        for (int k = 1; k < K_; k++) m = fmaxf(m, compat[k]);
        float ssum = 0.f;
        for (int k = 0; k < K_; k++) { float e = expf(compat[k]-m); swv[k] = e; ssum += e; }
        for (int k = 0; k < K_; k++) swv[k] /= ssum;
    }
    __syncthreads();

    // gate + slots_upd: thread = (k,d)
    if (tid < K_*DB_) {
        int k = tid >> 7, d = tid & 127;
        float swk = swv[k];
        float acc = Wgb[d];
        for (int e = 0; e < DB_; e++) acc += sl[k][e] * Wg[(size_t)e*DB_ + d];
        for (int e = 0; e < DB_; e++) acc += swk * Rt[e] * Wg[(size_t)(DB_+e)*DB_ + d];
        float g = 1.f / (1.f + expf(-acc));
        upd[k][d] = (1.f - g) * sl[k][d] + g * (swk * Rt[d]);
    }
    __syncthreads();

    // strand LN stats: wave k
    if (wvi < K_) {
        float v0 = upd[wvi][lane], v1 = upd[wvi][lane + 64];
        float s = v0 + v1, ss = v0*v0 + v1*v1;
        #pragma unroll
        for (int off = 32; off; off >>= 1) { s += __shfl_xor(s, off); ss += __shfl_xor(ss, off); }
        if (lane == 0) {
            float mu = s / (float)DB_;
            mu7[wvi] = mu;
            rs7[wvi] = rsqrtf(ss/(float)DB_ - mu*mu + 1e-5f);
        }
    }
    __syncthreads();
    if (tid < K_*DB_) {
        int k = tid >> 7, d = tid & 127;
        Bn[k][d] = (upd[k][d] - mu7[k]) * rs7[k] * lnw[d] + lnb[d];
    }
    __syncthreads();

    // Q/K/V: thread = (k,d), 3 dots of 128
    if (tid < K_*DB_) {
        int k = tid >> 7, d = tid & 127;
        float aq = 0.f, ak = 0.f, av = 0.f;
        for (int e = 0; e < DB_; e++) {
            float bn = Bn[k][e];
            aq += bn * WsQ[(size_t)e*DB_ + d];
            ak += bn * WsK[(size_t)e*DB_ + d];
            av += bn * WsV[(size_t)e*DB_ + d];
        }
        qq[k][d] = aq; kk2[k][d] = ak; vv[k][d] = av;
    }
    __syncthreads();

    // sa[q][j]: wave q (0..6), lanes split 8 per j, 16 elems per lane
    if (wvi < K_) {
        int j = lane >> 3, s = lane & 7;
        float acc = 0.f;
        if (j < K_) {
            int e0 = s * 16;
            for (int e = e0; e < e0 + 16; e++) acc += qq[wvi][e] * kk2[j][e];
        }
        #pragma unroll
        for (int off = 4; off; off >>= 1) acc += __shfl_xor(acc, off, 8);
        if (s == 0 && j < K_) sa[wvi][j] = acc * SCALE_;
    }
    __syncthreads();
    if (tid < K_) {
        float m = sa[tid][0];
        for (int j = 1; j < K_; j++) m = fmaxf(m, sa[tid][j]);
        float ssum = 0.f;
        for (int j = 0; j < K_; j++) { float e = expf(sa[tid][j]-m); sa[tid][j] = e; ssum += e; }
        for (int j = 0; j < K_; j++) sa[tid][j] /= ssum;
    }
    __syncthreads();

    // ctx + output: thread = (k,d)
    if (tid < K_*DB_) {
        int k = tid >> 7, d = tid & 127;
        float lam = tanhf(lambda_[d]);
        lam = fminf(fmaxf(lam, -0.5f), 0.5f);
        float c = 0.f;
        #pragma unroll
        for (int j = 0; j < K_; j++) c += sa[k][j] * vv[j][d];
        float sn = upd[k][d] + c * lam;
        snws[((size_t)b*K_ + k)*DB_ + d] = sn;
        out_slots[((size_t)b*K_ + k)*DB_ + d] = sn;
    }
}

// ---------------- losses ----------------
__global__ __launch_bounds__(256) void loss_kernel(const float* __restrict__ sn,
                                                   const float* __restrict__ sl0,
                                                   float* __restrict__ out)
{
    __shared__ float sh[8];
    __shared__ float nrm[B_*K_];
    float acc = 0.f;
    for (int p = threadIdx.x; p < B_*K_*DB_; p += 256) { float d = sn[p] - sl0[p]; acc += d*d; }
    for (int off = 32; off; off >>= 1) acc += __shfl_down(acc, off);
    int lane = threadIdx.x & 63, w = threadIdx.x >> 6;
    if (lane == 0) sh[w] = acc;
    __syncthreads();
    if (threadIdx.x == 0) out[0] = (sh[0]+sh[1]+sh[2]+sh[3]) / (float)(B_*K_*DB_);
    if (threadIdx.x < B_*K_) {
        float s = 0.f;
        const float* a = sn + (size_t)threadIdx.x * DB_;
        for (int d = 0; d < DB_; d++) s += a[d]*a[d];
        nrm[threadIdx.x] = fmaxf(sqrtf(s), 1e-12f);
    }
    __syncthreads();
    float acc2 = 0.f;
    for (int p = threadIdx.x; p < B_*K_*K_; p += 256) {
        int bb = p / (K_*K_), r = p % (K_*K_), q = r / K_, j = r % K_;
        if (q != j) {
            const float* a = sn + ((size_t)bb*K_ + q)*DB_;
            const float* c = sn + ((size_t)bb*K_ + j)*DB_;
            float dot = 0.f;
            for (int d = 0; d < DB_; d++) dot += a[d]*c[d];
            float cs = dot / (nrm[bb*K_+q] * nrm[bb*K_+j]);
            acc2 += cs*cs;
        }
    }
    for (int off = 32; off; off >>= 1) acc2 += __shfl_down(acc2, off);
    __syncthreads();
    if (lane == 0) sh[w] = acc2;
    __syncthreads();
    if (threadIdx.x == 0) out[1] = (sh[0]+sh[1]+sh[2]+sh[3]) / (float)(B_*(K_*K_-K_));
}

// ---------------- w0q + phi/psi partials: grid (B, 8), one wave per W0 row ----------------
__global__ __launch_bounds__(256) void w0q_part_kernel(const float* __restrict__ qmean,
                                                       const float* __restrict__ W0,
                                                       float* __restrict__ part)
{
    int b = blockIdx.x, c = blockIdx.y, tid = threadIdx.x;
    __shared__ float qm[D_];
    for (int p = tid; p < D_; p += 256) qm[p] = qmean[(size_t)b*D_ + p];
    __syncthreads();
    int w = tid >> 6, lane = tid & 63;
    float ph = 0.f, ps = 0.f;
    for (int r = 0; r < 16; r++) {
        int d = c*64 + w*16 + r;
        const float* wr = W0 + (size_t)d*D_;
        float s = 0.f;
        #pragma unroll
        for (int q = 0; q < 8; q++) s += qm[lane + q*64] * wr[lane + q*64];
        #pragma unroll
        for (int off = 32; off; off >>= 1) s += __shfl_xor(s, off);
        float phi = (s - PSI_*qm[d]) * INV_DENOM_;
        float psi = (PHI_*qm[d] - s) * INV_DENOM_;
        ph += phi*phi; ps += psi*psi;
    }
    __shared__ float shp[4], shs[4];
    if (lane == 0) { shp[w] = ph; shs[w] = ps; }
    __syncthreads();
    if (tid == 0) {
        part[((size_t)b*8 + c)*2 + 0] = shp[0]+shp[1]+shp[2]+shp[3];
        part[((size_t)b*8 + c)*2 + 1] = shs[0]+shs[1]+shs[2]+shs[3];
    }
}

// ---------------- basis: reduce partials -> (b1, b2) per batch ----------------
__global__ __launch_bounds__(64) void basis_kernel(const float* __restrict__ part,
                                                   float* __restrict__ basis)
{
    int b = threadIdx.x;
    if (b < B_) {
        float P = 0.f, Q = 0.f;
        for (int c = 0; c < 8; c++) {
            P += part[((size_t)b*8 + c)*2 + 0];
            Q += part[((size_t)b*8 + c)*2 + 1];
        }
        float pm = sqrtf(P), qm = sqrtf(Q);
        float tot = pm + qm + 1e-6f;
        basis[b*2 + 0] = pm / tot;
        basis[b*2 + 1] = qm / tot;
    }
}

// ---------------- kq & vg: grid (B, K) ----------------
__global__ __launch_bounds__(256) void kqvg_kernel(
    const float* __restrict__ sn, const float* __restrict__ WKr,
    const float* __restrict__ WQr, const float* __restrict__ WVr,
    const float* __restrict__ rc, const float* __restrict__ basis,
    float* __restrict__ kq, float* __restrict__ vg)
{
    int b = blockIdx.x, k = blockIdx.y, tid = threadIdx.x;
    __shared__ float sl[DB_], kr[DB_];
    if (tid < DB_) sl[tid] = sn[((size_t)b*K_ + k)*DB_ + tid];
    __syncthreads();
    if (tid < DB_) {
        float a = 0.f;
        for (int e = 0; e < DB_; e++) a += sl[e] * WKr[(size_t)e*DB_ + tid];
        kr[tid] = a;
    }
    __syncthreads();
    float b1 = basis[b*2 + 0], b2 = basis[b*2 + 1];
    #pragma unroll
    for (int rep = 0; rep < 2; rep++) {
        int e = tid + rep*256;
        float a = 0.f;
        const float* wq = WQr + (size_t)e*DB_;
        for (int d = 0; d < DB_; d++) a += kr[d] * wq[d];
        kq[((size_t)b*K_ + k)*D_ + e] = a;
    }
    #pragma unroll
    for (int rep = 0; rep < 2; rep++) {
        int dd = tid + rep*256;
        float a = 0.f;
        for (int e = 0; e < DB_; e++) a += sl[e] * WVr[(size_t)e*D_ + dd];
        float gpre = rc[((size_t)k*3 + 0)*D_ + dd] + b1*rc[((size_t)k*3 + 1)*D_ + dd] + b2*rc[((size_t)k*3 + 2)*D_ + dd];
        float g = tanhf(gpre);
        g = fminf(fmaxf(g, -0.5f), 0.5f);
        vg[((size_t)b*K_ + k)*D_ + dd] = a * g;
    }
}

// ---------------- z: softmax over 7 slots + weighted combine ----------------
__global__ __launch_bounds__(256) void z_kernel(const float* __restrict__ Xr,
                                                const float* __restrict__ kq,
                                                const float* __restrict__ vg,
                                                float* __restrict__ z)
{
    int b = blockIdx.x;
    int t0 = blockIdx.y * 64;
    __shared__ float kqs[K_][D_];
    __shared__ float vgs[K_][D_];
    int tid = threadIdx.x;
    for (int p = tid; p < K_*D_; p += 256) {
        kqs[p>>9][p&511] = kq[(size_t)b*K_*D_ + p];
        vgs[p>>9][p&511] = vg[(size_t)b*K_*D_ + p];
    }
    __syncthreads();
    int lane = tid & 63, w = tid >> 6;
    for (int it = 0; it < 16; it++) {
        int t = t0 + w*16 + it;
        const float* x = Xr + ((size_t)b*T_ + t)*D_;
        float xr[8];
        float s[K_] = {0,0,0,0,0,0,0};
        #pragma unroll
        for (int r = 0; r < 8; r++) {
            int e = lane + r*64;
            xr[r] = x[e];
            #pragma unroll
            for (int k = 0; k < K_; k++) s[k] += xr[r] * kqs[k][e];
        }
        #pragma unroll
        for (int k = 0; k < K_; k++)
            for (int off = 32; off; off >>= 1) s[k] += __shfl_xor(s[k], off);
        float sc[K_];
        float m = NEGINF;
        #pragma unroll
        for (int k = 0; k < K_; k++) { sc[k] = s[k] * SCALE_; m = fmaxf(m, sc[k]); }
        float p[K_], ssum = 0.f;
        #pragma unroll
        for (int k = 0; k < K_; k++) { p[k] = expf(sc[k] - m); ssum += p[k]; }
        float inv = 1.f / ssum;
        float* zp = z + ((size_t)b*T_ + t)*D_;
        #pragma unroll
        for (int r = 0; r < 8; r++) {
            int e = lane + r*64;
            float a = 0.f;
            #pragma unroll
            for (int k = 0; k < K_; k++) a += p[k] * vgs[k][e];
            zp[e] = a * inv;
        }
    }
}

extern "C" void kernel_launch(void* const* d_in, const int* in_sizes, int n_in,
                              void* d_out, int out_size, void* d_ws, size_t ws_size,
                              hipStream_t stream)
{
    const float* X_write = (const float*)d_in[0];
    const float* X_read  = (const float*)d_in[1];
    const float* slots   = (const float*)d_in[2];
    const float* W0      = (const float*)d_in[3];
    const float* lnw_w   = (const float*)d_in[4];
    const float* lnw_b   = (const float*)d_in[5];
    const float* W_V     = (const float*)d_in[6];
    const float* W_K_slot= (const float*)d_in[7];
    const float* skb     = (const float*)d_in[8];
    const float* Wg      = (const float*)d_in[9];
    const float* Wgb     = (const float*)d_in[10];
    const float* lns_w   = (const float*)d_in[11];
    const float* lns_b   = (const float*)d_in[12];
    const float* WsQ     = (const float*)d_in[13];
    const float* WsK     = (const float*)d_in[14];
    const float* WsV     = (const float*)d_in[15];
    const float* lambda_ = (const float*)d_in[16];
    const float* WQr     = (const float*)d_in[17];
    const float* WKr     = (const float*)d_in[18];
    const float* WVr     = (const float*)d_in[19];
    const float* rc      = (const float*)d_in[20];
    const float* temps   = (const float*)d_in[21];

    const size_t NXD = (size_t)B_*T_*D_;           // 16777216
    unsigned short* Xh  = (unsigned short*)d_ws;
    unsigned short* Xl  = Xh + NXD;
    unsigned short* Ch  = Xl + NXD;                // XW0 hi
    unsigned short* Cl  = Ch + NXD;                // XW0 lo
    unsigned short* W0h = Cl + NXD;                // 262144
    unsigned short* W0l = W0h + (size_t)D_*D_;
    float* fscr  = (float*)(W0l + (size_t)D_*D_);
    float* qpart = fscr;                           // B*8*D = 65536
    float* qmean = qpart + (size_t)B_*8*D_;        // 8192
    float* snws  = qmean + (size_t)B_*D_;          // 14336
    float* kq    = snws + (size_t)B_*K_*DB_;       // 57344
    float* vg    = kq + (size_t)B_*K_*D_;          // 57344
    float* tv    = vg + (size_t)B_*K_*D_;          // 256
    int*   ti    = (int*)(tv + 256);
    int*   tj    = (int*)(tv + 512);
    float* cv    = tv + 768;                       // B*64*16 = 16384
    int*   ci    = (int*)(cv + (size_t)B_*64*16);  // 16384
    float* w0p   = (float*)(ci + (size_t)B_*64*16);// B*8*2 = 256
    float* basis = w0p + 256;                      // B*2 = 32

    float* z_out     = (float*)d_out;
    float* slots_out = z_out + NXD;
    float* loss_out  = slots_out + (size_t)B_*K_*DB_;
    float* sal       = z_out;    // scratch inside z region; consumed before z_kernel writes

    ln_kernel<<<dim3(B_*T_), dim3(256), 0, stream>>>(X_write, lnw_w, lnw_b, Xh, Xl);
    w0cvt_kernel<<<dim3(256), dim3(256), 0, stream>>>(W0, W0h, W0l);
    qmean_part_k<<<dim3(B_, 8), dim3(512), 0, stream>>>(X_read, qpart);
    qmean_final_k<<<dim3(B_), dim3(512), 0, stream>>>(qpart, qmean);
    gemm_xw0_mfma<<<dim3(B_*T_/128, D_/128), dim3(256), 0, stream>>>(Xh, Xl, W0h, W0l, Ch, Cl);
    sal_mfma<<<dim3(B_, T_/64), dim3(256), 0, stream>>>(Xh, Xl, Ch, Cl, sal);
    topk_stage1<<<dim3(B_, 64), dim3(256), 0, stream>>>(sal, cv, ci);
    topk_stage2<<<dim3(B_), dim3(256), 0, stream>>>(cv, ci, ti, tj, tv);
    slot_kernel<<<dim3(B_), dim3(1024), 0, stream>>>(Xh, Xl, slots, ti, tj, tv,
        W_V, W_K_slot, skb, Wg, Wgb, lns_w, lns_b, WsQ, WsK, WsV, lambda_, temps,
        snws, slots_out);
    loss_kernel<<<dim3(1), dim3(256), 0, stream>>>(snws, slots, loss_out);
    w0q_part_kernel<<<dim3(B_, 8), dim3(256), 0, stream>>>(qmean, W0, w0p);
    basis_kernel<<<dim3(1), dim3(64), 0, stream>>>(w0p, basis);
    kqvg_kernel<<<dim3(B_, K_), dim3(256), 0, stream>>>(snws, WKr, WQr, WVr, rc, basis, kq, vg);
    z_kernel<<<dim3(B_, T_/64), dim3(256), 0, stream>>>(X_read, kq, vg, z_out);
}

// Round 6
// 312.870 us; speedup vs baseline: 4.1344x; 1.1123x over previous
//
#include <hip/hip_runtime.h>
#include <math.h>

#define B_ 16
#define T_ 2048
#define D_ 512
#define DB_ 128
#define K_ 7
#define TOPK_ 16
#define WIN_ 64

static constexpr float SCALE_ = 0.08838834764831845f;   // 128^-0.5
static constexpr float PHI_ = 1.618033988749895f;
static constexpr float PSI_ = -0.6180339887498949f;
static constexpr float INV_DENOM_ = 0.4472135954999579f; // 1/(PHI-PSI)
static constexpr float NEGV = -1e30f;
static constexpr float NEGINF = -3.402823466e38f;

typedef __attribute__((ext_vector_type(8))) __bf16 bf16x8;
typedef __attribute__((ext_vector_type(8))) unsigned short u16x8;
typedef __attribute__((ext_vector_type(4))) float f32x4;

__device__ inline float softplusf(float x){
    return fmaxf(x, 0.f) + log1pf(expf(-fabsf(x)));
}
__device__ inline unsigned short f2bf(float x){
    unsigned int u = __float_as_uint(x);
    unsigned int r = (u + 0x7FFFu + ((u >> 16) & 1u)) >> 16;
    return (unsigned short)r;
}
__device__ inline float bf2f(unsigned short h){
    return __uint_as_float(((unsigned int)h) << 16);
}
__device__ inline bf16x8 ld_bf8(const unsigned short* p){
    u16x8 r = *(const u16x8*)p;
    return __builtin_bit_cast(bf16x8, r);
}
// packed bf16 convert: D.lo16 = bf16(a), D.hi16 = bf16(b)
__device__ inline unsigned int pkbf(float a, float b){
    unsigned int r;
    asm("v_cvt_pk_bf16_f32 %0, %1, %2" : "=v"(r) : "v"(a), "v"(b));
    return r;
}

// ---------------- prep: LN(X_write)->Xh/Xl  |  W0->hi/lo  |  qmean partials ----------------
__global__ __launch_bounds__(256) void prep_kernel(const float* __restrict__ X,
                                                   const float* __restrict__ w,
                                                   const float* __restrict__ b,
                                                   unsigned short* __restrict__ Xh,
                                                   unsigned short* __restrict__ Xl,
                                                   const float* __restrict__ W0,
                                                   unsigned short* __restrict__ Wh,
                                                   unsigned short* __restrict__ Wl,
                                                   const float* __restrict__ Xr,
                                                   float* __restrict__ qpart)
{
    int bx = blockIdx.x;
    int tid = threadIdx.x;
    if (bx < 32768) {
        // LayerNorm
        int row = bx;
        const float* x = X + (size_t)row * D_;
        float2 v = ((const float2*)x)[tid];
        float s = v.x + v.y, ss = v.x*v.x + v.y*v.y;
        for (int off = 32; off; off >>= 1) { s += __shfl_down(s, off); ss += __shfl_down(ss, off); }
        __shared__ float sh[8];
        int wid = tid >> 6, lane = tid & 63;
        if (lane == 0) { sh[wid] = s; sh[4+wid] = ss; }
        __syncthreads();
        if (tid == 0) {
            float S = sh[0]+sh[1]+sh[2]+sh[3], SS = sh[4]+sh[5]+sh[6]+sh[7];
            float mu = S / (float)D_;
            float var = SS / (float)D_ - mu*mu;
            sh[0] = mu; sh[1] = rsqrtf(var + 1e-5f);
        }
        __syncthreads();
        float mu = sh[0], rs = sh[1];
        float2 wv = ((const float2*)w)[tid];
        float2 bv = ((const float2*)b)[tid];
        float ox = (v.x - mu) * rs * wv.x + bv.x;
        float oy = (v.y - mu) * rs * wv.y + bv.y;
        unsigned short hx = f2bf(ox), hy = f2bf(oy);
        unsigned short lx = f2bf(ox - bf2f(hx)), ly = f2bf(oy - bf2f(hy));
        ((unsigned int*)(Xh + (size_t)row * D_))[tid] = (unsigned int)hx | ((unsigned int)hy << 16);
        ((unsigned int*)(Xl + (size_t)row * D_))[tid] = (unsigned int)lx | ((unsigned int)ly << 16);
    } else if (bx < 33024) {
        // W0 hi/lo
        int gid = (bx - 32768) * 256 + tid;
        float4 v = ((const float4*)W0)[gid];
        unsigned short h0 = f2bf(v.x), h1 = f2bf(v.y), h2 = f2bf(v.z), h3 = f2bf(v.w);
        ushort4 hv = make_ushort4(h0, h1, h2, h3);
        ushort4 lv = make_ushort4(f2bf(v.x - bf2f(h0)), f2bf(v.y - bf2f(h1)),
                                  f2bf(v.z - bf2f(h2)), f2bf(v.w - bf2f(h3)));
        *(ushort4*)&Wh[(size_t)gid*4] = hv;
        *(ushort4*)&Wl[(size_t)gid*4] = lv;
    } else {
        // qmean partials: (b, c) over 32 chunks of 64 rows
        int idx = bx - 33024;
        int b_ = idx >> 5, c = idx & 31;
        const float* base = Xr + ((size_t)(b_*T_ + c*64)) * D_;
        float s0 = 0.f, s1 = 0.f;
        for (int t = 0; t < 64; t++) {
            s0 += base[(size_t)t*D_ + tid];
            s1 += base[(size_t)t*D_ + tid + 256];
        }
        qpart[((size_t)b_*32 + c)*D_ + tid] = s0;
        qpart[((size_t)b_*32 + c)*D_ + tid + 256] = s1;
    }
}

// ---------------- XW0 = Xn @ W0^T  (bf16x3 MFMA, swapped operands, packed epilogue) --------
__global__ __launch_bounds__(256) void gemm_xw0_mfma(const unsigned short* __restrict__ Ah,
                                                     const unsigned short* __restrict__ Al,
                                                     const unsigned short* __restrict__ Wh,
                                                     const unsigned short* __restrict__ Wl,
                                                     unsigned short* __restrict__ Ch,
                                                     unsigned short* __restrict__ Cl)
{
    __shared__ unsigned short sAh[128*40], sAl[128*40], sBh[128*40], sBl[128*40];
    int t0 = blockIdx.x * 128, d0 = blockIdx.y * 128;
    int tid = threadIdx.x;
    int lane = tid & 63, wid = tid >> 6;
    int wr = wid >> 1, wc = wid & 1;
    int fr = lane & 15, kc = (lane >> 4) * 8;

    f32x4 acc[4][4];
    #pragma unroll
    for (int m = 0; m < 4; m++)
        #pragma unroll
        for (int n = 0; n < 4; n++) acc[m][n] = (f32x4){0.f,0.f,0.f,0.f};

    int srow = tid >> 1, skh = (tid & 1) * 16;

    for (int kk = 0; kk < 512; kk += 32) {
        const unsigned short* gAh = Ah + (size_t)(t0 + srow)*512 + kk + skh;
        const unsigned short* gAl = Al + (size_t)(t0 + srow)*512 + kk + skh;
        const unsigned short* gWh = Wh + (size_t)(d0 + srow)*512 + kk + skh;
        const unsigned short* gWl = Wl + (size_t)(d0 + srow)*512 + kk + skh;
        int so = srow*40 + skh;
        *(uint4*)&sAh[so]     = *(const uint4*)(gAh);
        *(uint4*)&sAh[so + 8] = *(const uint4*)(gAh + 8);
        *(uint4*)&sAl[so]     = *(const uint4*)(gAl);
        *(uint4*)&sAl[so + 8] = *(const uint4*)(gAl + 8);
        *(uint4*)&sBh[so]     = *(const uint4*)(gWh);
        *(uint4*)&sBh[so + 8] = *(const uint4*)(gWh + 8);
        *(uint4*)&sBl[so]     = *(const uint4*)(gWl);
        *(uint4*)&sBl[so + 8] = *(const uint4*)(gWl + 8);
        __syncthreads();

        bf16x8 ah[4], al[4], bh[4], bl[4];
        #pragma unroll
        for (int m = 0; m < 4; m++) {
            int r = (wr*64 + m*16 + fr)*40 + kc;
            ah[m] = ld_bf8(&sAh[r]);
            al[m] = ld_bf8(&sAl[r]);
        }
        #pragma unroll
        for (int n = 0; n < 4; n++) {
            int r = (wc*64 + n*16 + fr)*40 + kc;
            bh[n] = ld_bf8(&sBh[r]);
            bl[n] = ld_bf8(&sBl[r]);
        }
        // swapped: first operand = W0 rows (-> D rows = d), second = Xn rows (-> D cols = t)
        #pragma unroll
        for (int m = 0; m < 4; m++)
            #pragma unroll
            for (int n = 0; n < 4; n++) {
                acc[m][n] = __builtin_amdgcn_mfma_f32_16x16x32_bf16(bh[n], ah[m], acc[m][n], 0, 0, 0);
                acc[m][n] = __builtin_amdgcn_mfma_f32_16x16x32_bf16(bh[n], al[m], acc[m][n], 0, 0, 0);
                acc[m][n] = __builtin_amdgcn_mfma_f32_16x16x32_bf16(bl[n], ah[m], acc[m][n], 0, 0, 0);
            }
        __syncthreads();
    }

    // lane holds 4 consecutive d for one t per tile
    #pragma unroll
    for (int m = 0; m < 4; m++) {
        int t = t0 + wr*64 + m*16 + fr;
        #pragma unroll
        for (int n = 0; n < 4; n++) {
            int dbase = d0 + wc*64 + n*16 + (lane >> 4)*4;
            float a0 = acc[m][n][0], a1 = acc[m][n][1], a2 = acc[m][n][2], a3 = acc[m][n][3];
            unsigned int h01 = pkbf(a0, a1), h23 = pkbf(a2, a3);
            float r0 = a0 - __uint_as_float(h01 << 16);
            float r1 = a1 - __uint_as_float(h01 & 0xFFFF0000u);
            float r2 = a2 - __uint_as_float(h23 << 16);
            float r3 = a3 - __uint_as_float(h23 & 0xFFFF0000u);
            unsigned int l01 = pkbf(r0, r1), l23 = pkbf(r2, r3);
            uint2 hv; hv.x = h01; hv.y = h23;
            uint2 lv; lv.x = l01; lv.y = l23;
            *(uint2*)&Ch[(size_t)t*512 + dbase] = hv;
            *(uint2*)&Cl[(size_t)t*512 + dbase] = lv;
        }
    }
}

// ---------------- sal (banded) via bf16x3 MFMA ----------------
__global__ __launch_bounds__(256) void sal_mfma(const unsigned short* __restrict__ Xh,
                                                const unsigned short* __restrict__ Xl,
                                                const unsigned short* __restrict__ Wh,
                                                const unsigned short* __restrict__ Wl,
                                                float* __restrict__ sal)
{
    int b = blockIdx.x, i0 = blockIdx.y * 64;
    __shared__ unsigned short sAh[64*40], sAl[64*40], sBh[128*40], sBl[128*40];
    int tid = threadIdx.x;
    int lane = tid & 63, wc = tid >> 6;
    int fr = lane & 15, kc = (lane >> 4) * 8;

    const unsigned short* XhB = Xh + (size_t)b*T_*D_;
    const unsigned short* XlB = Xl + (size_t)b*T_*D_;
    const unsigned short* WhB = Wh + (size_t)b*T_*D_;
    const unsigned short* WlB = Wl + (size_t)b*T_*D_;

    f32x4 acc[4][2];
    #pragma unroll
    for (int m = 0; m < 4; m++) { acc[m][0] = (f32x4){0.f,0.f,0.f,0.f}; acc[m][1] = (f32x4){0.f,0.f,0.f,0.f}; }

    int arow = tid >> 2, akh = (tid & 3) * 8;
    int brow = tid >> 1, bkh = (tid & 1) * 16;
    int jrow = i0 - 64 + brow;
    const uint4 z4 = make_uint4(0,0,0,0);

    for (int kk = 0; kk < 512; kk += 32) {
        *(uint4*)&sAh[arow*40 + akh] = *(const uint4*)(XhB + (size_t)(i0 + arow)*512 + kk + akh);
        *(uint4*)&sAl[arow*40 + akh] = *(const uint4*)(XlB + (size_t)(i0 + arow)*512 + kk + akh);
        int bo = brow*40 + bkh;
        if (jrow >= 0) {
            const unsigned short* gh = WhB + (size_t)jrow*512 + kk + bkh;
            const unsigned short* gl = WlB + (size_t)jrow*512 + kk + bkh;
            *(uint4*)&sBh[bo]     = *(const uint4*)(gh);
            *(uint4*)&sBh[bo + 8] = *(const uint4*)(gh + 8);
            *(uint4*)&sBl[bo]     = *(const uint4*)(gl);
            *(uint4*)&sBl[bo + 8] = *(const uint4*)(gl + 8);
        } else {
            *(uint4*)&sBh[bo] = z4; *(uint4*)&sBh[bo + 8] = z4;
            *(uint4*)&sBl[bo] = z4; *(uint4*)&sBl[bo + 8] = z4;
        }
        __syncthreads();

        bf16x8 ah[4], al[4], bh[2], bl[2];
        #pragma unroll
        for (int m = 0; m < 4; m++) {
            int r = (m*16 + fr)*40 + kc;
            ah[m] = ld_bf8(&sAh[r]);
            al[m] = ld_bf8(&sAl[r]);
        }
        #pragma unroll
        for (int n = 0; n < 2; n++) {
            int r = (wc*32 + n*16 + fr)*40 + kc;
            bh[n] = ld_bf8(&sBh[r]);
            bl[n] = ld_bf8(&sBl[r]);
        }
        #pragma unroll
        for (int m = 0; m < 4; m++)
            #pragma unroll
            for (int n = 0; n < 2; n++) {
                acc[m][n] = __builtin_amdgcn_mfma_f32_16x16x32_bf16(ah[m], bh[n], acc[m][n], 0, 0, 0);
                acc[m][n] = __builtin_amdgcn_mfma_f32_16x16x32_bf16(ah[m], bl[n], acc[m][n], 0, 0, 0);
                acc[m][n] = __builtin_amdgcn_mfma_f32_16x16x32_bf16(al[m], bh[n], acc[m][n], 0, 0, 0);
            }
        __syncthreads();
    }

    float* salB = sal + (size_t)b*T_*WIN_;
    #pragma unroll
    for (int m = 0; m < 4; m++) {
        #pragma unroll
        for (int n = 0; n < 2; n++) {
            int jl = wc*32 + n*16 + fr;
            #pragma unroll
            for (int r = 0; r < 4; r++) {
                int il = m*16 + (lane >> 4)*4 + r;
                int o = il - jl + 64;
                if (o >= 1 && o <= 64) {
                    int jg = i0 - 64 + jl;
                    salB[(size_t)(i0 + il)*WIN_ + (o - 1)] = (jg >= 0) ? acc[m][n][r] : NEGV;
                }
            }
        }
    }
}

// ---------------- top-16: stage 1, per (batch, chunk) per-wave top-16, barrier-free -------
__global__ __launch_bounds__(256) void topk_stage1(const float* __restrict__ sal,
                                                   float* __restrict__ cv, int* __restrict__ ci)
{
    int b = blockIdx.x, c = blockIdx.y;
    const float* s = sal + (size_t)b*(T_*WIN_) + (size_t)c*2048;
    int base = c*2048;
    int tid = threadIdx.x;
    int lane = tid & 63, wvi = tid >> 6;
    // per-thread sorted 8 (value desc, idx asc)
    float lv[8]; int li[8];
    #pragma unroll
    for (int k = 0; k < 8; k++) { lv[k] = NEGINF; li[k] = 0x7FFFFFFF; }
    #pragma unroll
    for (int r = 0; r < 8; r++) {
        int p = tid + r*256;
        float v = s[p];
        int idx = base + p;
        if (v > lv[7]) {
            int k = 7;
            while (k > 0 && lv[k-1] < v) { lv[k] = lv[k-1]; li[k] = li[k-1]; k--; }
            lv[k] = v; li[k] = idx;
        }
    }
    // per-wave extract top-16 via shuffle argmax
    float* cvo = cv + (((size_t)b*64 + c)*64) + wvi*16;
    int*   cio = ci + (((size_t)b*64 + c)*64) + wvi*16;
    int head = 0;
    for (int r = 0; r < 16; r++) {
        float bv = (head < 8) ? lv[head] : NEGINF;
        int   bi = (head < 8) ? li[head] : 0x7FFFFFFF;
        float wv_ = bv; int wi = bi;
        #pragma unroll
        for (int off = 1; off < 64; off <<= 1) {
            float v2 = __shfl_xor(wv_, off);
            int   i2 = __shfl_xor(wi, off);
            if (v2 > wv_ || (v2 == wv_ && i2 < wi)) { wv_ = v2; wi = i2; }
        }
        if (bv == wv_ && bi == wi) head++;
        if (lane == 0) { cvo[r] = wv_; cio[r] = wi; }
    }
}

// ---------------- slot pipeline (per batch, 1024 thr): topk-merge + slot + loss partials --
__global__ __launch_bounds__(1024) void slot_kernel(
    const unsigned short* __restrict__ Xh, const unsigned short* __restrict__ Xl,
    const float* __restrict__ slots_in,
    const float* __restrict__ cv, const int* __restrict__ ci,
    const float* __restrict__ W_V, const float* __restrict__ W_K_slot, const float* __restrict__ skb,
    const float* __restrict__ Wg, const float* __restrict__ Wgb,
    const float* __restrict__ lnw, const float* __restrict__ lnb,
    const float* __restrict__ WsQ, const float* __restrict__ WsK, const float* __restrict__ WsV,
    const float* __restrict__ lambda_, const float* __restrict__ temps,
    float* __restrict__ snws, float* __restrict__ out_slots,
    float* __restrict__ lpP, float* __restrict__ lpD)
{
    int b = blockIdx.x, tid = threadIdx.x;
    int lane = tid & 63, wvi = tid >> 6;        // 16 waves
    __shared__ float alpha[16];
    __shared__ int   tis[16], tjs[16];
    __shared__ float tvv[16]; __shared__ int tii[16];
    __shared__ float scv[256]; __shared__ int sci[256];
    __shared__ float y[D_];
    __shared__ float part[8][DB_];
    __shared__ float pf[1024];
    __shared__ float Rt[DB_];
    __shared__ float sl[K_][DB_];
    __shared__ float upd[K_][DB_];
    __shared__ float Bn[K_][DB_];
    __shared__ float qq[K_][DB_], kk2[K_][DB_], vv[K_][DB_];
    __shared__ float snsh[K_][DB_];
    __shared__ float swv[K_], compat[K_], mu7[K_], rs7[K_], nr7[K_], ldv[K_];
    __shared__ float sa[K_][K_];

    for (int p = tid; p < K_*DB_; p += 1024) sl[p>>7][p&127] = slots_in[(size_t)b*K_*DB_ + p];

    // ---- top-16 merge over 4096 candidates ----
    {
        const float* cvb = cv + (size_t)b*4096;
        const int*   cib = ci + (size_t)b*4096;
        float lv[4]; int li[4];
        #pragma unroll
        for (int k = 0; k < 4; k++) { lv[k] = NEGINF; li[k] = 0x7FFFFFFF; }
        #pragma unroll
        for (int r = 0; r < 4; r++) {
            int p = tid + r*1024;
            float v = cvb[p];
            int idx = cib[p];
            if (v > lv[3] || (v == lv[3] && idx < li[3])) {
                int k = 3;
                while (k > 0 && (lv[k-1] < v || (lv[k-1] == v && li[k-1] > idx))) {
                    lv[k] = lv[k-1]; li[k] = li[k-1]; k--;
                }
                lv[k] = v; li[k] = idx;
            }
        }
        int head = 0;
        for (int r = 0; r < 16; r++) {
            float bv = (head < 4) ? lv[head] : NEGINF;
            int   bi = (head < 4) ? li[head] : 0x7FFFFFFF;
            float wv_ = bv; int wi = bi;
            #pragma unroll
            for (int off = 1; off < 64; off <<= 1) {
                float v2 = __shfl_xor(wv_, off);
                int   i2 = __shfl_xor(wi, off);
                if (v2 > wv_ || (v2 == wv_ && i2 < wi)) { wv_ = v2; wi = i2; }
            }
            if (bv == wv_ && bi == wi) head++;
            if (lane == 0) { scv[wvi*16 + r] = wv_; sci[wvi*16 + r] = wi; }
        }
        __syncthreads();
        if (wvi == 0) {
            float mv[4]; int mi[4];
            #pragma unroll
            for (int k = 0; k < 4; k++) { mv[k] = NEGINF; mi[k] = 0x7FFFFFFF; }
            #pragma unroll
            for (int r = 0; r < 4; r++) {
                int p = lane + r*64;
                float v = scv[p]; int idx = sci[p];
                if (v > mv[3] || (v == mv[3] && idx < mi[3])) {
                    int k = 3;
                    while (k > 0 && (mv[k-1] < v || (mv[k-1] == v && mi[k-1] > idx))) {
                        mv[k] = mv[k-1]; mi[k] = mi[k-1]; k--;
                    }
                    mv[k] = v; mi[k] = idx;
                }
            }
            int head2 = 0;
            for (int r = 0; r < 16; r++) {
                float bv = (head2 < 4) ? mv[head2] : NEGINF;
                int   bi = (head2 < 4) ? mi[head2] : 0x7FFFFFFF;
                float wv_ = bv; int wi = bi;
                #pragma unroll
                for (int off = 1; off < 64; off <<= 1) {
                    float v2 = __shfl_xor(wv_, off);
                    int   i2 = __shfl_xor(wi, off);
                    if (v2 > wv_ || (v2 == wv_ && i2 < wi)) { wv_ = v2; wi = i2; }
                }
                if (bv == wv_ && bi == wi) head2++;
                if (lane == 0) { tvv[r] = wv_; tii[r] = wi; }
            }
        }
        __syncthreads();
    }
    if (tid < 16) {
        float v = tvv[tid];
        int flat = tii[tid];
        tis[tid] = flat >> 6;
        tjs[tid] = (flat >> 6) - ((flat & 63) + 1);
        float m = v;
        #pragma unroll
        for (int off = 8; off; off >>= 1) m = fmaxf(m, __shfl_xor(m, off, 16));
        float e = expf(v - m);
        float s = e;
        #pragma unroll
        for (int off = 8; off; off >>= 1) s += __shfl_xor(s, off, 16);
        alpha[tid] = e / s;
    }
    __syncthreads();

    // y[e] = sum_k alpha_k (Xn[i_k,e] - Xn[j_k,e])
    if (tid < D_) {
        float acc = 0.f;
        #pragma unroll
        for (int k = 0; k < 16; k++) {
            int i = tis[k], j = tjs[k];
            float xi = bf2f(Xh[((size_t)b*T_ + i)*D_ + tid]) + bf2f(Xl[((size_t)b*T_ + i)*D_ + tid]);
            float xj = bf2f(Xh[((size_t)b*T_ + j)*D_ + tid]) + bf2f(Xl[((size_t)b*T_ + j)*D_ + tid]);
            acc += alpha[k] * (xi - xj);
        }
        y[tid] = acc;
    }
    __syncthreads();

    // Rt = y @ W_V
    {
        int g = tid >> 7, d = tid & 127;
        float acc = 0.f;
        int e0 = g * 64;
        for (int e = e0; e < e0 + 64; e++) acc += y[e] * W_V[(size_t)e*DB_ + d];
        part[g][d] = acc;
    }
    __syncthreads();
    if (tid < DB_) {
        float acc = 0.f;
        #pragma unroll
        for (int g = 0; g < 8; g++) acc += part[g][tid];
        Rt[tid] = acc;
    }
    __syncthreads();

    // slot keys * Rt (into qq as scratch)
    if (tid < K_*DB_) {
        int k = tid >> 7, d = tid & 127;
        float acc = skb[k*DB_ + d];
        for (int e = 0; e < DB_; e++) acc += sl[k][e] * W_K_slot[(size_t)e*DB_ + d];
        qq[k][d] = acc * Rt[d];
    }
    __syncthreads();
    if (wvi < K_) {
        float acc = qq[wvi][lane] + qq[wvi][lane + 64];
        #pragma unroll
        for (int off = 32; off; off >>= 1) acc += __shfl_xor(acc, off);
        if (lane == 0) compat[wvi] = acc * SCALE_ * softplusf(temps[wvi]);
    }
    __syncthreads();
    if (tid == 0) {
        float m = compat[0];
        for (int k = 1; k < K_; k++) m = fmaxf(m, compat[k]);
        float ssum = 0.f;
        for (int k = 0; k < K_; k++) { float e = expf(compat[k]-m); swv[k] = e; ssum += e; }
        for (int k = 0; k < K_; k++) swv[k] /= ssum;
    }
    __syncthreads();

    // gate + slots_upd
    if (tid < K_*DB_) {
        int k = tid >> 7, d = tid & 127;
        float swk = swv[k];
        float acc = Wgb[d];
        for (int e = 0; e < DB_; e++) acc += sl[k][e] * Wg[(size_t)e*DB_ + d];
        for (int e = 0; e < DB_; e++) acc += swk * Rt[e] * Wg[(size_t)(DB_+e)*DB_ + d];
        float g = 1.f / (1.f + expf(-acc));
        upd[k][d] = (1.f - g) * sl[k][d] + g * (swk * Rt[d]);
    }
    __syncthreads();

    // strand LN stats
    if (wvi < K_) {
        float v0 = upd[wvi][lane], v1 = upd[wvi][lane + 64];
        float s = v0 + v1, ss = v0*v0 + v1*v1;
        #pragma unroll
        for (int off = 32; off; off >>= 1) { s += __shfl_xor(s, off); ss += __shfl_xor(ss, off); }
        if (lane == 0) {
            float mu = s / (float)DB_;
            mu7[wvi] = mu;
            rs7[wvi] = rsqrtf(ss/(float)DB_ - mu*mu + 1e-5f);
        }
    }
    __syncthreads();
    if (tid < K_*DB_) {
        int k = tid >> 7, d = tid & 127;
        Bn[k][d] = (upd[k][d] - mu7[k]) * rs7[k] * lnw[d] + lnb[d];
    }
    __syncthreads();

    // Q/K/V
    if (tid < K_*DB_) {
        int k = tid >> 7, d = tid & 127;
        float aq = 0.f, ak = 0.f, av = 0.f;
        for (int e = 0; e < DB_; e++) {
            float bn = Bn[k][e];
            aq += bn * WsQ[(size_t)e*DB_ + d];
            ak += bn * WsK[(size_t)e*DB_ + d];
            av += bn * WsV[(size_t)e*DB_ + d];
        }
        qq[k][d] = aq; kk2[k][d] = ak; vv[k][d] = av;
    }
    __syncthreads();

    // sa[q][j]
    if (wvi < K_) {
        int j = lane >> 3, s = lane & 7;
        float acc = 0.f;
        if (j < K_) {
            int e0 = s * 16;
            for (int e = e0; e < e0 + 16; e++) acc += qq[wvi][e] * kk2[j][e];
        }
        #pragma unroll
        for (int off = 4; off; off >>= 1) acc += __shfl_xor(acc, off, 8);
        if (s == 0 && j < K_) sa[wvi][j] = acc * SCALE_;
    }
    __syncthreads();
    if (tid < K_) {
        float m = sa[tid][0];
        for (int j = 1; j < K_; j++) m = fmaxf(m, sa[tid][j]);
        float ssum = 0.f;
        for (int j = 0; j < K_; j++) { float e = expf(sa[tid][j]-m); sa[tid][j] = e; ssum += e; }
        for (int j = 0; j < K_; j++) sa[tid][j] /= ssum;
    }
    __syncthreads();

    // ctx + output
    if (tid < K_*DB_) {
        int k = tid >> 7, d = tid & 127;
        float lam = tanhf(lambda_[d]);
        lam = fminf(fmaxf(lam, -0.5f), 0.5f);
        float c = 0.f;
        #pragma unroll
        for (int j = 0; j < K_; j++) c += sa[k][j] * vv[j][d];
        float sn = upd[k][d] + c * lam;
        snsh[k][d] = sn;
        snws[((size_t)b*K_ + k)*DB_ + d] = sn;
        out_slots[((size_t)b*K_ + k)*DB_ + d] = sn;
    }
    __syncthreads();

    // ---- loss partials (per batch) ----
    {
        float dsq = 0.f;
        if (tid < K_*DB_) {
            int k = tid >> 7, d = tid & 127;
            float dd = snsh[k][d] - sl[k][d];
            dsq = dd*dd;
        }
        pf[tid] = dsq;
        if (wvi < K_) {
            float v0 = snsh[wvi][lane], v1 = snsh[wvi][lane + 64];
            float ss = v0*v0 + v1*v1;
            #pragma unroll
            for (int off = 32; off; off >>= 1) ss += __shfl_xor(ss, off);
            if (lane == 0) nr7[wvi] = fmaxf(sqrtf(ss), 1e-12f);
        }
        __syncthreads();
        if (wvi == 0) {
            float s = 0.f;
            #pragma unroll
            for (int q = 0; q < 16; q++) s += pf[lane + q*64];
            #pragma unroll
            for (int off = 32; off; off >>= 1) s += __shfl_xor(s, off);
            if (lane == 0) lpP[b] = s;
        }
        if (wvi >= 1 && wvi <= K_) {
            int q = wvi - 1;
            float accq = 0.f;
            for (int j = 0; j < K_; j++) {
                if (j == q) continue;
                float dt = snsh[q][lane]*snsh[j][lane] + snsh[q][lane+64]*snsh[j][lane+64];
                #pragma unroll
                for (int off = 32; off; off >>= 1) dt += __shfl_xor(dt, off);
                float cs = dt / (nr7[q] * nr7[j]);
                accq += cs*cs;
            }
            if (lane == 0) ldv[q] = accq;
        }
        __syncthreads();
        if (tid == 0) {
            float s = 0.f;
            for (int q = 0; q < K_; q++) s += ldv[q];
            lpD[b] = s;
        }
    }
}

// ---------------- w0q + phi/psi partials (qmean-final fused): grid (B, 8) ----------------
__global__ __launch_bounds__(256) void w0q_part_kernel(const float* __restrict__ qpart,
                                                       const float* __restrict__ W0,
                                                       float* __restrict__ w0p)
{
    int b = blockIdx.x, c = blockIdx.y, tid = threadIdx.x;
    __shared__ float qm[D_];
    for (int p = tid; p < D_; p += 256) {
        float s = 0.f;
        for (int cc = 0; cc < 32; cc++) s += qpart[((size_t)b*32 + cc)*D_ + p];
        qm[p] = s * (1.f/2048.f);
    }
    __syncthreads();
    int w = tid >> 6, lane = tid & 63;
    float ph = 0.f, ps = 0.f;
    for (int r = 0; r < 16; r++) {
        int d = c*64 + w*16 + r;
        const float* wr = W0 + (size_t)d*D_;
        float s = 0.f;
        #pragma unroll
        for (int q = 0; q < 8; q++) s += qm[lane + q*64] * wr[lane + q*64];
        #pragma unroll
        for (int off = 32; off; off >>= 1) s += __shfl_xor(s, off);
        float phi = (s - PSI_*qm[d]) * INV_DENOM_;
        float psi = (PHI_*qm[d] - s) * INV_DENOM_;
        ph += phi*phi; ps += psi*psi;
    }
    __shared__ float shp[4], shs[4];
    if (lane == 0) { shp[w] = ph; shs[w] = ps; }
    __syncthreads();
    if (tid == 0) {
        w0p[((size_t)b*8 + c)*2 + 0] = shp[0]+shp[1]+shp[2]+shp[3];
        w0p[((size_t)b*8 + c)*2 + 1] = shs[0]+shs[1]+shs[2]+shs[3];
    }
}

// ---------------- kq & vg (+basis inline, +loss finalize): grid (B, K) ----------------
__global__ __launch_bounds__(256) void kqvg_kernel(
    const float* __restrict__ sn, const float* __restrict__ WKr,
    const float* __restrict__ WQr, const float* __restrict__ WVr,
    const float* __restrict__ rc, const float* __restrict__ w0p,
    const float* __restrict__ lpP, const float* __restrict__ lpD,
    float* __restrict__ kq, float* __restrict__ vg, float* __restrict__ loss_out)
{
    int b = blockIdx.x, k = blockIdx.y, tid = threadIdx.x;
    if (b == 0 && k == 0 && tid == 0) {
        float s = 0.f, s2 = 0.f;
        for (int bb = 0; bb < B_; bb++) { s += lpP[bb]; s2 += lpD[bb]; }
        loss_out[0] = s / (float)(B_*K_*DB_);
        loss_out[1] = s2 / (float)(B_*(K_*K_-K_));
    }
    float P = 0.f, Q = 0.f;
    #pragma unroll
    for (int c = 0; c < 8; c++) {
        P += w0p[((size_t)b*8 + c)*2 + 0];
        Q += w0p[((size_t)b*8 + c)*2 + 1];
    }
    float pm = sqrtf(P), qm2 = sqrtf(Q);
    float tot = pm + qm2 + 1e-6f;
    float b1 = pm / tot, b2 = qm2 / tot;

    __shared__ float sl[DB_], kr[DB_];
    if (tid < DB_) sl[tid] = sn[((size_t)b*K_ + k)*DB_ + tid];
    __syncthreads();
    if (tid < DB_) {
        float a = 0.f;
        for (int e = 0; e < DB_; e++) a += sl[e] * WKr[(size_t)e*DB_ + tid];
        kr[tid] = a;
    }
    __syncthreads();
    #pragma unroll
    for (int rep = 0; rep < 2; rep++) {
        int e = tid + rep*256;
        float a = 0.f;
        const float* wq = WQr + (size_t)e*DB_;
        for (int d = 0; d < DB_; d++) a += kr[d] * wq[d];
        kq[((size_t)b*K_ + k)*D_ + e] = a;
    }
    #pragma unroll
    for (int rep = 0; rep < 2; rep++) {
        int dd = tid + rep*256;
        float a = 0.f;
        for (int e = 0; e < DB_; e++) a += sl[e] * WVr[(size_t)e*D_ + dd];
        float gpre = rc[((size_t)k*3 + 0)*D_ + dd] + b1*rc[((size_t)k*3 + 1)*D_ + dd] + b2*rc[((size_t)k*3 + 2)*D_ + dd];
        float g = tanhf(gpre);
        g = fminf(fmaxf(g, -0.5f), 0.5f);
        vg[((size_t)b*K_ + k)*D_ + dd] = a * g;
    }
}

// ---------------- z: softmax over 7 slots + weighted combine ----------------
__global__ __launch_bounds__(256) void z_kernel(const float* __restrict__ Xr,
                                                const float* __restrict__ kq,
                                                const float* __restrict__ vg,
                                                float* __restrict__ z)
{
    int b = blockIdx.x;
    int t0 = blockIdx.y * 64;
    __shared__ float kqs[K_][D_];
    __shared__ float vgs[K_][D_];
    int tid = threadIdx.x;
    for (int p = tid; p < K_*D_; p += 256) {
        kqs[p>>9][p&511] = kq[(size_t)b*K_*D_ + p];
        vgs[p>>9][p&511] = vg[(size_t)b*K_*D_ + p];
    }
    __syncthreads();
    int lane = tid & 63, w = tid >> 6;
    for (int it = 0; it < 16; it++) {
        int t = t0 + w*16 + it;
        const float* x = Xr + ((size_t)b*T_ + t)*D_;
        float xr[8];
        float s[K_] = {0,0,0,0,0,0,0};
        #pragma unroll
        for (int r = 0; r < 8; r++) {
            int e = lane + r*64;
            xr[r] = x[e];
            #pragma unroll
            for (int k = 0; k < K_; k++) s[k] += xr[r] * kqs[k][e];
        }
        #pragma unroll
        for (int k = 0; k < K_; k++)
            for (int off = 32; off; off >>= 1) s[k] += __shfl_xor(s[k], off);
        float sc[K_];
        float m = NEGINF;
        #pragma unroll
        for (int k = 0; k < K_; k++) { sc[k] = s[k] * SCALE_; m = fmaxf(m, sc[k]); }
        float p[K_], ssum = 0.f;
        #pragma unroll
        for (int k = 0; k < K_; k++) { p[k] = expf(sc[k] - m); ssum += p[k]; }
        float inv = 1.f / ssum;
        float* zp = z + ((size_t)b*T_ + t)*D_;
        #pragma unroll
        for (int r = 0; r < 8; r++) {
            int e = lane + r*64;
            float a = 0.f;
            #pragma unroll
            for (int k = 0; k < K_; k++) a += p[k] * vgs[k][e];
            zp[e] = a * inv;
        }
    }
}

extern "C" void kernel_launch(void* const* d_in, const int* in_sizes, int n_in,
                              void* d_out, int out_size, void* d_ws, size_t ws_size,
                              hipStream_t stream)
{
    const float* X_write = (const float*)d_in[0];
    const float* X_read  = (const float*)d_in[1];
    const float* slots   = (const float*)d_in[2];
    const float* W0      = (const float*)d_in[3];
    const float* lnw_w   = (const float*)d_in[4];
    const float* lnw_b   = (const float*)d_in[5];
    const float* W_V     = (const float*)d_in[6];
    const float* W_K_slot= (const float*)d_in[7];
    const float* skb     = (const float*)d_in[8];
    const float* Wg      = (const float*)d_in[9];
    const float* Wgb     = (const float*)d_in[10];
    const float* lns_w   = (const float*)d_in[11];
    const float* lns_b   = (const float*)d_in[12];
    const float* WsQ     = (const float*)d_in[13];
    const float* WsK     = (const float*)d_in[14];
    const float* WsV     = (const float*)d_in[15];
    const float* lambda_ = (const float*)d_in[16];
    const float* WQr     = (const float*)d_in[17];
    const float* WKr     = (const float*)d_in[18];
    const float* WVr     = (const float*)d_in[19];
    const float* rc      = (const float*)d_in[20];
    const float* temps   = (const float*)d_in[21];

    const size_t NXD = (size_t)B_*T_*D_;           // 16777216
    unsigned short* Xh  = (unsigned short*)d_ws;
    unsigned short* Xl  = Xh + NXD;
    unsigned short* Ch  = Xl + NXD;
    unsigned short* Cl  = Ch + NXD;
    unsigned short* W0h = Cl + NXD;                // 262144
    unsigned short* W0l = W0h + (size_t)D_*D_;
    float* fscr  = (float*)(W0l + (size_t)D_*D_);
    float* qpart = fscr;                           // B*32*D = 262144
    float* w0p   = qpart + (size_t)B_*32*D_;       // 256
    float* snws  = w0p + 256;                      // 14336
    float* kq    = snws + (size_t)B_*K_*DB_;       // 57344
    float* vg    = kq + (size_t)B_*K_*D_;          // 57344
    float* cv    = vg + (size_t)B_*K_*D_;          // B*64*64 = 65536
    int*   ci    = (int*)(cv + (size_t)B_*64*64);  // 65536
    float* lpP   = (float*)(ci + (size_t)B_*64*64);// 16
    float* lpD   = lpP + 16;                       // 16

    float* z_out     = (float*)d_out;
    float* slots_out = z_out + NXD;
    float* loss_out  = slots_out + (size_t)B_*K_*DB_;
    float* sal       = z_out;    // scratch inside z region; consumed before z_kernel writes

    prep_kernel<<<dim3(32768 + 256 + 512), dim3(256), 0, stream>>>(
        X_write, lnw_w, lnw_b, Xh, Xl, W0, W0h, W0l, X_read, qpart);
    gemm_xw0_mfma<<<dim3(B_*T_/128, D_/128), dim3(256), 0, stream>>>(Xh, Xl, W0h, W0l, Ch, Cl);
    sal_mfma<<<dim3(B_, T_/64), dim3(256), 0, stream>>>(Xh, Xl, Ch, Cl, sal);
    topk_stage1<<<dim3(B_, 64), dim3(256), 0, stream>>>(sal, cv, ci);
    slot_kernel<<<dim3(B_), dim3(1024), 0, stream>>>(Xh, Xl, slots, cv, ci,
        W_V, W_K_slot, skb, Wg, Wgb, lns_w, lns_b, WsQ, WsK, WsV, lambda_, temps,
        snws, slots_out, lpP, lpD);
    w0q_part_kernel<<<dim3(B_, 8), dim3(256), 0, stream>>>(qpart, W0, w0p);
    kqvg_kernel<<<dim3(B_, K_), dim3(256), 0, stream>>>(snws, WKr, WQr, WVr, rc, w0p,
        lpP, lpD, kq, vg, loss_out);
    z_kernel<<<dim3(B_, T_/64), dim3(256), 0, stream>>>(X_read, kq, vg, z_out);
}

// Round 7
// 304.222 us; speedup vs baseline: 4.2519x; 1.0284x over previous
//
#include <hip/hip_runtime.h>
#include <math.h>

#define B_ 16
#define T_ 2048
#define D_ 512
#define DB_ 128
#define K_ 7
#define TOPK_ 16
#define WIN_ 64

static constexpr float SCALE_ = 0.08838834764831845f;   // 128^-0.5
static constexpr float PHI_ = 1.618033988749895f;
static constexpr float PSI_ = -0.6180339887498949f;
static constexpr float INV_DENOM_ = 0.4472135954999579f; // 1/(PHI-PSI)
static constexpr float NEGV = -1e30f;
static constexpr float NEGINF = -3.402823466e38f;

typedef __attribute__((ext_vector_type(8))) __bf16 bf16x8;
typedef __attribute__((ext_vector_type(8))) unsigned short u16x8;
typedef __attribute__((ext_vector_type(4))) float f32x4;

__device__ inline float softplusf(float x){
    return fmaxf(x, 0.f) + log1pf(expf(-fabsf(x)));
}
__device__ inline unsigned short f2bf(float x){
    unsigned int u = __float_as_uint(x);
    unsigned int r = (u + 0x7FFFu + ((u >> 16) & 1u)) >> 16;
    return (unsigned short)r;
}
__device__ inline float bf2f(unsigned short h){
    return __uint_as_float(((unsigned int)h) << 16);
}
__device__ inline bf16x8 ld_bf8(const unsigned short* p){
    u16x8 r = *(const u16x8*)p;
    return __builtin_bit_cast(bf16x8, r);
}
// packed bf16 convert: D.lo16 = bf16(a), D.hi16 = bf16(b)
__device__ inline unsigned int pkbf(float a, float b){
    unsigned int r;
    asm("v_cvt_pk_bf16_f32 %0, %1, %2" : "=v"(r) : "v"(a), "v"(b));
    return r;
}
// async global->LDS 16B per lane: dest = uniform lds base + lane*16
typedef __attribute__((address_space(3))) unsigned int as3_u32;
typedef const __attribute__((address_space(1))) unsigned int as1_u32c;
__device__ inline void gload16(const void* g, void* l){
    __builtin_amdgcn_global_load_lds((as1_u32c*)g, (as3_u32*)l, 16, 0, 0);
}

// ---------------- prep: LN(X_write)->Xh/Xl  |  W0->hi/lo  |  qmean partials ----------------
__global__ __launch_bounds__(256) void prep_kernel(const float* __restrict__ X,
                                                   const float* __restrict__ w,
                                                   const float* __restrict__ b,
                                                   unsigned short* __restrict__ Xh,
                                                   unsigned short* __restrict__ Xl,
                                                   const float* __restrict__ W0,
                                                   unsigned short* __restrict__ Wh,
                                                   unsigned short* __restrict__ Wl,
                                                   const float* __restrict__ Xr,
                                                   float* __restrict__ qpart)
{
    int bx = blockIdx.x;
    int tid = threadIdx.x;
    if (bx < 32768) {
        int row = bx;
        const float* x = X + (size_t)row * D_;
        float2 v = ((const float2*)x)[tid];
        float s = v.x + v.y, ss = v.x*v.x + v.y*v.y;
        for (int off = 32; off; off >>= 1) { s += __shfl_down(s, off); ss += __shfl_down(ss, off); }
        __shared__ float sh[8];
        int wid = tid >> 6, lane = tid & 63;
        if (lane == 0) { sh[wid] = s; sh[4+wid] = ss; }
        __syncthreads();
        if (tid == 0) {
            float S = sh[0]+sh[1]+sh[2]+sh[3], SS = sh[4]+sh[5]+sh[6]+sh[7];
            float mu = S / (float)D_;
            float var = SS / (float)D_ - mu*mu;
            sh[0] = mu; sh[1] = rsqrtf(var + 1e-5f);
        }
        __syncthreads();
        float mu = sh[0], rs = sh[1];
        float2 wv = ((const float2*)w)[tid];
        float2 bv = ((const float2*)b)[tid];
        float ox = (v.x - mu) * rs * wv.x + bv.x;
        float oy = (v.y - mu) * rs * wv.y + bv.y;
        unsigned short hx = f2bf(ox), hy = f2bf(oy);
        unsigned short lx = f2bf(ox - bf2f(hx)), ly = f2bf(oy - bf2f(hy));
        ((unsigned int*)(Xh + (size_t)row * D_))[tid] = (unsigned int)hx | ((unsigned int)hy << 16);
        ((unsigned int*)(Xl + (size_t)row * D_))[tid] = (unsigned int)lx | ((unsigned int)ly << 16);
    } else if (bx < 33024) {
        int gid = (bx - 32768) * 256 + tid;
        float4 v = ((const float4*)W0)[gid];
        unsigned short h0 = f2bf(v.x), h1 = f2bf(v.y), h2 = f2bf(v.z), h3 = f2bf(v.w);
        ushort4 hv = make_ushort4(h0, h1, h2, h3);
        ushort4 lv = make_ushort4(f2bf(v.x - bf2f(h0)), f2bf(v.y - bf2f(h1)),
                                  f2bf(v.z - bf2f(h2)), f2bf(v.w - bf2f(h3)));
        *(ushort4*)&Wh[(size_t)gid*4] = hv;
        *(ushort4*)&Wl[(size_t)gid*4] = lv;
    } else {
        int idx = bx - 33024;
        int b_ = idx >> 5, c = idx & 31;
        const float* base = Xr + ((size_t)(b_*T_ + c*64)) * D_;
        float s0 = 0.f, s1 = 0.f;
        for (int t = 0; t < 64; t++) {
            s0 += base[(size_t)t*D_ + tid];
            s1 += base[(size_t)t*D_ + tid + 256];
        }
        qpart[((size_t)b_*32 + c)*D_ + tid] = s0;
        qpart[((size_t)b_*32 + c)*D_ + tid + 256] = s1;
    }
}

// ---------------- XW0 = Xn @ W0^T  (bf16x3 MFMA, gload_lds staging, swizzled LDS, f32 out) --
// LDS layout: row stride 32 shorts (64B). chunk c (16B) of row r stored at slot (c+(r>>1))&3.
__global__ __launch_bounds__(256) void gemm_xw0_mfma(const unsigned short* __restrict__ Ah,
                                                     const unsigned short* __restrict__ Al,
                                                     const unsigned short* __restrict__ Wh,
                                                     const unsigned short* __restrict__ Wl,
                                                     float* __restrict__ Cf)
{
    __shared__ __align__(16) unsigned short sAh[128*32], sAl[128*32], sBh[128*32], sBl[128*32];
    int t0 = blockIdx.x * 128, d0 = blockIdx.y * 128;
    int tid = threadIdx.x;
    int lane = tid & 63, wid = tid >> 6;
    int wr = wid >> 1, wc = wid & 1;
    int fr = lane & 15;
    // swizzled read chunk (shorts offset within row)
    int kc2 = ((((lane >> 4) + (fr >> 1)) & 3) * 8);

    f32x4 acc[4][4];
    #pragma unroll
    for (int m = 0; m < 4; m++)
        #pragma unroll
        for (int n = 0; n < 4; n++) acc[m][n] = (f32x4){0.f,0.f,0.f,0.f};

    // staging: wave wid stages one array. lane ln -> row 16i+(ln>>2), slot ln&3,
    // global chunk c = ((ln&3) - ((ln>>3)&3)) & 3  (inverse swizzle on source)
    const unsigned short* gs = (wid==0) ? Ah : (wid==1) ? Al : (wid==2) ? Wh : Wl;
    unsigned short* ls = (wid==0) ? sAh : (wid==1) ? sAl : (wid==2) ? sBh : sBl;
    int rowoff = (wid < 2) ? t0 : d0;
    int cch = ((lane & 3) - ((lane >> 3) & 3)) & 3;
    const unsigned short* gbase = gs + (size_t)(rowoff + (lane >> 2))*512 + cch*8;

    for (int kk = 0; kk < 512; kk += 32) {
        #pragma unroll
        for (int i = 0; i < 8; i++)
            gload16(gbase + (size_t)(16*i)*512 + kk, ls + i*512);
        __syncthreads();

        bf16x8 ahf[4], alf[4], bhf[4], blf[4];
        #pragma unroll
        for (int m = 0; m < 4; m++) {
            int r = (wr*64 + m*16 + fr)*32 + kc2;
            ahf[m] = ld_bf8(&sAh[r]);
            alf[m] = ld_bf8(&sAl[r]);
        }
        #pragma unroll
        for (int n = 0; n < 4; n++) {
            int r = (wc*64 + n*16 + fr)*32 + kc2;
            bhf[n] = ld_bf8(&sBh[r]);
            blf[n] = ld_bf8(&sBl[r]);
        }
        #pragma unroll
        for (int m = 0; m < 4; m++)
            #pragma unroll
            for (int n = 0; n < 4; n++) {
                acc[m][n] = __builtin_amdgcn_mfma_f32_16x16x32_bf16(bhf[n], ahf[m], acc[m][n], 0, 0, 0);
                acc[m][n] = __builtin_amdgcn_mfma_f32_16x16x32_bf16(bhf[n], alf[m], acc[m][n], 0, 0, 0);
                acc[m][n] = __builtin_amdgcn_mfma_f32_16x16x32_bf16(blf[n], ahf[m], acc[m][n], 0, 0, 0);
            }
        __syncthreads();
    }

    // swapped orientation: lane holds 4 consecutive d (float4) for one t
    #pragma unroll
    for (int m = 0; m < 4; m++) {
        int t = t0 + wr*64 + m*16 + fr;
        #pragma unroll
        for (int n = 0; n < 4; n++) {
            int dbase = d0 + wc*64 + n*16 + (lane >> 4)*4;
            *(f32x4*)&Cf[(size_t)t*512 + dbase] = acc[m][n];
        }
    }
}

// ---------------- sal (banded) via bf16x3 MFMA, swizzled LDS, f32 XW0 input ----------------
__global__ __launch_bounds__(256) void sal_mfma(const unsigned short* __restrict__ Xh,
                                                const unsigned short* __restrict__ Xl,
                                                const float* __restrict__ Cf,
                                                float* __restrict__ sal)
{
    int b = blockIdx.x, i0 = blockIdx.y * 64;
    __shared__ __align__(16) unsigned short sAh[64*32], sAl[64*32], sBh[128*32], sBl[128*32];
    int tid = threadIdx.x;
    int lane = tid & 63, wcw = tid >> 6;
    int fr = lane & 15;
    int kc2 = ((((lane >> 4) + (fr >> 1)) & 3) * 8);

    const unsigned short* XhB = Xh + (size_t)b*T_*D_;
    const unsigned short* XlB = Xl + (size_t)b*T_*D_;
    const float* CfB = Cf + (size_t)b*T_*D_;

    f32x4 acc[4][2];
    #pragma unroll
    for (int m = 0; m < 4; m++) { acc[m][0] = (f32x4){0.f,0.f,0.f,0.f}; acc[m][1] = (f32x4){0.f,0.f,0.f,0.f}; }

    // A staging: thread -> (row ar, chunk ac), swizzled slot
    int ar = tid >> 2, ac = tid & 3;
    int aslot = (ac + (ar >> 1)) & 3;
    // B staging: thread -> (row brow, half h -> chunks 2h, 2h+1), f32 -> hi/lo bf16
    int brow = tid >> 1, bhh = tid & 1;
    int jrow = i0 - 64 + brow;

    for (int kk = 0; kk < 512; kk += 32) {
        *(uint4*)&sAh[ar*32 + aslot*8] = *(const uint4*)(XhB + (size_t)(i0 + ar)*512 + kk + ac*8);
        *(uint4*)&sAl[ar*32 + aslot*8] = *(const uint4*)(XlB + (size_t)(i0 + ar)*512 + kk + ac*8);
        #pragma unroll
        for (int cc = 0; cc < 2; cc++) {
            int c = 2*bhh + cc;
            int slot = (c + (brow >> 1)) & 3;
            uint4 hv, lv;
            if (jrow >= 0) {
                const float* src = CfB + (size_t)jrow*512 + kk + c*8;
                float4 v0 = *(const float4*)src;
                float4 v1 = *(const float4*)(src + 4);
                unsigned int h01 = pkbf(v0.x, v0.y), h23 = pkbf(v0.z, v0.w);
                unsigned int h45 = pkbf(v1.x, v1.y), h67 = pkbf(v1.z, v1.w);
                float r0 = v0.x - __uint_as_float(h01 << 16);
                float r1 = v0.y - __uint_as_float(h01 & 0xFFFF0000u);
                float r2 = v0.z - __uint_as_float(h23 << 16);
                float r3 = v0.w - __uint_as_float(h23 & 0xFFFF0000u);
                float r4 = v1.x - __uint_as_float(h45 << 16);
                float r5 = v1.y - __uint_as_float(h45 & 0xFFFF0000u);
                float r6 = v1.z - __uint_as_float(h67 << 16);
                float r7 = v1.w - __uint_as_float(h67 & 0xFFFF0000u);
                hv.x = h01; hv.y = h23; hv.z = h45; hv.w = h67;
                lv.x = pkbf(r0, r1); lv.y = pkbf(r2, r3); lv.z = pkbf(r4, r5); lv.w = pkbf(r6, r7);
            } else {
                hv = make_uint4(0,0,0,0); lv = make_uint4(0,0,0,0);
            }
            *(uint4*)&sBh[brow*32 + slot*8] = hv;
            *(uint4*)&sBl[brow*32 + slot*8] = lv;
        }
        __syncthreads();

        bf16x8 ahf[4], alf[4], bhf[2], blf[2];
        #pragma unroll
        for (int m = 0; m < 4; m++) {
            int r = (m*16 + fr)*32 + kc2;
            ahf[m] = ld_bf8(&sAh[r]);
            alf[m] = ld_bf8(&sAl[r]);
        }
        #pragma unroll
        for (int n = 0; n < 2; n++) {
            int r = (wcw*32 + n*16 + fr)*32 + kc2;
            bhf[n] = ld_bf8(&sBh[r]);
            blf[n] = ld_bf8(&sBl[r]);
        }
        #pragma unroll
        for (int m = 0; m < 4; m++)
            #pragma unroll
            for (int n = 0; n < 2; n++) {
                acc[m][n] = __builtin_amdgcn_mfma_f32_16x16x32_bf16(ahf[m], bhf[n], acc[m][n], 0, 0, 0);
                acc[m][n] = __builtin_amdgcn_mfma_f32_16x16x32_bf16(ahf[m], blf[n], acc[m][n], 0, 0, 0);
                acc[m][n] = __builtin_amdgcn_mfma_f32_16x16x32_bf16(alf[m], bhf[n], acc[m][n], 0, 0, 0);
            }
        __syncthreads();
    }

    float* salB = sal + (size_t)b*T_*WIN_;
    #pragma unroll
    for (int m = 0; m < 4; m++) {
        #pragma unroll
        for (int n = 0; n < 2; n++) {
            int jl = wcw*32 + n*16 + fr;
            #pragma unroll
            for (int r = 0; r < 4; r++) {
                int il = m*16 + (lane >> 4)*4 + r;
                int o = il - jl + 64;
                if (o >= 1 && o <= 64) {
                    int jg = i0 - 64 + jl;
                    salB[(size_t)(i0 + il)*WIN_ + (o - 1)] = (jg >= 0) ? acc[m][n][r] : NEGV;
                }
            }
        }
    }
}

// ---------------- top-16: stage 1, per (batch, chunk) per-wave top-16, barrier-free -------
__global__ __launch_bounds__(256) void topk_stage1(const float* __restrict__ sal,
                                                   float* __restrict__ cv, int* __restrict__ ci)
{
    int b = blockIdx.x, c = blockIdx.y;
    const float* s = sal + (size_t)b*(T_*WIN_) + (size_t)c*2048;
    int base = c*2048;
    int tid = threadIdx.x;
    int lane = tid & 63, wvi = tid >> 6;
    float lv[8]; int li[8];
    #pragma unroll
    for (int k = 0; k < 8; k++) { lv[k] = NEGINF; li[k] = 0x7FFFFFFF; }
    #pragma unroll
    for (int r = 0; r < 8; r++) {
        int p = tid + r*256;
        float v = s[p];
        int idx = base + p;
        if (v > lv[7]) {
            int k = 7;
            while (k > 0 && lv[k-1] < v) { lv[k] = lv[k-1]; li[k] = li[k-1]; k--; }
            lv[k] = v; li[k] = idx;
        }
    }
    float* cvo = cv + (((size_t)b*64 + c)*64) + wvi*16;
    int*   cio = ci + (((size_t)b*64 + c)*64) + wvi*16;
    int head = 0;
    for (int r = 0; r < 16; r++) {
        float bv = (head < 8) ? lv[head] : NEGINF;
        int   bi = (head < 8) ? li[head] : 0x7FFFFFFF;
        float wv_ = bv; int wi = bi;
        #pragma unroll
        for (int off = 1; off < 64; off <<= 1) {
            float v2 = __shfl_xor(wv_, off);
            int   i2 = __shfl_xor(wi, off);
            if (v2 > wv_ || (v2 == wv_ && i2 < wi)) { wv_ = v2; wi = i2; }
        }
        if (bv == wv_ && bi == wi) head++;
        if (lane == 0) { cvo[r] = wv_; cio[r] = wi; }
    }
}

// ---------------- slot pipeline (per batch, 1024 thr): topk-merge + slot + loss partials --
__global__ __launch_bounds__(1024) void slot_kernel(
    const unsigned short* __restrict__ Xh, const unsigned short* __restrict__ Xl,
    const float* __restrict__ slots_in,
    const float* __restrict__ cv, const int* __restrict__ ci,
    const float* __restrict__ W_V, const float* __restrict__ W_K_slot, const float* __restrict__ skb,
    const float* __restrict__ Wg, const float* __restrict__ Wgb,
    const float* __restrict__ lnw, const float* __restrict__ lnb,
    const float* __restrict__ WsQ, const float* __restrict__ WsK, const float* __restrict__ WsV,
    const float* __restrict__ lambda_, const float* __restrict__ temps,
    float* __restrict__ snws, float* __restrict__ out_slots,
    float* __restrict__ lpP, float* __restrict__ lpD)
{
    int b = blockIdx.x, tid = threadIdx.x;
    int lane = tid & 63, wvi = tid >> 6;        // 16 waves
    __shared__ float alpha[16];
    __shared__ int   tis[16], tjs[16];
    __shared__ float tvv[16]; __shared__ int tii[16];
    __shared__ float scv[256]; __shared__ int sci[256];
    __shared__ float y[D_];
    __shared__ float part[8][DB_];
    __shared__ float pf[1024];
    __shared__ float Rt[DB_];
    __shared__ float sl[K_][DB_];
    __shared__ float upd[K_][DB_];
    __shared__ float Bn[K_][DB_];
    __shared__ float qq[K_][DB_], kk2[K_][DB_], vv[K_][DB_];
    __shared__ float snsh[K_][DB_];
    __shared__ float swv[K_], compat[K_], mu7[K_], rs7[K_], nr7[K_], ldv[K_];
    __shared__ float sa[K_][K_];

    for (int p = tid; p < K_*DB_; p += 1024) sl[p>>7][p&127] = slots_in[(size_t)b*K_*DB_ + p];

    // ---- top-16 merge over 4096 candidates ----
    {
        const float* cvb = cv + (size_t)b*4096;
        const int*   cib = ci + (size_t)b*4096;
        float lv[4]; int li[4];
        #pragma unroll
        for (int k = 0; k < 4; k++) { lv[k] = NEGINF; li[k] = 0x7FFFFFFF; }
        #pragma unroll
        for (int r = 0; r < 4; r++) {
            int p = tid + r*1024;
            float v = cvb[p];
            int idx = cib[p];
            if (v > lv[3] || (v == lv[3] && idx < li[3])) {
                int k = 3;
                while (k > 0 && (lv[k-1] < v || (lv[k-1] == v && li[k-1] > idx))) {
                    lv[k] = lv[k-1]; li[k] = li[k-1]; k--;
                }
                lv[k] = v; li[k] = idx;
            }
        }
        int head = 0;
        for (int r = 0; r < 16; r++) {
            float bv = (head < 4) ? lv[head] : NEGINF;
            int   bi = (head < 4) ? li[head] : 0x7FFFFFFF;
            float wv_ = bv; int wi = bi;
            #pragma unroll
            for (int off = 1; off < 64; off <<= 1) {
                float v2 = __shfl_xor(wv_, off);
                int   i2 = __shfl_xor(wi, off);
                if (v2 > wv_ || (v2 == wv_ && i2 < wi)) { wv_ = v2; wi = i2; }
            }
            if (bv == wv_ && bi == wi) head++;
            if (lane == 0) { scv[wvi*16 + r] = wv_; sci[wvi*16 + r] = wi; }
        }
        __syncthreads();
        if (wvi == 0) {
            float mv[4]; int mi[4];
            #pragma unroll
            for (int k = 0; k < 4; k++) { mv[k] = NEGINF; mi[k] = 0x7FFFFFFF; }
            #pragma unroll
            for (int r = 0; r < 4; r++) {
                int p = lane + r*64;
                float v = scv[p]; int idx = sci[p];
                if (v > mv[3] || (v == mv[3] && idx < mi[3])) {
                    int k = 3;
                    while (k > 0 && (mv[k-1] < v || (mv[k-1] == v && mi[k-1] > idx))) {
                        mv[k] = mv[k-1]; mi[k] = mi[k-1]; k--;
                    }
                    mv[k] = v; mi[k] = idx;
                }
            }
            int head2 = 0;
            for (int r = 0; r < 16; r++) {
                float bv = (head2 < 4) ? mv[head2] : NEGINF;
                int   bi = (head2 < 4) ? mi[head2] : 0x7FFFFFFF;
                float wv_ = bv; int wi = bi;
                #pragma unroll
                for (int off = 1; off < 64; off <<= 1) {
                    float v2 = __shfl_xor(wv_, off);
                    int   i2 = __shfl_xor(wi, off);
                    if (v2 > wv_ || (v2 == wv_ && i2 < wi)) { wv_ = v2; wi = i2; }
                }
                if (bv == wv_ && bi == wi) head2++;
                if (lane == 0) { tvv[r] = wv_; tii[r] = wi; }
            }
        }
        __syncthreads();
    }
    if (tid < 16) {
        float v = tvv[tid];
        int flat = tii[tid];
        tis[tid] = flat >> 6;
        tjs[tid] = (flat >> 6) - ((flat & 63) + 1);
        float m = v;
        #pragma unroll
        for (int off = 8; off; off >>= 1) m = fmaxf(m, __shfl_xor(m, off, 16));
        float e = expf(v - m);
        float s = e;
        #pragma unroll
        for (int off = 8; off; off >>= 1) s += __shfl_xor(s, off, 16);
        alpha[tid] = e / s;
    }
    __syncthreads();

    if (tid < D_) {
        float acc = 0.f;
        #pragma unroll
        for (int k = 0; k < 16; k++) {
            int i = tis[k], j = tjs[k];
            float xi = bf2f(Xh[((size_t)b*T_ + i)*D_ + tid]) + bf2f(Xl[((size_t)b*T_ + i)*D_ + tid]);
            float xj = bf2f(Xh[((size_t)b*T_ + j)*D_ + tid]) + bf2f(Xl[((size_t)b*T_ + j)*D_ + tid]);
            acc += alpha[k] * (xi - xj);
        }
        y[tid] = acc;
    }
    __syncthreads();

    {
        int g = tid >> 7, d = tid & 127;
        float acc = 0.f;
        int e0 = g * 64;
        for (int e = e0; e < e0 + 64; e++) acc += y[e] * W_V[(size_t)e*DB_ + d];
        part[g][d] = acc;
    }
    __syncthreads();
    if (tid < DB_) {
        float acc = 0.f;
        #pragma unroll
        for (int g = 0; g < 8; g++) acc += part[g][tid];
        Rt[tid] = acc;
    }
    __syncthreads();

    if (tid < K_*DB_) {
        int k = tid >> 7, d = tid & 127;
        float acc = skb[k*DB_ + d];
        for (int e = 0; e < DB_; e++) acc += sl[k][e] * W_K_slot[(size_t)e*DB_ + d];
        qq[k][d] = acc * Rt[d];
    }
    __syncthreads();
    if (wvi < K_) {
        float acc = qq[wvi][lane] + qq[wvi][lane + 64];
        #pragma unroll
        for (int off = 32; off; off >>= 1) acc += __shfl_xor(acc, off);
        if (lane == 0) compat[wvi] = acc * SCALE_ * softplusf(temps[wvi]);
    }
    __syncthreads();
    if (tid == 0) {
        float m = compat[0];
        for (int k = 1; k < K_; k++) m = fmaxf(m, compat[k]);
        float ssum = 0.f;
        for (int k = 0; k < K_; k++) { float e = expf(compat[k]-m); swv[k] = e; ssum += e; }
        for (int k = 0; k < K_; k++) swv[k] /= ssum;
    }
    __syncthreads();

    if (tid < K_*DB_) {
        int k = tid >> 7, d = tid & 127;
        float swk = swv[k];
        float acc = Wgb[d];
        for (int e = 0; e < DB_; e++) acc += sl[k][e] * Wg[(size_t)e*DB_ + d];
        for (int e = 0; e < DB_; e++) acc += swk * Rt[e] * Wg[(size_t)(DB_+e)*DB_ + d];
        float g = 1.f / (1.f + expf(-acc));
        upd[k][d] = (1.f - g) * sl[k][d] + g * (swk * Rt[d]);
    }
    __syncthreads();

    if (wvi < K_) {
        float v0 = upd[wvi][lane], v1 = upd[wvi][lane + 64];
        float s = v0 + v1, ss = v0*v0 + v1*v1;
        #pragma unroll
        for (int off = 32; off; off >>= 1) { s += __shfl_xor(s, off); ss += __shfl_xor(ss, off); }
        if (lane == 0) {
            float mu = s / (float)DB_;
            mu7[wvi] = mu;
            rs7[wvi] = rsqrtf(ss/(float)DB_ - mu*mu + 1e-5f);
        }
    }
    __syncthreads();
    if (tid < K_*DB_) {
        int k = tid >> 7, d = tid & 127;
        Bn[k][d] = (upd[k][d] - mu7[k]) * rs7[k] * lnw[d] + lnb[d];
    }
    __syncthreads();

    if (tid < K_*DB_) {
        int k = tid >> 7, d = tid & 127;
        float aq = 0.f, ak = 0.f, av = 0.f;
        for (int e = 0; e < DB_; e++) {
            float bn = Bn[k][e];
            aq += bn * WsQ[(size_t)e*DB_ + d];
            ak += bn * WsK[(size_t)e*DB_ + d];
            av += bn * WsV[(size_t)e*DB_ + d];
        }
        qq[k][d] = aq; kk2[k][d] = ak; vv[k][d] = av;
    }
    __syncthreads();

    if (wvi < K_) {
        int j = lane >> 3, s = lane & 7;
        float acc = 0.f;
        if (j < K_) {
            int e0 = s * 16;
            for (int e = e0; e < e0 + 16; e++) acc += qq[wvi][e] * kk2[j][e];
        }
        #pragma unroll
        for (int off = 4; off; off >>= 1) acc += __shfl_xor(acc, off, 8);
        if (s == 0 && j < K_) sa[wvi][j] = acc * SCALE_;
    }
    __syncthreads();
    if (tid < K_) {
        float m = sa[tid][0];
        for (int j = 1; j < K_; j++) m = fmaxf(m, sa[tid][j]);
        float ssum = 0.f;
        for (int j = 0; j < K_; j++) { float e = expf(sa[tid][j]-m); sa[tid][j] = e; ssum += e; }
        for (int j = 0; j < K_; j++) sa[tid][j] /= ssum;
    }
    __syncthreads();

    if (tid < K_*DB_) {
        int k = tid >> 7, d = tid & 127;
        float lam = tanhf(lambda_[d]);
        lam = fminf(fmaxf(lam, -0.5f), 0.5f);
        float c = 0.f;
        #pragma unroll
        for (int j = 0; j < K_; j++) c += sa[k][j] * vv[j][d];
        float sn = upd[k][d] + c * lam;
        snsh[k][d] = sn;
        snws[((size_t)b*K_ + k)*DB_ + d] = sn;
        out_slots[((size_t)b*K_ + k)*DB_ + d] = sn;
    }
    __syncthreads();

    {
        float dsq = 0.f;
        if (tid < K_*DB_) {
            int k = tid >> 7, d = tid & 127;
            float dd = snsh[k][d] - sl[k][d];
            dsq = dd*dd;
        }
        pf[tid] = dsq;
        if (wvi < K_) {
            float v0 = snsh[wvi][lane], v1 = snsh[wvi][lane + 64];
            float ss = v0*v0 + v1*v1;
            #pragma unroll
            for (int off = 32; off; off >>= 1) ss += __shfl_xor(ss, off);
            if (lane == 0) nr7[wvi] = fmaxf(sqrtf(ss), 1e-12f);
        }
        __syncthreads();
        if (wvi == 0) {
            float s = 0.f;
            #pragma unroll
            for (int q = 0; q < 16; q++) s += pf[lane + q*64];
            #pragma unroll
            for (int off = 32; off; off >>= 1) s += __shfl_xor(s, off);
            if (lane == 0) lpP[b] = s;
        }
        if (wvi >= 1 && wvi <= K_) {
            int q = wvi - 1;
            float accq = 0.f;
            for (int j = 0; j < K_; j++) {
                if (j == q) continue;
                float dt = snsh[q][lane]*snsh[j][lane] + snsh[q][lane+64]*snsh[j][lane+64];
                #pragma unroll
                for (int off = 32; off; off >>= 1) dt += __shfl_xor(dt, off);
                float cs = dt / (nr7[q] * nr7[j]);
                accq += cs*cs;
            }
            if (lane == 0) ldv[q] = accq;
        }
        __syncthreads();
        if (tid == 0) {
            float s = 0.f;
            for (int q = 0; q < K_; q++) s += ldv[q];
            lpD[b] = s;
        }
    }
}

// ---------------- w0q + phi/psi partials (qmean-final fused): grid (B, 8) ----------------
__global__ __launch_bounds__(256) void w0q_part_kernel(const float* __restrict__ qpart,
                                                       const float* __restrict__ W0,
                                                       float* __restrict__ w0p)
{
    int b = blockIdx.x, c = blockIdx.y, tid = threadIdx.x;
    __shared__ float qm[D_];
    for (int p = tid; p < D_; p += 256) {
        float s = 0.f;
        for (int cc = 0; cc < 32; cc++) s += qpart[((size_t)b*32 + cc)*D_ + p];
        qm[p] = s * (1.f/2048.f);
    }
    __syncthreads();
    int w = tid >> 6, lane = tid & 63;
    float ph = 0.f, ps = 0.f;
    for (int r = 0; r < 16; r++) {
        int d = c*64 + w*16 + r;
        const float* wr = W0 + (size_t)d*D_;
        float s = 0.f;
        #pragma unroll
        for (int q = 0; q < 8; q++) s += qm[lane + q*64] * wr[lane + q*64];
        #pragma unroll
        for (int off = 32; off; off >>= 1) s += __shfl_xor(s, off);
        float phi = (s - PSI_*qm[d]) * INV_DENOM_;
        float psi = (PHI_*qm[d] - s) * INV_DENOM_;
        ph += phi*phi; ps += psi*psi;
    }
    __shared__ float shp[4], shs[4];
    if (lane == 0) { shp[w] = ph; shs[w] = ps; }
    __syncthreads();
    if (tid == 0) {
        w0p[((size_t)b*8 + c)*2 + 0] = shp[0]+shp[1]+shp[2]+shp[3];
        w0p[((size_t)b*8 + c)*2 + 1] = shs[0]+shs[1]+shs[2]+shs[3];
    }
}

// ---------------- kq & vg (+basis inline, +loss finalize): grid (B, K) ----------------
__global__ __launch_bounds__(256) void kqvg_kernel(
    const float* __restrict__ sn, const float* __restrict__ WKr,
    const float* __restrict__ WQr, const float* __restrict__ WVr,
    const float* __restrict__ rc, const float* __restrict__ w0p,
    const float* __restrict__ lpP, const float* __restrict__ lpD,
    float* __restrict__ kq, float* __restrict__ vg, float* __restrict__ loss_out)
{
    int b = blockIdx.x, k = blockIdx.y, tid = threadIdx.x;
    if (b == 0 && k == 0 && tid == 0) {
        float s = 0.f, s2 = 0.f;
        for (int bb = 0; bb < B_; bb++) { s += lpP[bb]; s2 += lpD[bb]; }
        loss_out[0] = s / (float)(B_*K_*DB_);
        loss_out[1] = s2 / (float)(B_*(K_*K_-K_));
    }
    float P = 0.f, Q = 0.f;
    #pragma unroll
    for (int c = 0; c < 8; c++) {
        P += w0p[((size_t)b*8 + c)*2 + 0];
        Q += w0p[((size_t)b*8 + c)*2 + 1];
    }
    float pm = sqrtf(P), qm2 = sqrtf(Q);
    float tot = pm + qm2 + 1e-6f;
    float b1 = pm / tot, b2 = qm2 / tot;

    __shared__ float sl[DB_], kr[DB_];
    if (tid < DB_) sl[tid] = sn[((size_t)b*K_ + k)*DB_ + tid];
    __syncthreads();
    if (tid < DB_) {
        float a = 0.f;
        for (int e = 0; e < DB_; e++) a += sl[e] * WKr[(size_t)e*DB_ + tid];
        kr[tid] = a;
    }
    __syncthreads();
    #pragma unroll
    for (int rep = 0; rep < 2; rep++) {
        int e = tid + rep*256;
        float a = 0.f;
        const float* wq = WQr + (size_t)e*DB_;
        for (int d = 0; d < DB_; d++) a += kr[d] * wq[d];
        kq[((size_t)b*K_ + k)*D_ + e] = a;
    }
    #pragma unroll
    for (int rep = 0; rep < 2; rep++) {
        int dd = tid + rep*256;
        float a = 0.f;
        for (int e = 0; e < DB_; e++) a += sl[e] * WVr[(size_t)e*D_ + dd];
        float gpre = rc[((size_t)k*3 + 0)*D_ + dd] + b1*rc[((size_t)k*3 + 1)*D_ + dd] + b2*rc[((size_t)k*3 + 2)*D_ + dd];
        float g = tanhf(gpre);
        g = fminf(fmaxf(g, -0.5f), 0.5f);
        vg[((size_t)b*K_ + k)*D_ + dd] = a * g;
    }
}

// ---------------- z: softmax over 7 slots + weighted combine ----------------
__global__ __launch_bounds__(256) void z_kernel(const float* __restrict__ Xr,
                                                const float* __restrict__ kq,
                                                const float* __restrict__ vg,
                                                float* __restrict__ z)
{
    int b = blockIdx.x;
    int t0 = blockIdx.y * 64;
    __shared__ float kqs[K_][D_];
    __shared__ float vgs[K_][D_];
    int tid = threadIdx.x;
    for (int p = tid; p < K_*D_; p += 256) {
        kqs[p>>9][p&511] = kq[(size_t)b*K_*D_ + p];
        vgs[p>>9][p&511] = vg[(size_t)b*K_*D_ + p];
    }
    __syncthreads();
    int lane = tid & 63, w = tid >> 6;
    for (int it = 0; it < 16; it++) {
        int t = t0 + w*16 + it;
        const float* x = Xr + ((size_t)b*T_ + t)*D_;
        float xr[8];
        float s[K_] = {0,0,0,0,0,0,0};
        #pragma unroll
        for (int r = 0; r < 8; r++) {
            int e = lane + r*64;
            xr[r] = x[e];
            #pragma unroll
            for (int k = 0; k < K_; k++) s[k] += xr[r] * kqs[k][e];
        }
        #pragma unroll
        for (int k = 0; k < K_; k++)
            for (int off = 32; off; off >>= 1) s[k] += __shfl_xor(s[k], off);
        float sc[K_];
        float m = NEGINF;
        #pragma unroll
        for (int k = 0; k < K_; k++) { sc[k] = s[k] * SCALE_; m = fmaxf(m, sc[k]); }
        float p[K_], ssum = 0.f;
        #pragma unroll
        for (int k = 0; k < K_; k++) { p[k] = expf(sc[k] - m); ssum += p[k]; }
        float inv = 1.f / ssum;
        float* zp = z + ((size_t)b*T_ + t)*D_;
        #pragma unroll
        for (int r = 0; r < 8; r++) {
            int e = lane + r*64;
            float a = 0.f;
            #pragma unroll
            for (int k = 0; k < K_; k++) a += p[k] * vgs[k][e];
            zp[e] = a * inv;
        }
    }
}

extern "C" void kernel_launch(void* const* d_in, const int* in_sizes, int n_in,
                              void* d_out, int out_size, void* d_ws, size_t ws_size,
                              hipStream_t stream)
{
    const float* X_write = (const float*)d_in[0];
    const float* X_read  = (const float*)d_in[1];
    const float* slots   = (const float*)d_in[2];
    const float* W0      = (const float*)d_in[3];
    const float* lnw_w   = (const float*)d_in[4];
    const float* lnw_b   = (const float*)d_in[5];
    const float* W_V     = (const float*)d_in[6];
    const float* W_K_slot= (const float*)d_in[7];
    const float* skb     = (const float*)d_in[8];
    const float* Wg      = (const float*)d_in[9];
    const float* Wgb     = (const float*)d_in[10];
    const float* lns_w   = (const float*)d_in[11];
    const float* lns_b   = (const float*)d_in[12];
    const float* WsQ     = (const float*)d_in[13];
    const float* WsK     = (const float*)d_in[14];
    const float* WsV     = (const float*)d_in[15];
    const float* lambda_ = (const float*)d_in[16];
    const float* WQr     = (const float*)d_in[17];
    const float* WKr     = (const float*)d_in[18];
    const float* WVr     = (const float*)d_in[19];
    const float* rc      = (const float*)d_in[20];
    const float* temps   = (const float*)d_in[21];

    const size_t NXD = (size_t)B_*T_*D_;           // 16777216
    unsigned short* Xh  = (unsigned short*)d_ws;
    unsigned short* Xl  = Xh + NXD;
    float* Cf           = (float*)(Xl + NXD);      // f32 XW0, 64MB
    unsigned short* W0h = (unsigned short*)(Cf + NXD);
    unsigned short* W0l = W0h + (size_t)D_*D_;
    float* fscr  = (float*)(W0l + (size_t)D_*D_);
    float* qpart = fscr;                           // B*32*D = 262144
    float* w0p   = qpart + (size_t)B_*32*D_;       // 256
    float* snws  = w0p + 256;                      // 14336
    float* kq    = snws + (size_t)B_*K_*DB_;       // 57344
    float* vg    = kq + (size_t)B_*K_*D_;          // 57344
    float* cv    = vg + (size_t)B_*K_*D_;          // B*64*64 = 65536
    int*   ci    = (int*)(cv + (size_t)B_*64*64);  // 65536
    float* lpP   = (float*)(ci + (size_t)B_*64*64);// 16
    float* lpD   = lpP + 16;                       // 16

    float* z_out     = (float*)d_out;
    float* slots_out = z_out + NXD;
    float* loss_out  = slots_out + (size_t)B_*K_*DB_;
    float* sal       = z_out;    // scratch inside z region; consumed before z_kernel writes

    prep_kernel<<<dim3(32768 + 256 + 512), dim3(256), 0, stream>>>(
        X_write, lnw_w, lnw_b, Xh, Xl, W0, W0h, W0l, X_read, qpart);
    gemm_xw0_mfma<<<dim3(B_*T_/128, D_/128), dim3(256), 0, stream>>>(Xh, Xl, W0h, W0l, Cf);
    sal_mfma<<<dim3(B_, T_/64), dim3(256), 0, stream>>>(Xh, Xl, Cf, sal);
    topk_stage1<<<dim3(B_, 64), dim3(256), 0, stream>>>(sal, cv, ci);
    slot_kernel<<<dim3(B_), dim3(1024), 0, stream>>>(Xh, Xl, slots, cv, ci,
        W_V, W_K_slot, skb, Wg, Wgb, lns_w, lns_b, WsQ, WsK, WsV, lambda_, temps,
        snws, slots_out, lpP, lpD);
    w0q_part_kernel<<<dim3(B_, 8), dim3(256), 0, stream>>>(qpart, W0, w0p);
    kqvg_kernel<<<dim3(B_, K_), dim3(256), 0, stream>>>(snws, WKr, WQr, WVr, rc, w0p,
        lpP, lpD, kq, vg, loss_out);
    z_kernel<<<dim3(B_, T_/64), dim3(256), 0, stream>>>(X_read, kq, vg, z_out);
}

// Round 8
// 288.061 us; speedup vs baseline: 4.4904x; 1.0561x over previous
//
#include <hip/hip_runtime.h>
#include <math.h>

#define B_ 16
#define T_ 2048
#define D_ 512
#define DB_ 128
#define K_ 7
#define TOPK_ 16
#define WIN_ 64

static constexpr float SCALE_ = 0.08838834764831845f;   // 128^-0.5
static constexpr float PHI_ = 1.618033988749895f;
static constexpr float PSI_ = -0.6180339887498949f;
static constexpr float INV_DENOM_ = 0.4472135954999579f; // 1/(PHI-PSI)
static constexpr float NEGV = -1e30f;
static constexpr float NEGINF = -3.402823466e38f;

typedef __attribute__((ext_vector_type(8))) __bf16 bf16x8;
typedef __attribute__((ext_vector_type(8))) unsigned short u16x8;
typedef __attribute__((ext_vector_type(4))) float f32x4;

__device__ inline float softplusf(float x){
    return fmaxf(x, 0.f) + log1pf(expf(-fabsf(x)));
}
__device__ inline unsigned short f2bf(float x){
    unsigned int u = __float_as_uint(x);
    unsigned int r = (u + 0x7FFFu + ((u >> 16) & 1u)) >> 16;
    return (unsigned short)r;
}
__device__ inline float bf2f(unsigned short h){
    return __uint_as_float(((unsigned int)h) << 16);
}
__device__ inline bf16x8 ld_bf8(const unsigned short* p){
    u16x8 r = *(const u16x8*)p;
    return __builtin_bit_cast(bf16x8, r);
}
// packed bf16 convert: D.lo16 = bf16(a), D.hi16 = bf16(b)
__device__ inline unsigned int pkbf(float a, float b){
    unsigned int r;
    asm("v_cvt_pk_bf16_f32 %0, %1, %2" : "=v"(r) : "v"(a), "v"(b));
    return r;
}
// async global->LDS 16B per lane: dest = uniform lds base + lane*16
typedef __attribute__((address_space(3))) unsigned int as3_u32;
typedef const __attribute__((address_space(1))) unsigned int as1_u32c;
__device__ inline void gload16(const void* g, void* l){
    __builtin_amdgcn_global_load_lds((as1_u32c*)g, (as3_u32*)l, 16, 0, 0);
}

// ---------------- prep: LN(X_write)->Xh/Xl (wave-per-row) | W0->hi/lo | qmean partials -----
__global__ __launch_bounds__(256) void prep_kernel(const float* __restrict__ X,
                                                   const float* __restrict__ w,
                                                   const float* __restrict__ b,
                                                   unsigned short* __restrict__ Xh,
                                                   unsigned short* __restrict__ Xl,
                                                   const float* __restrict__ W0,
                                                   unsigned short* __restrict__ Wh,
                                                   unsigned short* __restrict__ Wl,
                                                   const float* __restrict__ Xr,
                                                   float* __restrict__ qpart)
{
    int bx = blockIdx.x;
    int tid = threadIdx.x;
    if (bx < 4096) {
        // LayerNorm: wave-per-row, barrier-free. 4 waves x 2 rows = 8 rows/block.
        int lane = tid & 63, wv = tid >> 6;
        int row = bx * 8 + wv * 2;
        float4 wv0 = *(const float4*)(w + lane*4);
        float4 wv1 = *(const float4*)(w + 256 + lane*4);
        float4 bv0 = *(const float4*)(b + lane*4);
        float4 bv1 = *(const float4*)(b + 256 + lane*4);
        #pragma unroll
        for (int rr = 0; rr < 2; rr++) {
            const float* x = X + (size_t)(row + rr) * D_;
            float4 v0 = *(const float4*)(x + lane*4);
            float4 v1 = *(const float4*)(x + 256 + lane*4);
            float s  = v0.x+v0.y+v0.z+v0.w + v1.x+v1.y+v1.z+v1.w;
            float ss = v0.x*v0.x+v0.y*v0.y+v0.z*v0.z+v0.w*v0.w
                     + v1.x*v1.x+v1.y*v1.y+v1.z*v1.z+v1.w*v1.w;
            #pragma unroll
            for (int off = 32; off; off >>= 1) { s += __shfl_xor(s, off); ss += __shfl_xor(ss, off); }
            float mu = s * (1.f/512.f);
            float rs = rsqrtf(ss*(1.f/512.f) - mu*mu + 1e-5f);
            float o0 = (v0.x - mu)*rs*wv0.x + bv0.x;
            float o1 = (v0.y - mu)*rs*wv0.y + bv0.y;
            float o2 = (v0.z - mu)*rs*wv0.z + bv0.z;
            float o3 = (v0.w - mu)*rs*wv0.w + bv0.w;
            float o4 = (v1.x - mu)*rs*wv1.x + bv1.x;
            float o5 = (v1.y - mu)*rs*wv1.y + bv1.y;
            float o6 = (v1.z - mu)*rs*wv1.z + bv1.z;
            float o7 = (v1.w - mu)*rs*wv1.w + bv1.w;
            unsigned short h0 = f2bf(o0), h1 = f2bf(o1), h2 = f2bf(o2), h3 = f2bf(o3);
            unsigned short h4 = f2bf(o4), h5 = f2bf(o5), h6 = f2bf(o6), h7 = f2bf(o7);
            uint2 hA; hA.x = (unsigned int)h0 | ((unsigned int)h1 << 16);
                      hA.y = (unsigned int)h2 | ((unsigned int)h3 << 16);
            uint2 hB; hB.x = (unsigned int)h4 | ((unsigned int)h5 << 16);
                      hB.y = (unsigned int)h6 | ((unsigned int)h7 << 16);
            uint2 lA; lA.x = (unsigned int)f2bf(o0 - bf2f(h0)) | ((unsigned int)f2bf(o1 - bf2f(h1)) << 16);
                      lA.y = (unsigned int)f2bf(o2 - bf2f(h2)) | ((unsigned int)f2bf(o3 - bf2f(h3)) << 16);
            uint2 lB; lB.x = (unsigned int)f2bf(o4 - bf2f(h4)) | ((unsigned int)f2bf(o5 - bf2f(h5)) << 16);
                      lB.y = (unsigned int)f2bf(o6 - bf2f(h6)) | ((unsigned int)f2bf(o7 - bf2f(h7)) << 16);
            unsigned short* xh = Xh + (size_t)(row + rr) * D_;
            unsigned short* xl = Xl + (size_t)(row + rr) * D_;
            *(uint2*)(xh + lane*4) = hA;
            *(uint2*)(xh + 256 + lane*4) = hB;
            *(uint2*)(xl + lane*4) = lA;
            *(uint2*)(xl + 256 + lane*4) = lB;
        }
    } else if (bx < 4352) {
        int gid = (bx - 4096) * 256 + tid;
        float4 v = ((const float4*)W0)[gid];
        unsigned short h0 = f2bf(v.x), h1 = f2bf(v.y), h2 = f2bf(v.z), h3 = f2bf(v.w);
        ushort4 hv = make_ushort4(h0, h1, h2, h3);
        ushort4 lv = make_ushort4(f2bf(v.x - bf2f(h0)), f2bf(v.y - bf2f(h1)),
                                  f2bf(v.z - bf2f(h2)), f2bf(v.w - bf2f(h3)));
        *(ushort4*)&Wh[(size_t)gid*4] = hv;
        *(ushort4*)&Wl[(size_t)gid*4] = lv;
    } else {
        int idx = bx - 4352;
        int b_ = idx >> 5, c = idx & 31;
        const float* base = Xr + ((size_t)(b_*T_ + c*64)) * D_;
        float s0 = 0.f, s1 = 0.f;
        for (int t = 0; t < 64; t++) {
            s0 += base[(size_t)t*D_ + tid];
            s1 += base[(size_t)t*D_ + tid + 256];
        }
        qpart[((size_t)b_*32 + c)*D_ + tid] = s0;
        qpart[((size_t)b_*32 + c)*D_ + tid + 256] = s1;
    }
}

// ---------------- XW0 = Xn @ W0^T  (bf16x3 MFMA, gload_lds staging, swizzled LDS, f32 out) --
__global__ __launch_bounds__(256) void gemm_xw0_mfma(const unsigned short* __restrict__ Ah,
                                                     const unsigned short* __restrict__ Al,
                                                     const unsigned short* __restrict__ Wh,
                                                     const unsigned short* __restrict__ Wl,
                                                     float* __restrict__ Cf)
{
    __shared__ __align__(16) unsigned short sAh[128*32], sAl[128*32], sBh[128*32], sBl[128*32];
    int t0 = blockIdx.x * 128, d0 = blockIdx.y * 128;
    int tid = threadIdx.x;
    int lane = tid & 63, wid = tid >> 6;
    int wr = wid >> 1, wc = wid & 1;
    int fr = lane & 15;
    int kc2 = ((((lane >> 4) + (fr >> 1)) & 3) * 8);

    f32x4 acc[4][4];
    #pragma unroll
    for (int m = 0; m < 4; m++)
        #pragma unroll
        for (int n = 0; n < 4; n++) acc[m][n] = (f32x4){0.f,0.f,0.f,0.f};

    const unsigned short* gs = (wid==0) ? Ah : (wid==1) ? Al : (wid==2) ? Wh : Wl;
    unsigned short* ls = (wid==0) ? sAh : (wid==1) ? sAl : (wid==2) ? sBh : sBl;
    int rowoff = (wid < 2) ? t0 : d0;
    int cch = ((lane & 3) - ((lane >> 3) & 3)) & 3;
    const unsigned short* gbase = gs + (size_t)(rowoff + (lane >> 2))*512 + cch*8;

    for (int kk = 0; kk < 512; kk += 32) {
        #pragma unroll
        for (int i = 0; i < 8; i++)
            gload16(gbase + (size_t)(16*i)*512 + kk, ls + i*512);
        __syncthreads();

        bf16x8 ahf[4], alf[4], bhf[4], blf[4];
        #pragma unroll
        for (int m = 0; m < 4; m++) {
            int r = (wr*64 + m*16 + fr)*32 + kc2;
            ahf[m] = ld_bf8(&sAh[r]);
            alf[m] = ld_bf8(&sAl[r]);
        }
        #pragma unroll
        for (int n = 0; n < 4; n++) {
            int r = (wc*64 + n*16 + fr)*32 + kc2;
            bhf[n] = ld_bf8(&sBh[r]);
            blf[n] = ld_bf8(&sBl[r]);
        }
        #pragma unroll
        for (int m = 0; m < 4; m++)
            #pragma unroll
            for (int n = 0; n < 4; n++) {
                acc[m][n] = __builtin_amdgcn_mfma_f32_16x16x32_bf16(bhf[n], ahf[m], acc[m][n], 0, 0, 0);
                acc[m][n] = __builtin_amdgcn_mfma_f32_16x16x32_bf16(bhf[n], alf[m], acc[m][n], 0, 0, 0);
                acc[m][n] = __builtin_amdgcn_mfma_f32_16x16x32_bf16(blf[n], ahf[m], acc[m][n], 0, 0, 0);
            }
        __syncthreads();
    }

    #pragma unroll
    for (int m = 0; m < 4; m++) {
        int t = t0 + wr*64 + m*16 + fr;
        #pragma unroll
        for (int n = 0; n < 4; n++) {
            int dbase = d0 + wc*64 + n*16 + (lane >> 4)*4;
            *(f32x4*)&Cf[(size_t)t*512 + dbase] = acc[m][n];
        }
    }
}

// ---------------- sal (banded) via bf16x3 MFMA, swizzled LDS, f32 XW0 input ----------------
__global__ __launch_bounds__(256) void sal_mfma(const unsigned short* __restrict__ Xh,
                                                const unsigned short* __restrict__ Xl,
                                                const float* __restrict__ Cf,
                                                float* __restrict__ sal)
{
    int b = blockIdx.x, i0 = blockIdx.y * 64;
    __shared__ __align__(16) unsigned short sAh[64*32], sAl[64*32], sBh[128*32], sBl[128*32];
    int tid = threadIdx.x;
    int lane = tid & 63, wcw = tid >> 6;
    int fr = lane & 15;
    int kc2 = ((((lane >> 4) + (fr >> 1)) & 3) * 8);

    const unsigned short* XhB = Xh + (size_t)b*T_*D_;
    const unsigned short* XlB = Xl + (size_t)b*T_*D_;
    const float* CfB = Cf + (size_t)b*T_*D_;

    f32x4 acc[4][2];
    #pragma unroll
    for (int m = 0; m < 4; m++) { acc[m][0] = (f32x4){0.f,0.f,0.f,0.f}; acc[m][1] = (f32x4){0.f,0.f,0.f,0.f}; }

    int ar = tid >> 2, ac = tid & 3;
    int aslot = (ac + (ar >> 1)) & 3;
    int brow = tid >> 1, bhh = tid & 1;
    int jrow = i0 - 64 + brow;

    for (int kk = 0; kk < 512; kk += 32) {
        *(uint4*)&sAh[ar*32 + aslot*8] = *(const uint4*)(XhB + (size_t)(i0 + ar)*512 + kk + ac*8);
        *(uint4*)&sAl[ar*32 + aslot*8] = *(const uint4*)(XlB + (size_t)(i0 + ar)*512 + kk + ac*8);
        #pragma unroll
        for (int cc = 0; cc < 2; cc++) {
            int c = 2*bhh + cc;
            int slot = (c + (brow >> 1)) & 3;
            uint4 hv, lv;
            if (jrow >= 0) {
                const float* src = CfB + (size_t)jrow*512 + kk + c*8;
                float4 v0 = *(const float4*)src;
                float4 v1 = *(const float4*)(src + 4);
                unsigned int h01 = pkbf(v0.x, v0.y), h23 = pkbf(v0.z, v0.w);
                unsigned int h45 = pkbf(v1.x, v1.y), h67 = pkbf(v1.z, v1.w);
                float r0 = v0.x - __uint_as_float(h01 << 16);
                float r1 = v0.y - __uint_as_float(h01 & 0xFFFF0000u);
                float r2 = v0.z - __uint_as_float(h23 << 16);
                float r3 = v0.w - __uint_as_float(h23 & 0xFFFF0000u);
                float r4 = v1.x - __uint_as_float(h45 << 16);
                float r5 = v1.y - __uint_as_float(h45 & 0xFFFF0000u);
                float r6 = v1.z - __uint_as_float(h67 << 16);
                float r7 = v1.w - __uint_as_float(h67 & 0xFFFF0000u);
                hv.x = h01; hv.y = h23; hv.z = h45; hv.w = h67;
                lv.x = pkbf(r0, r1); lv.y = pkbf(r2, r3); lv.z = pkbf(r4, r5); lv.w = pkbf(r6, r7);
            } else {
                hv = make_uint4(0,0,0,0); lv = make_uint4(0,0,0,0);
            }
            *(uint4*)&sBh[brow*32 + slot*8] = hv;
            *(uint4*)&sBl[brow*32 + slot*8] = lv;
        }
        __syncthreads();

        bf16x8 ahf[4], alf[4], bhf[2], blf[2];
        #pragma unroll
        for (int m = 0; m < 4; m++) {
            int r = (m*16 + fr)*32 + kc2;
            ahf[m] = ld_bf8(&sAh[r]);
            alf[m] = ld_bf8(&sAl[r]);
        }
        #pragma unroll
        for (int n = 0; n < 2; n++) {
            int r = (wcw*32 + n*16 + fr)*32 + kc2;
            bhf[n] = ld_bf8(&sBh[r]);
            blf[n] = ld_bf8(&sBl[r]);
        }
        #pragma unroll
        for (int m = 0; m < 4; m++)
            #pragma unroll
            for (int n = 0; n < 2; n++) {
                acc[m][n] = __builtin_amdgcn_mfma_f32_16x16x32_bf16(ahf[m], bhf[n], acc[m][n], 0, 0, 0);
                acc[m][n] = __builtin_amdgcn_mfma_f32_16x16x32_bf16(ahf[m], blf[n], acc[m][n], 0, 0, 0);
                acc[m][n] = __builtin_amdgcn_mfma_f32_16x16x32_bf16(alf[m], bhf[n], acc[m][n], 0, 0, 0);
            }
        __syncthreads();
    }

    float* salB = sal + (size_t)b*T_*WIN_;
    #pragma unroll
    for (int m = 0; m < 4; m++) {
        #pragma unroll
        for (int n = 0; n < 2; n++) {
            int jl = wcw*32 + n*16 + fr;
            #pragma unroll
            for (int r = 0; r < 4; r++) {
                int il = m*16 + (lane >> 4)*4 + r;
                int o = il - jl + 64;
                if (o >= 1 && o <= 64) {
                    int jg = i0 - 64 + jl;
                    salB[(size_t)(i0 + il)*WIN_ + (o - 1)] = (jg >= 0) ? acc[m][n][r] : NEGV;
                }
            }
        }
    }
}

// ---------------- top-16: stage 1, per (batch, chunk) per-wave top-16, barrier-free -------
__global__ __launch_bounds__(256) void topk_stage1(const float* __restrict__ sal,
                                                   float* __restrict__ cv, int* __restrict__ ci)
{
    int b = blockIdx.x, c = blockIdx.y;
    const float* s = sal + (size_t)b*(T_*WIN_) + (size_t)c*2048;
    int base = c*2048;
    int tid = threadIdx.x;
    int lane = tid & 63, wvi = tid >> 6;
    float lv[8]; int li[8];
    #pragma unroll
    for (int k = 0; k < 8; k++) { lv[k] = NEGINF; li[k] = 0x7FFFFFFF; }
    #pragma unroll
    for (int r = 0; r < 8; r++) {
        int p = tid + r*256;
        float v = s[p];
        int idx = base + p;
        if (v > lv[7]) {
            int k = 7;
            while (k > 0 && lv[k-1] < v) { lv[k] = lv[k-1]; li[k] = li[k-1]; k--; }
            lv[k] = v; li[k] = idx;
        }
    }
    float* cvo = cv + (((size_t)b*64 + c)*64) + wvi*16;
    int*   cio = ci + (((size_t)b*64 + c)*64) + wvi*16;
    int head = 0;
    for (int r = 0; r < 16; r++) {
        float bv = (head < 8) ? lv[head] : NEGINF;
        int   bi = (head < 8) ? li[head] : 0x7FFFFFFF;
        float wv_ = bv; int wi = bi;
        #pragma unroll
        for (int off = 1; off < 64; off <<= 1) {
            float v2 = __shfl_xor(wv_, off);
            int   i2 = __shfl_xor(wi, off);
            if (v2 > wv_ || (v2 == wv_ && i2 < wi)) { wv_ = v2; wi = i2; }
        }
        if (bv == wv_ && bi == wi) head++;
        if (lane == 0) { cvo[r] = wv_; cio[r] = wi; }
    }
}

// ---------------- slot pipeline (per batch, 1024 thr): topk-merge + slot + loss partials --
__global__ __launch_bounds__(1024) void slot_kernel(
    const unsigned short* __restrict__ Xh, const unsigned short* __restrict__ Xl,
    const float* __restrict__ slots_in,
    const float* __restrict__ cv, const int* __restrict__ ci,
    const float* __restrict__ W_V, const float* __restrict__ W_K_slot, const float* __restrict__ skb,
    const float* __restrict__ Wg, const float* __restrict__ Wgb,
    const float* __restrict__ lnw, const float* __restrict__ lnb,
    const float* __restrict__ WsQ, const float* __restrict__ WsK, const float* __restrict__ WsV,
    const float* __restrict__ lambda_, const float* __restrict__ temps,
    float* __restrict__ snws, float* __restrict__ out_slots,
    float* __restrict__ lpP, float* __restrict__ lpD)
{
    int b = blockIdx.x, tid = threadIdx.x;
    int lane = tid & 63, wvi = tid >> 6;        // 16 waves
    __shared__ float alpha[16];
    __shared__ int   tis[16], tjs[16];
    __shared__ float tvv[16]; __shared__ int tii[16];
    __shared__ float scv[256]; __shared__ int sci[256];
    __shared__ float y[D_];
    __shared__ float part[8][DB_];
    __shared__ float pf[1024];
    __shared__ float Rt[DB_];
    __shared__ float sl[K_][DB_];
    __shared__ float upd[K_][DB_];
    __shared__ float Bn[K_][DB_];
    __shared__ float qq[K_][DB_], kk2[K_][DB_], vv[K_][DB_];
    __shared__ float snsh[K_][DB_];
    __shared__ float swv[K_], compat[K_], mu7[K_], rs7[K_], nr7[K_], ldv[K_];
    __shared__ float sa[K_][K_];

    for (int p = tid; p < K_*DB_; p += 1024) sl[p>>7][p&127] = slots_in[(size_t)b*K_*DB_ + p];

    {
        const float* cvb = cv + (size_t)b*4096;
        const int*   cib = ci + (size_t)b*4096;
        float lv[4]; int li[4];
        #pragma unroll
        for (int k = 0; k < 4; k++) { lv[k] = NEGINF; li[k] = 0x7FFFFFFF; }
        #pragma unroll
        for (int r = 0; r < 4; r++) {
            int p = tid + r*1024;
            float v = cvb[p];
            int idx = cib[p];
            if (v > lv[3] || (v == lv[3] && idx < li[3])) {
                int k = 3;
                while (k > 0 && (lv[k-1] < v || (lv[k-1] == v && li[k-1] > idx))) {
                    lv[k] = lv[k-1]; li[k] = li[k-1]; k--;
                }
                lv[k] = v; li[k] = idx;
            }
        }
        int head = 0;
        for (int r = 0; r < 16; r++) {
            float bv = (head < 4) ? lv[head] : NEGINF;
            int   bi = (head < 4) ? li[head] : 0x7FFFFFFF;
            float wv_ = bv; int wi = bi;
            #pragma unroll
            for (int off = 1; off < 64; off <<= 1) {
                float v2 = __shfl_xor(wv_, off);
                int   i2 = __shfl_xor(wi, off);
                if (v2 > wv_ || (v2 == wv_ && i2 < wi)) { wv_ = v2; wi = i2; }
            }
            if (bv == wv_ && bi == wi) head++;
            if (lane == 0) { scv[wvi*16 + r] = wv_; sci[wvi*16 + r] = wi; }
        }
        __syncthreads();
        if (wvi == 0) {
            float mv[4]; int mi[4];
            #pragma unroll
            for (int k = 0; k < 4; k++) { mv[k] = NEGINF; mi[k] = 0x7FFFFFFF; }
            #pragma unroll
            for (int r = 0; r < 4; r++) {
                int p = lane + r*64;
                float v = scv[p]; int idx = sci[p];
                if (v > mv[3] || (v == mv[3] && idx < mi[3])) {
                    int k = 3;
                    while (k > 0 && (mv[k-1] < v || (mv[k-1] == v && mi[k-1] > idx))) {
                        mv[k] = mv[k-1]; mi[k] = mi[k-1]; k--;
                    }
                    mv[k] = v; mi[k] = idx;
                }
            }
            int head2 = 0;
            for (int r = 0; r < 16; r++) {
                float bv = (head2 < 4) ? mv[head2] : NEGINF;
                int   bi = (head2 < 4) ? mi[head2] : 0x7FFFFFFF;
                float wv_ = bv; int wi = bi;
                #pragma unroll
                for (int off = 1; off < 64; off <<= 1) {
                    float v2 = __shfl_xor(wv_, off);
                    int   i2 = __shfl_xor(wi, off);
                    if (v2 > wv_ || (v2 == wv_ && i2 < wi)) { wv_ = v2; wi = i2; }
                }
                if (bv == wv_ && bi == wi) head2++;
                if (lane == 0) { tvv[r] = wv_; tii[r] = wi; }
            }
        }
        __syncthreads();
    }
    if (tid < 16) {
        float v = tvv[tid];
        int flat = tii[tid];
        tis[tid] = flat >> 6;
        tjs[tid] = (flat >> 6) - ((flat & 63) + 1);
        float m = v;
        #pragma unroll
        for (int off = 8; off; off >>= 1) m = fmaxf(m, __shfl_xor(m, off, 16));
        float e = expf(v - m);
        float s = e;
        #pragma unroll
        for (int off = 8; off; off >>= 1) s += __shfl_xor(s, off, 16);
        alpha[tid] = e / s;
    }
    __syncthreads();

    if (tid < D_) {
        float acc = 0.f;
        #pragma unroll
        for (int k = 0; k < 16; k++) {
            int i = tis[k], j = tjs[k];
            float xi = bf2f(Xh[((size_t)b*T_ + i)*D_ + tid]) + bf2f(Xl[((size_t)b*T_ + i)*D_ + tid]);
            float xj = bf2f(Xh[((size_t)b*T_ + j)*D_ + tid]) + bf2f(Xl[((size_t)b*T_ + j)*D_ + tid]);
            acc += alpha[k] * (xi - xj);
        }
        y[tid] = acc;
    }
    __syncthreads();

    {
        int g = tid >> 7, d = tid & 127;
        float acc = 0.f;
        int e0 = g * 64;
        for (int e = e0; e < e0 + 64; e++) acc += y[e] * W_V[(size_t)e*DB_ + d];
        part[g][d] = acc;
    }
    __syncthreads();
    if (tid < DB_) {
        float acc = 0.f;
        #pragma unroll
        for (int g = 0; g < 8; g++) acc += part[g][tid];
        Rt[tid] = acc;
    }
    __syncthreads();

    if (tid < K_*DB_) {
        int k = tid >> 7, d = tid & 127;
        float acc = skb[k*DB_ + d];
        for (int e = 0; e < DB_; e++) acc += sl[k][e] * W_K_slot[(size_t)e*DB_ + d];
        qq[k][d] = acc * Rt[d];
    }
    __syncthreads();
    if (wvi < K_) {
        float acc = qq[wvi][lane] + qq[wvi][lane + 64];
        #pragma unroll
        for (int off = 32; off; off >>= 1) acc += __shfl_xor(acc, off);
        if (lane == 0) compat[wvi] = acc * SCALE_ * softplusf(temps[wvi]);
    }
    __syncthreads();
    if (tid == 0) {
        float m = compat[0];
        for (int k = 1; k < K_; k++) m = fmaxf(m, compat[k]);
        float ssum = 0.f;
        for (int k = 0; k < K_; k++) { float e = expf(compat[k]-m); swv[k] = e; ssum += e; }
        for (int k = 0; k < K_; k++) swv[k] /= ssum;
    }
    __syncthreads();

    if (tid < K_*DB_) {
        int k = tid >> 7, d = tid & 127;
        float swk = swv[k];
        float acc = Wgb[d];
        for (int e = 0; e < DB_; e++) acc += sl[k][e] * Wg[(size_t)e*DB_ + d];
        for (int e = 0; e < DB_; e++) acc += swk * Rt[e] * Wg[(size_t)(DB_+e)*DB_ + d];
        float g = 1.f / (1.f + expf(-acc));
        upd[k][d] = (1.f - g) * sl[k][d] + g * (swk * Rt[d]);
    }
    __syncthreads();

    if (wvi < K_) {
        float v0 = upd[wvi][lane], v1 = upd[wvi][lane + 64];
        float s = v0 + v1, ss = v0*v0 + v1*v1;
        #pragma unroll
        for (int off = 32; off; off >>= 1) { s += __shfl_xor(s, off); ss += __shfl_xor(ss, off); }
        if (lane == 0) {
            float mu = s / (float)DB_;
            mu7[wvi] = mu;
            rs7[wvi] = rsqrtf(ss/(float)DB_ - mu*mu + 1e-5f);
        }
    }
    __syncthreads();
    if (tid < K_*DB_) {
        int k = tid >> 7, d = tid & 127;
        Bn[k][d] = (upd[k][d] - mu7[k]) * rs7[k] * lnw[d] + lnb[d];
    }
    __syncthreads();

    if (tid < K_*DB_) {
        int k = tid >> 7, d = tid & 127;
        float aq = 0.f, ak = 0.f, av = 0.f;
        for (int e = 0; e < DB_; e++) {
            float bn = Bn[k][e];
            aq += bn * WsQ[(size_t)e*DB_ + d];
            ak += bn * WsK[(size_t)e*DB_ + d];
            av += bn * WsV[(size_t)e*DB_ + d];
        }
        qq[k][d] = aq; kk2[k][d] = ak; vv[k][d] = av;
    }
    __syncthreads();

    if (wvi < K_) {
        int j = lane >> 3, s = lane & 7;
        float acc = 0.f;
        if (j < K_) {
            int e0 = s * 16;
            for (int e = e0; e < e0 + 16; e++) acc += qq[wvi][e] * kk2[j][e];
        }
        #pragma unroll
        for (int off = 4; off; off >>= 1) acc += __shfl_xor(acc, off, 8);
        if (s == 0 && j < K_) sa[wvi][j] = acc * SCALE_;
    }
    __syncthreads();
    if (tid < K_) {
        float m = sa[tid][0];
        for (int j = 1; j < K_; j++) m = fmaxf(m, sa[tid][j]);
        float ssum = 0.f;
        for (int j = 0; j < K_; j++) { float e = expf(sa[tid][j]-m); sa[tid][j] = e; ssum += e; }
        for (int j = 0; j < K_; j++) sa[tid][j] /= ssum;
    }
    __syncthreads();

    if (tid < K_*DB_) {
        int k = tid >> 7, d = tid & 127;
        float lam = tanhf(lambda_[d]);
        lam = fminf(fmaxf(lam, -0.5f), 0.5f);
        float c = 0.f;
        #pragma unroll
        for (int j = 0; j < K_; j++) c += sa[k][j] * vv[j][d];
        float sn = upd[k][d] + c * lam;
        snsh[k][d] = sn;
        snws[((size_t)b*K_ + k)*DB_ + d] = sn;
        out_slots[((size_t)b*K_ + k)*DB_ + d] = sn;
    }
    __syncthreads();

    {
        float dsq = 0.f;
        if (tid < K_*DB_) {
            int k = tid >> 7, d = tid & 127;
            float dd = snsh[k][d] - sl[k][d];
            dsq = dd*dd;
        }
        pf[tid] = dsq;
        if (wvi < K_) {
            float v0 = snsh[wvi][lane], v1 = snsh[wvi][lane + 64];
            float ss = v0*v0 + v1*v1;
            #pragma unroll
            for (int off = 32; off; off >>= 1) ss += __shfl_xor(ss, off);
            if (lane == 0) nr7[wvi] = fmaxf(sqrtf(ss), 1e-12f);
        }
        __syncthreads();
        if (wvi == 0) {
            float s = 0.f;
            #pragma unroll
            for (int q = 0; q < 16; q++) s += pf[lane + q*64];
            #pragma unroll
            for (int off = 32; off; off >>= 1) s += __shfl_xor(s, off);
            if (lane == 0) lpP[b] = s;
        }
        if (wvi >= 1 && wvi <= K_) {
            int q = wvi - 1;
            float accq = 0.f;
            for (int j = 0; j < K_; j++) {
                if (j == q) continue;
                float dt = snsh[q][lane]*snsh[j][lane] + snsh[q][lane+64]*snsh[j][lane+64];
                #pragma unroll
                for (int off = 32; off; off >>= 1) dt += __shfl_xor(dt, off);
                float cs = dt / (nr7[q] * nr7[j]);
                accq += cs*cs;
            }
            if (lane == 0) ldv[q] = accq;
        }
        __syncthreads();
        if (tid == 0) {
            float s = 0.f;
            for (int q = 0; q < K_; q++) s += ldv[q];
            lpD[b] = s;
        }
    }
}

// ---------------- w0q + phi/psi partials (qmean-final fused): grid (B, 8) ----------------
__global__ __launch_bounds__(256) void w0q_part_kernel(const float* __restrict__ qpart,
                                                       const float* __restrict__ W0,
                                                       float* __restrict__ w0p)
{
    int b = blockIdx.x, c = blockIdx.y, tid = threadIdx.x;
    __shared__ float qm[D_];
    for (int p = tid; p < D_; p += 256) {
        float s = 0.f;
        for (int cc = 0; cc < 32; cc++) s += qpart[((size_t)b*32 + cc)*D_ + p];
        qm[p] = s * (1.f/2048.f);
    }
    __syncthreads();
    int w = tid >> 6, lane = tid & 63;
    float ph = 0.f, ps = 0.f;
    for (int r = 0; r < 16; r++) {
        int d = c*64 + w*16 + r;
        const float* wr = W0 + (size_t)d*D_;
        float s = 0.f;
        #pragma unroll
        for (int q = 0; q < 8; q++) s += qm[lane + q*64] * wr[lane + q*64];
        #pragma unroll
        for (int off = 32; off; off >>= 1) s += __shfl_xor(s, off);
        float phi = (s - PSI_*qm[d]) * INV_DENOM_;
        float psi = (PHI_*qm[d] - s) * INV_DENOM_;
        ph += phi*phi; ps += psi*psi;
    }
    __shared__ float shp[4], shs[4];
    if (lane == 0) { shp[w] = ph; shs[w] = ps; }
    __syncthreads();
    if (tid == 0) {
        w0p[((size_t)b*8 + c)*2 + 0] = shp[0]+shp[1]+shp[2]+shp[3];
        w0p[((size_t)b*8 + c)*2 + 1] = shs[0]+shs[1]+shs[2]+shs[3];
    }
}

// ---------------- kq & vg (+basis inline, +loss finalize): grid (B, K) ----------------
__global__ __launch_bounds__(256) void kqvg_kernel(
    const float* __restrict__ sn, const float* __restrict__ WKr,
    const float* __restrict__ WQr, const float* __restrict__ WVr,
    const float* __restrict__ rc, const float* __restrict__ w0p,
    const float* __restrict__ lpP, const float* __restrict__ lpD,
    float* __restrict__ kq, float* __restrict__ vg, float* __restrict__ loss_out)
{
    int b = blockIdx.x, k = blockIdx.y, tid = threadIdx.x;
    if (b == 0 && k == 0 && tid == 0) {
        float s = 0.f, s2 = 0.f;
        for (int bb = 0; bb < B_; bb++) { s += lpP[bb]; s2 += lpD[bb]; }
        loss_out[0] = s / (float)(B_*K_*DB_);
        loss_out[1] = s2 / (float)(B_*(K_*K_-K_));
    }
    float P = 0.f, Q = 0.f;
    #pragma unroll
    for (int c = 0; c < 8; c++) {
        P += w0p[((size_t)b*8 + c)*2 + 0];
        Q += w0p[((size_t)b*8 + c)*2 + 1];
    }
    float pm = sqrtf(P), qm2 = sqrtf(Q);
    float tot = pm + qm2 + 1e-6f;
    float b1 = pm / tot, b2 = qm2 / tot;

    __shared__ float sl[DB_], kr[DB_];
    if (tid < DB_) sl[tid] = sn[((size_t)b*K_ + k)*DB_ + tid];
    __syncthreads();
    if (tid < DB_) {
        float a = 0.f;
        for (int e = 0; e < DB_; e++) a += sl[e] * WKr[(size_t)e*DB_ + tid];
        kr[tid] = a;
    }
    __syncthreads();
    #pragma unroll
    for (int rep = 0; rep < 2; rep++) {
        int e = tid + rep*256;
        float a = 0.f;
        const float* wq = WQr + (size_t)e*DB_;
        for (int d = 0; d < DB_; d++) a += kr[d] * wq[d];
        kq[((size_t)b*K_ + k)*D_ + e] = a;
    }
    #pragma unroll
    for (int rep = 0; rep < 2; rep++) {
        int dd = tid + rep*256;
        float a = 0.f;
        for (int e = 0; e < DB_; e++) a += sl[e] * WVr[(size_t)e*D_ + dd];
        float gpre = rc[((size_t)k*3 + 0)*D_ + dd] + b1*rc[((size_t)k*3 + 1)*D_ + dd] + b2*rc[((size_t)k*3 + 2)*D_ + dd];
        float g = tanhf(gpre);
        g = fminf(fmaxf(g, -0.5f), 0.5f);
        vg[((size_t)b*K_ + k)*D_ + dd] = a * g;
    }
}

// ---------------- z: softmax over 7 slots + weighted combine ----------------
__global__ __launch_bounds__(256) void z_kernel(const float* __restrict__ Xr,
                                                const float* __restrict__ kq,
                                                const float* __restrict__ vg,
                                                float* __restrict__ z)
{
    int b = blockIdx.x;
    int t0 = blockIdx.y * 64;
    __shared__ float kqs[K_][D_];
    __shared__ float vgs[K_][D_];
    int tid = threadIdx.x;
    for (int p = tid; p < K_*D_; p += 256) {
        kqs[p>>9][p&511] = kq[(size_t)b*K_*D_ + p];
        vgs[p>>9][p&511] = vg[(size_t)b*K_*D_ + p];
    }
    __syncthreads();
    int lane = tid & 63, w = tid >> 6;
    for (int it = 0; it < 16; it++) {
        int t = t0 + w*16 + it;
        const float* x = Xr + ((size_t)b*T_ + t)*D_;
        float xr[8];
        float s[K_] = {0,0,0,0,0,0,0};
        #pragma unroll
        for (int r = 0; r < 8; r++) {
            int e = lane + r*64;
            xr[r] = x[e];
            #pragma unroll
            for (int k = 0; k < K_; k++) s[k] += xr[r] * kqs[k][e];
        }
        #pragma unroll
        for (int k = 0; k < K_; k++)
            for (int off = 32; off; off >>= 1) s[k] += __shfl_xor(s[k], off);
        float sc[K_];
        float m = NEGINF;
        #pragma unroll
        for (int k = 0; k < K_; k++) { sc[k] = s[k] * SCALE_; m = fmaxf(m, sc[k]); }
        float p[K_], ssum = 0.f;
        #pragma unroll
        for (int k = 0; k < K_; k++) { p[k] = expf(sc[k] - m); ssum += p[k]; }
        float inv = 1.f / ssum;
        float* zp = z + ((size_t)b*T_ + t)*D_;
        #pragma unroll
        for (int r = 0; r < 8; r++) {
            int e = lane + r*64;
            float a = 0.f;
            #pragma unroll
            for (int k = 0; k < K_; k++) a += p[k] * vgs[k][e];
            zp[e] = a * inv;
        }
    }
}

extern "C" void kernel_launch(void* const* d_in, const int* in_sizes, int n_in,
                              void* d_out, int out_size, void* d_ws, size_t ws_size,
                              hipStream_t stream)
{
    const float* X_write = (const float*)d_in[0];
    const float* X_read  = (const float*)d_in[1];
    const float* slots   = (const float*)d_in[2];
    const float* W0      = (const float*)d_in[3];
    const float* lnw_w   = (const float*)d_in[4];
    const float* lnw_b   = (const float*)d_in[5];
    const float* W_V     = (const float*)d_in[6];
    const float* W_K_slot= (const float*)d_in[7];
    const float* skb     = (const float*)d_in[8];
    const float* Wg      = (const float*)d_in[9];
    const float* Wgb     = (const float*)d_in[10];
    const float* lns_w   = (const float*)d_in[11];
    const float* lns_b   = (const float*)d_in[12];
    const float* WsQ     = (const float*)d_in[13];
    const float* WsK     = (const float*)d_in[14];
    const float* WsV     = (const float*)d_in[15];
    const float* lambda_ = (const float*)d_in[16];
    const float* WQr     = (const float*)d_in[17];
    const float* WKr     = (const float*)d_in[18];
    const float* WVr     = (const float*)d_in[19];
    const float* rc      = (const float*)d_in[20];
    const float* temps   = (const float*)d_in[21];

    const size_t NXD = (size_t)B_*T_*D_;           // 16777216
    unsigned short* Xh  = (unsigned short*)d_ws;
    unsigned short* Xl  = Xh + NXD;
    float* Cf           = (float*)(Xl + NXD);      // f32 XW0, 64MB
    unsigned short* W0h = (unsigned short*)(Cf + NXD);
    unsigned short* W0l = W0h + (size_t)D_*D_;
    float* fscr  = (float*)(W0l + (size_t)D_*D_);
    float* qpart = fscr;                           // B*32*D = 262144
    float* w0p   = qpart + (size_t)B_*32*D_;       // 256
    float* snws  = w0p + 256;                      // 14336
    float* kq    = snws + (size_t)B_*K_*DB_;       // 57344
    float* vg    = kq + (size_t)B_*K_*D_;          // 57344
    float* cv    = vg + (size_t)B_*K_*D_;          // B*64*64 = 65536
    int*   ci    = (int*)(cv + (size_t)B_*64*64);  // 65536
    float* lpP   = (float*)(ci + (size_t)B_*64*64);// 16
    float* lpD   = lpP + 16;                       // 16

    float* z_out     = (float*)d_out;
    float* slots_out = z_out + NXD;
    float* loss_out  = slots_out + (size_t)B_*K_*DB_;
    float* sal       = z_out;    // scratch inside z region; consumed before z_kernel writes

    prep_kernel<<<dim3(4096 + 256 + 512), dim3(256), 0, stream>>>(
        X_write, lnw_w, lnw_b, Xh, Xl, W0, W0h, W0l, X_read, qpart);
    gemm_xw0_mfma<<<dim3(B_*T_/128, D_/128), dim3(256), 0, stream>>>(Xh, Xl, W0h, W0l, Cf);
    sal_mfma<<<dim3(B_, T_/64), dim3(256), 0, stream>>>(Xh, Xl, Cf, sal);
    topk_stage1<<<dim3(B_, 64), dim3(256), 0, stream>>>(sal, cv, ci);
    slot_kernel<<<dim3(B_), dim3(1024), 0, stream>>>(Xh, Xl, slots, cv, ci,
        W_V, W_K_slot, skb, Wg, Wgb, lns_w, lns_b, WsQ, WsK, WsV, lambda_, temps,
        snws, slots_out, lpP, lpD);
    w0q_part_kernel<<<dim3(B_, 8), dim3(256), 0, stream>>>(qpart, W0, w0p);
    kqvg_kernel<<<dim3(B_, K_), dim3(256), 0, stream>>>(snws, WKr, WQr, WVr, rc, w0p,
        lpP, lpD, kq, vg, loss_out);
    z_kernel<<<dim3(B_, T_/64), dim3(256), 0, stream>>>(X_read, kq, vg, z_out);
}

// Round 9
// 269.893 us; speedup vs baseline: 4.7927x; 1.0673x over previous
//
#include <hip/hip_runtime.h>
#include <math.h>

#define B_ 16
#define T_ 2048
#define D_ 512
#define DB_ 128
#define K_ 7
#define TOPK_ 16
#define WIN_ 64

static constexpr float SCALE_ = 0.08838834764831845f;   // 128^-0.5
static constexpr float PHI_ = 1.618033988749895f;
static constexpr float PSI_ = -0.6180339887498949f;
static constexpr float INV_DENOM_ = 0.4472135954999579f; // 1/(PHI-PSI)
static constexpr float NEGV = -1e30f;
static constexpr float NEGINF = -3.402823466e38f;

typedef __attribute__((ext_vector_type(8))) __bf16 bf16x8;
typedef __attribute__((ext_vector_type(8))) unsigned short u16x8;
typedef __attribute__((ext_vector_type(4))) float f32x4;

__device__ inline float softplusf(float x){
    return fmaxf(x, 0.f) + log1pf(expf(-fabsf(x)));
}
__device__ inline unsigned short f2bf(float x){
    unsigned int u = __float_as_uint(x);
    unsigned int r = (u + 0x7FFFu + ((u >> 16) & 1u)) >> 16;
    return (unsigned short)r;
}
__device__ inline float bf2f(unsigned short h){
    return __uint_as_float(((unsigned int)h) << 16);
}
__device__ inline bf16x8 ld_bf8(const unsigned short* p){
    u16x8 r = *(const u16x8*)p;
    return __builtin_bit_cast(bf16x8, r);
}
// packed bf16 convert: D.lo16 = bf16(a), D.hi16 = bf16(b)
__device__ inline unsigned int pkbf(float a, float b){
    unsigned int r;
    asm("v_cvt_pk_bf16_f32 %0, %1, %2" : "=v"(r) : "v"(a), "v"(b));
    return r;
}
// async global->LDS 16B per lane: dest = uniform lds base + lane*16
typedef __attribute__((address_space(3))) unsigned int as3_u32;
typedef const __attribute__((address_space(1))) unsigned int as1_u32c;
__device__ inline void gload16(const void* g, void* l){
    __builtin_amdgcn_global_load_lds((as1_u32c*)g, (as3_u32*)l, 16, 0, 0);
}

// ---------------- prep: LN(X_write)->Xh/Xl (wave-per-row) | W0->hi/lo | qmean partials -----
__global__ __launch_bounds__(256) void prep_kernel(const float* __restrict__ X,
                                                   const float* __restrict__ w,
                                                   const float* __restrict__ b,
                                                   unsigned short* __restrict__ Xh,
                                                   unsigned short* __restrict__ Xl,
                                                   const float* __restrict__ W0,
                                                   unsigned short* __restrict__ Wh,
                                                   unsigned short* __restrict__ Wl,
                                                   const float* __restrict__ Xr,
                                                   float* __restrict__ qpart)
{
    int bx = blockIdx.x;
    int tid = threadIdx.x;
    if (bx < 4096) {
        int lane = tid & 63, wv = tid >> 6;
        int row = bx * 8 + wv * 2;
        float4 wv0 = *(const float4*)(w + lane*4);
        float4 wv1 = *(const float4*)(w + 256 + lane*4);
        float4 bv0 = *(const float4*)(b + lane*4);
        float4 bv1 = *(const float4*)(b + 256 + lane*4);
        #pragma unroll
        for (int rr = 0; rr < 2; rr++) {
            const float* x = X + (size_t)(row + rr) * D_;
            float4 v0 = *(const float4*)(x + lane*4);
            float4 v1 = *(const float4*)(x + 256 + lane*4);
            float s  = v0.x+v0.y+v0.z+v0.w + v1.x+v1.y+v1.z+v1.w;
            float ss = v0.x*v0.x+v0.y*v0.y+v0.z*v0.z+v0.w*v0.w
                     + v1.x*v1.x+v1.y*v1.y+v1.z*v1.z+v1.w*v1.w;
            #pragma unroll
            for (int off = 32; off; off >>= 1) { s += __shfl_xor(s, off); ss += __shfl_xor(ss, off); }
            float mu = s * (1.f/512.f);
            float rs = rsqrtf(ss*(1.f/512.f) - mu*mu + 1e-5f);
            float o0 = (v0.x - mu)*rs*wv0.x + bv0.x;
            float o1 = (v0.y - mu)*rs*wv0.y + bv0.y;
            float o2 = (v0.z - mu)*rs*wv0.z + bv0.z;
            float o3 = (v0.w - mu)*rs*wv0.w + bv0.w;
            float o4 = (v1.x - mu)*rs*wv1.x + bv1.x;
            float o5 = (v1.y - mu)*rs*wv1.y + bv1.y;
            float o6 = (v1.z - mu)*rs*wv1.z + bv1.z;
            float o7 = (v1.w - mu)*rs*wv1.w + bv1.w;
            unsigned short h0 = f2bf(o0), h1 = f2bf(o1), h2 = f2bf(o2), h3 = f2bf(o3);
            unsigned short h4 = f2bf(o4), h5 = f2bf(o5), h6 = f2bf(o6), h7 = f2bf(o7);
            uint2 hA; hA.x = (unsigned int)h0 | ((unsigned int)h1 << 16);
                      hA.y = (unsigned int)h2 | ((unsigned int)h3 << 16);
            uint2 hB; hB.x = (unsigned int)h4 | ((unsigned int)h5 << 16);
                      hB.y = (unsigned int)h6 | ((unsigned int)h7 << 16);
            uint2 lA; lA.x = (unsigned int)f2bf(o0 - bf2f(h0)) | ((unsigned int)f2bf(o1 - bf2f(h1)) << 16);
                      lA.y = (unsigned int)f2bf(o2 - bf2f(h2)) | ((unsigned int)f2bf(o3 - bf2f(h3)) << 16);
            uint2 lB; lB.x = (unsigned int)f2bf(o4 - bf2f(h4)) | ((unsigned int)f2bf(o5 - bf2f(h5)) << 16);
                      lB.y = (unsigned int)f2bf(o6 - bf2f(h6)) | ((unsigned int)f2bf(o7 - bf2f(h7)) << 16);
            unsigned short* xh = Xh + (size_t)(row + rr) * D_;
            unsigned short* xl = Xl + (size_t)(row + rr) * D_;
            *(uint2*)(xh + lane*4) = hA;
            *(uint2*)(xh + 256 + lane*4) = hB;
            *(uint2*)(xl + lane*4) = lA;
            *(uint2*)(xl + 256 + lane*4) = lB;
        }
    } else if (bx < 4352) {
        int gid = (bx - 4096) * 256 + tid;
        float4 v = ((const float4*)W0)[gid];
        unsigned short h0 = f2bf(v.x), h1 = f2bf(v.y), h2 = f2bf(v.z), h3 = f2bf(v.w);
        ushort4 hv = make_ushort4(h0, h1, h2, h3);
        ushort4 lv = make_ushort4(f2bf(v.x - bf2f(h0)), f2bf(v.y - bf2f(h1)),
                                  f2bf(v.z - bf2f(h2)), f2bf(v.w - bf2f(h3)));
        *(ushort4*)&Wh[(size_t)gid*4] = hv;
        *(ushort4*)&Wl[(size_t)gid*4] = lv;
    } else {
        int idx = bx - 4352;
        int b_ = idx >> 5, c = idx & 31;
        const float* base = Xr + ((size_t)(b_*T_ + c*64)) * D_;
        float s0 = 0.f, s1 = 0.f;
        for (int t = 0; t < 64; t++) {
            s0 += base[(size_t)t*D_ + tid];
            s1 += base[(size_t)t*D_ + tid + 256];
        }
        qpart[((size_t)b_*32 + c)*D_ + tid] = s0;
        qpart[((size_t)b_*32 + c)*D_ + tid + 256] = s1;
    }
}

// ---------------- XW0: bf16x3 MFMA, DOUBLE-BUFFERED gload_lds, swizzled LDS, f32 out -------
// 2-phase: barrier -> issue STAGE(next) -> ds_read+MFMA(cur). One barrier per K-step.
__global__ __launch_bounds__(256) void gemm_xw0_mfma(const unsigned short* __restrict__ Ah,
                                                     const unsigned short* __restrict__ Al,
                                                     const unsigned short* __restrict__ Wh,
                                                     const unsigned short* __restrict__ Wl,
                                                     float* __restrict__ Cf)
{
    __shared__ __align__(16) unsigned short sAh[2*128*32], sAl[2*128*32], sBh[2*128*32], sBl[2*128*32];
    int t0 = blockIdx.x * 128, d0 = blockIdx.y * 128;
    int tid = threadIdx.x;
    int lane = tid & 63, wid = tid >> 6;
    int wr = wid >> 1, wc = wid & 1;
    int fr = lane & 15;
    int kc2 = ((((lane >> 4) + (fr >> 1)) & 3) * 8);

    f32x4 acc[4][4];
    #pragma unroll
    for (int m = 0; m < 4; m++)
        #pragma unroll
        for (int n = 0; n < 4; n++) acc[m][n] = (f32x4){0.f,0.f,0.f,0.f};

    const unsigned short* gs = (wid==0) ? Ah : (wid==1) ? Al : (wid==2) ? Wh : Wl;
    unsigned short* lsA = (wid==0) ? sAh : (wid==1) ? sAl : (wid==2) ? sBh : sBl;
    int rowoff = (wid < 2) ? t0 : d0;
    int cch = ((lane & 3) - ((lane >> 3) & 3)) & 3;
    const unsigned short* gbase = gs + (size_t)(rowoff + (lane >> 2))*512 + cch*8;

    // prologue: stage K-tile 0 into buf 0
    #pragma unroll
    for (int i = 0; i < 8; i++)
        gload16(gbase + (size_t)(16*i)*512 + 0, lsA + i*512);

    for (int t = 0; t < 16; t++) {
        int cur = t & 1;
        __syncthreads();   // drains vmcnt -> buf[cur] ready; also separates prev reads
        if (t < 15) {
            unsigned short* ls = lsA + (cur^1)*(128*32);
            int kk = (t+1)*32;
            #pragma unroll
            for (int i = 0; i < 8; i++)
                gload16(gbase + (size_t)(16*i)*512 + kk, ls + i*512);
        }
        int bo = cur*(128*32);
        bf16x8 ahf[4], alf[4], bhf[4], blf[4];
        #pragma unroll
        for (int m = 0; m < 4; m++) {
            int r = bo + (wr*64 + m*16 + fr)*32 + kc2;
            ahf[m] = ld_bf8(&sAh[r]);
            alf[m] = ld_bf8(&sAl[r]);
        }
        #pragma unroll
        for (int n = 0; n < 4; n++) {
            int r = bo + (wc*64 + n*16 + fr)*32 + kc2;
            bhf[n] = ld_bf8(&sBh[r]);
            blf[n] = ld_bf8(&sBl[r]);
        }
        #pragma unroll
        for (int m = 0; m < 4; m++)
            #pragma unroll
            for (int n = 0; n < 4; n++) {
                acc[m][n] = __builtin_amdgcn_mfma_f32_16x16x32_bf16(bhf[n], ahf[m], acc[m][n], 0, 0, 0);
                acc[m][n] = __builtin_amdgcn_mfma_f32_16x16x32_bf16(bhf[n], alf[m], acc[m][n], 0, 0, 0);
                acc[m][n] = __builtin_amdgcn_mfma_f32_16x16x32_bf16(blf[n], ahf[m], acc[m][n], 0, 0, 0);
            }
    }

    #pragma unroll
    for (int m = 0; m < 4; m++) {
        int t = t0 + wr*64 + m*16 + fr;
        #pragma unroll
        for (int n = 0; n < 4; n++) {
            int dbase = d0 + wc*64 + n*16 + (lane >> 4)*4;
            *(f32x4*)&Cf[(size_t)t*512 + dbase] = acc[m][n];
        }
    }
}

// ---------------- sal: bf16x3 MFMA, swizzled LDS, issue-early global loads (T14) -----------
__global__ __launch_bounds__(256) void sal_mfma(const unsigned short* __restrict__ Xh,
                                                const unsigned short* __restrict__ Xl,
                                                const float* __restrict__ Cf,
                                                float* __restrict__ sal)
{
    int b = blockIdx.x, i0 = blockIdx.y * 64;
    __shared__ __align__(16) unsigned short sAh[64*32], sAl[64*32], sBh[128*32], sBl[128*32];
    int tid = threadIdx.x;
    int lane = tid & 63, wcw = tid >> 6;
    int fr = lane & 15;
    int kc2 = ((((lane >> 4) + (fr >> 1)) & 3) * 8);

    const unsigned short* XhB = Xh + (size_t)b*T_*D_;
    const unsigned short* XlB = Xl + (size_t)b*T_*D_;
    const float* CfB = Cf + (size_t)b*T_*D_;

    f32x4 acc[4][2];
    #pragma unroll
    for (int m = 0; m < 4; m++) { acc[m][0] = (f32x4){0.f,0.f,0.f,0.f}; acc[m][1] = (f32x4){0.f,0.f,0.f,0.f}; }

    int ar = tid >> 2, ac = tid & 3;
    int aslot = (ac + (ar >> 1)) & 3;
    int brow = tid >> 1, bhh = tid & 1;
    int jrow = i0 - 64 + brow;

    // register staging state
    uint4 rAh, rAl;
    float4 rB0[2], rB1[2];

    auto LOAD = [&](int kk){
        rAh = *(const uint4*)(XhB + (size_t)(i0 + ar)*512 + kk + ac*8);
        rAl = *(const uint4*)(XlB + (size_t)(i0 + ar)*512 + kk + ac*8);
        #pragma unroll
        for (int cc = 0; cc < 2; cc++) {
            int c = 2*bhh + cc;
            if (jrow >= 0) {
                const float* src = CfB + (size_t)jrow*512 + kk + c*8;
                rB0[cc] = *(const float4*)src;
                rB1[cc] = *(const float4*)(src + 4);
            } else {
                rB0[cc] = make_float4(0.f,0.f,0.f,0.f);
                rB1[cc] = make_float4(0.f,0.f,0.f,0.f);
            }
        }
    };
    auto WRITE = [&](){
        *(uint4*)&sAh[ar*32 + aslot*8] = rAh;
        *(uint4*)&sAl[ar*32 + aslot*8] = rAl;
        #pragma unroll
        for (int cc = 0; cc < 2; cc++) {
            int c = 2*bhh + cc;
            int slot = (c + (brow >> 1)) & 3;
            uint4 hv, lv;
            float4 v0 = rB0[cc], v1 = rB1[cc];
            unsigned int h01 = pkbf(v0.x, v0.y), h23 = pkbf(v0.z, v0.w);
            unsigned int h45 = pkbf(v1.x, v1.y), h67 = pkbf(v1.z, v1.w);
            float r0 = v0.x - __uint_as_float(h01 << 16);
            float r1 = v0.y - __uint_as_float(h01 & 0xFFFF0000u);
            float r2 = v0.z - __uint_as_float(h23 << 16);
            float r3 = v0.w - __uint_as_float(h23 & 0xFFFF0000u);
            float r4 = v1.x - __uint_as_float(h45 << 16);
            float r5 = v1.y - __uint_as_float(h45 & 0xFFFF0000u);
            float r6 = v1.z - __uint_as_float(h67 << 16);
            float r7 = v1.w - __uint_as_float(h67 & 0xFFFF0000u);
            hv.x = h01; hv.y = h23; hv.z = h45; hv.w = h67;
            lv.x = pkbf(r0, r1); lv.y = pkbf(r2, r3); lv.z = pkbf(r4, r5); lv.w = pkbf(r6, r7);
            *(uint4*)&sBh[brow*32 + slot*8] = hv;
            *(uint4*)&sBl[brow*32 + slot*8] = lv;
        }
    };

    LOAD(0);
    for (int t = 0; t < 16; t++) {
        WRITE();                 // tile t into LDS
        __syncthreads();         // writes visible
        int kkn = (t+1)*32;
        bf16x8 ahf[4], alf[4], bhf[2], blf[2];
        #pragma unroll
        for (int m = 0; m < 4; m++) {
            int r = (m*16 + fr)*32 + kc2;
            ahf[m] = ld_bf8(&sAh[r]);
            alf[m] = ld_bf8(&sAl[r]);
        }
        #pragma unroll
        for (int n = 0; n < 2; n++) {
            int r = (wcw*32 + n*16 + fr)*32 + kc2;
            bhf[n] = ld_bf8(&sBh[r]);
            blf[n] = ld_bf8(&sBl[r]);
        }
        if (t < 15) LOAD(kkn);   // issue next-tile globals; land under MFMA
        #pragma unroll
        for (int m = 0; m < 4; m++)
            #pragma unroll
            for (int n = 0; n < 2; n++) {
                acc[m][n] = __builtin_amdgcn_mfma_f32_16x16x32_bf16(ahf[m], bhf[n], acc[m][n], 0, 0, 0);
                acc[m][n] = __builtin_amdgcn_mfma_f32_16x16x32_bf16(ahf[m], blf[n], acc[m][n], 0, 0, 0);
                acc[m][n] = __builtin_amdgcn_mfma_f32_16x16x32_bf16(alf[m], bhf[n], acc[m][n], 0, 0, 0);
            }
        __syncthreads();         // reads done before next WRITE
    }

    float* salB = sal + (size_t)b*T_*WIN_;
    #pragma unroll
    for (int m = 0; m < 4; m++) {
        #pragma unroll
        for (int n = 0; n < 2; n++) {
            int jl = wcw*32 + n*16 + fr;
            #pragma unroll
            for (int r = 0; r < 4; r++) {
                int il = m*16 + (lane >> 4)*4 + r;
                int o = il - jl + 64;
                if (o >= 1 && o <= 64) {
                    int jg = i0 - 64 + jl;
                    salB[(size_t)(i0 + il)*WIN_ + (o - 1)] = (jg >= 0) ? acc[m][n][r] : NEGV;
                }
            }
        }
    }
}

// ---------------- top-16 stage 1 (y<64) fused with w0q/phi-psi partials (y>=64) ------------
__global__ __launch_bounds__(256) void topk_stage1(const float* __restrict__ sal,
                                                   float* __restrict__ cv, int* __restrict__ ci,
                                                   const float* __restrict__ qpart,
                                                   const float* __restrict__ W0,
                                                   float* __restrict__ w0p)
{
    int b = blockIdx.x, tid = threadIdx.x;
    if (blockIdx.y >= 64) {
        // ---- w0q + phi/psi partials (qmean-final fused) ----
        int c = blockIdx.y - 64;
        __shared__ float qm[D_];
        for (int p = tid; p < D_; p += 256) {
            float s = 0.f;
            for (int cc = 0; cc < 32; cc++) s += qpart[((size_t)b*32 + cc)*D_ + p];
            qm[p] = s * (1.f/2048.f);
        }
        __syncthreads();
        int w = tid >> 6, lane = tid & 63;
        float ph = 0.f, ps = 0.f;
        for (int r = 0; r < 16; r++) {
            int d = c*64 + w*16 + r;
            const float* wr = W0 + (size_t)d*D_;
            float s = 0.f;
            #pragma unroll
            for (int q = 0; q < 8; q++) s += qm[lane + q*64] * wr[lane + q*64];
            #pragma unroll
            for (int off = 32; off; off >>= 1) s += __shfl_xor(s, off);
            float phi = (s - PSI_*qm[d]) * INV_DENOM_;
            float psi = (PHI_*qm[d] - s) * INV_DENOM_;
            ph += phi*phi; ps += psi*psi;
        }
        __shared__ float shp[4], shs[4];
        if (lane == 0) { shp[w] = ph; shs[w] = ps; }
        __syncthreads();
        if (tid == 0) {
            w0p[((size_t)b*8 + c)*2 + 0] = shp[0]+shp[1]+shp[2]+shp[3];
            w0p[((size_t)b*8 + c)*2 + 1] = shs[0]+shs[1]+shs[2]+shs[3];
        }
        return;
    }
    int c = blockIdx.y;
    const float* s = sal + (size_t)b*(T_*WIN_) + (size_t)c*2048;
    int base = c*2048;
    int lane = tid & 63, wvi = tid >> 6;
    float lv[8]; int li[8];
    #pragma unroll
    for (int k = 0; k < 8; k++) { lv[k] = NEGINF; li[k] = 0x7FFFFFFF; }
    #pragma unroll
    for (int r = 0; r < 8; r++) {
        int p = tid + r*256;
        float v = s[p];
        int idx = base + p;
        if (v > lv[7]) {
            int k = 7;
            while (k > 0 && lv[k-1] < v) { lv[k] = lv[k-1]; li[k] = li[k-1]; k--; }
            lv[k] = v; li[k] = idx;
        }
    }
    float* cvo = cv + (((size_t)b*64 + c)*64) + wvi*16;
    int*   cio = ci + (((size_t)b*64 + c)*64) + wvi*16;
    int head = 0;
    for (int r = 0; r < 16; r++) {
        float bv = (head < 8) ? lv[head] : NEGINF;
        int   bi = (head < 8) ? li[head] : 0x7FFFFFFF;
        float wv_ = bv; int wi = bi;
        #pragma unroll
        for (int off = 1; off < 64; off <<= 1) {
            float v2 = __shfl_xor(wv_, off);
            int   i2 = __shfl_xor(wi, off);
            if (v2 > wv_ || (v2 == wv_ && i2 < wi)) { wv_ = v2; wi = i2; }
        }
        if (bv == wv_ && bi == wi) head++;
        if (lane == 0) { cvo[r] = wv_; cio[r] = wi; }
    }
}

// ---------------- slot pipeline (per batch, 1024 thr): topk-merge + slot + loss partials --
__global__ __launch_bounds__(1024) void slot_kernel(
    const unsigned short* __restrict__ Xh, const unsigned short* __restrict__ Xl,
    const float* __restrict__ slots_in,
    const float* __restrict__ cv, const int* __restrict__ ci,
    const float* __restrict__ W_V, const float* __restrict__ W_K_slot, const float* __restrict__ skb,
    const float* __restrict__ Wg, const float* __restrict__ Wgb,
    const float* __restrict__ lnw, const float* __restrict__ lnb,
    const float* __restrict__ WsQ, const float* __restrict__ WsK, const float* __restrict__ WsV,
    const float* __restrict__ lambda_, const float* __restrict__ temps,
    float* __restrict__ snws, float* __restrict__ out_slots,
    float* __restrict__ lpP, float* __restrict__ lpD)
{
    int b = blockIdx.x, tid = threadIdx.x;
    int lane = tid & 63, wvi = tid >> 6;        // 16 waves
    __shared__ float alpha[16];
    __shared__ int   tis[16], tjs[16];
    __shared__ float tvv[16]; __shared__ int tii[16];
    __shared__ float scv[256]; __shared__ int sci[256];
    __shared__ float y[D_];
    __shared__ float part[8][DB_];
    __shared__ float pf[1024];
    __shared__ float Rt[DB_];
    __shared__ float sl[K_][DB_];
    __shared__ float upd[K_][DB_];
    __shared__ float Bn[K_][DB_];
    __shared__ float qq[K_][DB_], kk2[K_][DB_], vv[K_][DB_];
    __shared__ float snsh[K_][DB_];
    __shared__ float swv[K_], compat[K_], mu7[K_], rs7[K_], nr7[K_], ldv[K_];
    __shared__ float sa[K_][K_];

    for (int p = tid; p < K_*DB_; p += 1024) sl[p>>7][p&127] = slots_in[(size_t)b*K_*DB_ + p];

    {
        const float* cvb = cv + (size_t)b*4096;
        const int*   cib = ci + (size_t)b*4096;
        float lv[4]; int li[4];
        #pragma unroll
        for (int k = 0; k < 4; k++) { lv[k] = NEGINF; li[k] = 0x7FFFFFFF; }
        #pragma unroll
        for (int r = 0; r < 4; r++) {
            int p = tid + r*1024;
            float v = cvb[p];
            int idx = cib[p];
            if (v > lv[3] || (v == lv[3] && idx < li[3])) {
                int k = 3;
                while (k > 0 && (lv[k-1] < v || (lv[k-1] == v && li[k-1] > idx))) {
                    lv[k] = lv[k-1]; li[k] = li[k-1]; k--;
                }
                lv[k] = v; li[k] = idx;
            }
        }
        int head = 0;
        for (int r = 0; r < 16; r++) {
            float bv = (head < 4) ? lv[head] : NEGINF;
            int   bi = (head < 4) ? li[head] : 0x7FFFFFFF;
            float wv_ = bv; int wi = bi;
            #pragma unroll
            for (int off = 1; off < 64; off <<= 1) {
                float v2 = __shfl_xor(wv_, off);
                int   i2 = __shfl_xor(wi, off);
                if (v2 > wv_ || (v2 == wv_ && i2 < wi)) { wv_ = v2; wi = i2; }
            }
            if (bv == wv_ && bi == wi) head++;
            if (lane == 0) { scv[wvi*16 + r] = wv_; sci[wvi*16 + r] = wi; }
        }
        __syncthreads();
        if (wvi == 0) {
            float mv[4]; int mi[4];
            #pragma unroll
            for (int k = 0; k < 4; k++) { mv[k] = NEGINF; mi[k] = 0x7FFFFFFF; }
            #pragma unroll
            for (int r = 0; r < 4; r++) {
                int p = lane + r*64;
                float v = scv[p]; int idx = sci[p];
                if (v > mv[3] || (v == mv[3] && idx < mi[3])) {
                    int k = 3;
                    while (k > 0 && (mv[k-1] < v || (mv[k-1] == v && mi[k-1] > idx))) {
                        mv[k] = mv[k-1]; mi[k] = mi[k-1]; k--;
                    }
                    mv[k] = v; mi[k] = idx;
                }
            }
            int head2 = 0;
            for (int r = 0; r < 16; r++) {
                float bv = (head2 < 4) ? mv[head2] : NEGINF;
                int   bi = (head2 < 4) ? mi[head2] : 0x7FFFFFFF;
                float wv_ = bv; int wi = bi;
                #pragma unroll
                for (int off = 1; off < 64; off <<= 1) {
                    float v2 = __shfl_xor(wv_, off);
                    int   i2 = __shfl_xor(wi, off);
                    if (v2 > wv_ || (v2 == wv_ && i2 < wi)) { wv_ = v2; wi = i2; }
                }
                if (bv == wv_ && bi == wi) head2++;
                if (lane == 0) { tvv[r] = wv_; tii[r] = wi; }
            }
        }
        __syncthreads();
    }
    if (tid < 16) {
        float v = tvv[tid];
        int flat = tii[tid];
        tis[tid] = flat >> 6;
        tjs[tid] = (flat >> 6) - ((flat & 63) + 1);
        float m = v;
        #pragma unroll
        for (int off = 8; off; off >>= 1) m = fmaxf(m, __shfl_xor(m, off, 16));
        float e = expf(v - m);
        float s = e;
        #pragma unroll
        for (int off = 8; off; off >>= 1) s += __shfl_xor(s, off, 16);
        alpha[tid] = e / s;
    }
    __syncthreads();

    if (tid < D_) {
        float acc = 0.f;
        #pragma unroll
        for (int k = 0; k < 16; k++) {
            int i = tis[k], j = tjs[k];
            float xi = bf2f(Xh[((size_t)b*T_ + i)*D_ + tid]) + bf2f(Xl[((size_t)b*T_ + i)*D_ + tid]);
            float xj = bf2f(Xh[((size_t)b*T_ + j)*D_ + tid]) + bf2f(Xl[((size_t)b*T_ + j)*D_ + tid]);
            acc += alpha[k] * (xi - xj);
        }
        y[tid] = acc;
    }
    __syncthreads();

    {
        int g = tid >> 7, d = tid & 127;
        float acc = 0.f;
        int e0 = g * 64;
        for (int e = e0; e < e0 + 64; e++) acc += y[e] * W_V[(size_t)e*DB_ + d];
        part[g][d] = acc;
    }
    __syncthreads();
    if (tid < DB_) {
        float acc = 0.f;
        #pragma unroll
        for (int g = 0; g < 8; g++) acc += part[g][tid];
        Rt[tid] = acc;
    }
    __syncthreads();

    if (tid < K_*DB_) {
        int k = tid >> 7, d = tid & 127;
        float acc = skb[k*DB_ + d];
        for (int e = 0; e < DB_; e++) acc += sl[k][e] * W_K_slot[(size_t)e*DB_ + d];
        qq[k][d] = acc * Rt[d];
    }
    __syncthreads();
    if (wvi < K_) {
        float acc = qq[wvi][lane] + qq[wvi][lane + 64];
        #pragma unroll
        for (int off = 32; off; off >>= 1) acc += __shfl_xor(acc, off);
        if (lane == 0) compat[wvi] = acc * SCALE_ * softplusf(temps[wvi]);
    }
    __syncthreads();
    if (tid == 0) {
        float m = compat[0];
        for (int k = 1; k < K_; k++) m = fmaxf(m, compat[k]);
        float ssum = 0.f;
        for (int k = 0; k < K_; k++) { float e = expf(compat[k]-m); swv[k] = e; ssum += e; }
        for (int k = 0; k < K_; k++) swv[k] /= ssum;
    }
    __syncthreads();

    if (tid < K_*DB_) {
        int k = tid >> 7, d = tid & 127;
        float swk = swv[k];
        float acc = Wgb[d];
        for (int e = 0; e < DB_; e++) acc += sl[k][e] * Wg[(size_t)e*DB_ + d];
        for (int e = 0; e < DB_; e++) acc += swk * Rt[e] * Wg[(size_t)(DB_+e)*DB_ + d];
        float g = 1.f / (1.f + expf(-acc));
        upd[k][d] = (1.f - g) * sl[k][d] + g * (swk * Rt[d]);
    }
    __syncthreads();

    if (wvi < K_) {
        float v0 = upd[wvi][lane], v1 = upd[wvi][lane + 64];
        float s = v0 + v1, ss = v0*v0 + v1*v1;
        #pragma unroll
        for (int off = 32; off; off >>= 1) { s += __shfl_xor(s, off); ss += __shfl_xor(ss, off); }
        if (lane == 0) {
            float mu = s / (float)DB_;
            mu7[wvi] = mu;
            rs7[wvi] = rsqrtf(ss/(float)DB_ - mu*mu + 1e-5f);
        }
    }
    __syncthreads();
    if (tid < K_*DB_) {
        int k = tid >> 7, d = tid & 127;
        Bn[k][d] = (upd[k][d] - mu7[k]) * rs7[k] * lnw[d] + lnb[d];
    }
    __syncthreads();

    if (tid < K_*DB_) {
        int k = tid >> 7, d = tid & 127;
        float aq = 0.f, ak = 0.f, av = 0.f;
        for (int e = 0; e < DB_; e++) {
            float bn = Bn[k][e];
            aq += bn * WsQ[(size_t)e*DB_ + d];
            ak += bn * WsK[(size_t)e*DB_ + d];
            av += bn * WsV[(size_t)e*DB_ + d];
        }
        qq[k][d] = aq; kk2[k][d] = ak; vv[k][d] = av;
    }
    __syncthreads();

    if (wvi < K_) {
        int j = lane >> 3, s = lane & 7;
        float acc = 0.f;
        if (j < K_) {
            int e0 = s * 16;
            for (int e = e0; e < e0 + 16; e++) acc += qq[wvi][e] * kk2[j][e];
        }
        #pragma unroll
        for (int off = 4; off; off >>= 1) acc += __shfl_xor(acc, off, 8);
        if (s == 0 && j < K_) sa[wvi][j] = acc * SCALE_;
    }
    __syncthreads();
    if (tid < K_) {
        float m = sa[tid][0];
        for (int j = 1; j < K_; j++) m = fmaxf(m, sa[tid][j]);
        float ssum = 0.f;
        for (int j = 0; j < K_; j++) { float e = expf(sa[tid][j]-m); sa[tid][j] = e; ssum += e; }
        for (int j = 0; j < K_; j++) sa[tid][j] /= ssum;
    }
    __syncthreads();

    if (tid < K_*DB_) {
        int k = tid >> 7, d = tid & 127;
        float lam = tanhf(lambda_[d]);
        lam = fminf(fmaxf(lam, -0.5f), 0.5f);
        float c = 0.f;
        #pragma unroll
        for (int j = 0; j < K_; j++) c += sa[k][j] * vv[j][d];
        float sn = upd[k][d] + c * lam;
        snsh[k][d] = sn;
        snws[((size_t)b*K_ + k)*DB_ + d] = sn;
        out_slots[((size_t)b*K_ + k)*DB_ + d] = sn;
    }
    __syncthreads();

    {
        float dsq = 0.f;
        if (tid < K_*DB_) {
            int k = tid >> 7, d = tid & 127;
            float dd = snsh[k][d] - sl[k][d];
            dsq = dd*dd;
        }
        pf[tid] = dsq;
        if (wvi < K_) {
            float v0 = snsh[wvi][lane], v1 = snsh[wvi][lane + 64];
            float ss = v0*v0 + v1*v1;
            #pragma unroll
            for (int off = 32; off; off >>= 1) ss += __shfl_xor(ss, off);
            if (lane == 0) nr7[wvi] = fmaxf(sqrtf(ss), 1e-12f);
        }
        __syncthreads();
        if (wvi == 0) {
            float s = 0.f;
            #pragma unroll
            for (int q = 0; q < 16; q++) s += pf[lane + q*64];
            #pragma unroll
            for (int off = 32; off; off >>= 1) s += __shfl_xor(s, off);
            if (lane == 0) lpP[b] = s;
        }
        if (wvi >= 1 && wvi <= K_) {
            int q = wvi - 1;
            float accq = 0.f;
            for (int j = 0; j < K_; j++) {
                if (j == q) continue;
                float dt = snsh[q][lane]*snsh[j][lane] + snsh[q][lane+64]*snsh[j][lane+64];
                #pragma unroll
                for (int off = 32; off; off >>= 1) dt += __shfl_xor(dt, off);
                float cs = dt / (nr7[q] * nr7[j]);
                accq += cs*cs;
            }
            if (lane == 0) ldv[q] = accq;
        }
        __syncthreads();
        if (tid == 0) {
            float s = 0.f;
            for (int q = 0; q < K_; q++) s += ldv[q];
            lpD[b] = s;
        }
    }
}

// ---------------- kq & vg (+basis inline, +loss finalize): grid (B, K) ----------------
__global__ __launch_bounds__(256) void kqvg_kernel(
    const float* __restrict__ sn, const float* __restrict__ WKr,
    const float* __restrict__ WQr, const float* __restrict__ WVr,
    const float* __restrict__ rc, const float* __restrict__ w0p,
    const float* __restrict__ lpP, const float* __restrict__ lpD,
    float* __restrict__ kq, float* __restrict__ vg, float* __restrict__ loss_out)
{
    int b = blockIdx.x, k = blockIdx.y, tid = threadIdx.x;
    if (b == 0 && k == 0 && tid == 0) {
        float s = 0.f, s2 = 0.f;
        for (int bb = 0; bb < B_; bb++) { s += lpP[bb]; s2 += lpD[bb]; }
        loss_out[0] = s / (float)(B_*K_*DB_);
        loss_out[1] = s2 / (float)(B_*(K_*K_-K_));
    }
    float P = 0.f, Q = 0.f;
    #pragma unroll
    for (int c = 0; c < 8; c++) {
        P += w0p[((size_t)b*8 + c)*2 + 0];
        Q += w0p[((size_t)b*8 + c)*2 + 1];
    }
    float pm = sqrtf(P), qm2 = sqrtf(Q);
    float tot = pm + qm2 + 1e-6f;
    float b1 = pm / tot, b2 = qm2 / tot;

    __shared__ float sl[DB_], kr[DB_];
    if (tid < DB_) sl[tid] = sn[((size_t)b*K_ + k)*DB_ + tid];
    __syncthreads();
    if (tid < DB_) {
        float a = 0.f;
        for (int e = 0; e < DB_; e++) a += sl[e] * WKr[(size_t)e*DB_ + tid];
        kr[tid] = a;
    }
    __syncthreads();
    #pragma unroll
    for (int rep = 0; rep < 2; rep++) {
        int e = tid + rep*256;
        float a = 0.f;
        const float* wq = WQr + (size_t)e*DB_;
        for (int d = 0; d < DB_; d++) a += kr[d] * wq[d];
        kq[((size_t)b*K_ + k)*D_ + e] = a;
    }
    #pragma unroll
    for (int rep = 0; rep < 2; rep++) {
        int dd = tid + rep*256;
        float a = 0.f;
        for (int e = 0; e < DB_; e++) a += sl[e] * WVr[(size_t)e*D_ + dd];
        float gpre = rc[((size_t)k*3 + 0)*D_ + dd] + b1*rc[((size_t)k*3 + 1)*D_ + dd] + b2*rc[((size_t)k*3 + 2)*D_ + dd];
        float g = tanhf(gpre);
        g = fminf(fmaxf(g, -0.5f), 0.5f);
        vg[((size_t)b*K_ + k)*D_ + dd] = a * g;
    }
}

// ---------------- z: softmax over 7 slots + weighted combine ----------------
__global__ __launch_bounds__(256) void z_kernel(const float* __restrict__ Xr,
                                                const float* __restrict__ kq,
                                                const float* __restrict__ vg,
                                                float* __restrict__ z)
{
    int b = blockIdx.x;
    int t0 = blockIdx.y * 64;
    __shared__ float kqs[K_][D_];
    __shared__ float vgs[K_][D_];
    int tid = threadIdx.x;
    for (int p = tid; p < K_*D_; p += 256) {
        kqs[p>>9][p&511] = kq[(size_t)b*K_*D_ + p];
        vgs[p>>9][p&511] = vg[(size_t)b*K_*D_ + p];
    }
    __syncthreads();
    int lane = tid & 63, w = tid >> 6;
    for (int it = 0; it < 16; it++) {
        int t = t0 + w*16 + it;
        const float* x = Xr + ((size_t)b*T_ + t)*D_;
        float xr[8];
        float s[K_] = {0,0,0,0,0,0,0};
        #pragma unroll
        for (int r = 0; r < 8; r++) {
            int e = lane + r*64;
            xr[r] = x[e];
            #pragma unroll
            for (int k = 0; k < K_; k++) s[k] += xr[r] * kqs[k][e];
        }
        #pragma unroll
        for (int k = 0; k < K_; k++)
            for (int off = 32; off; off >>= 1) s[k] += __shfl_xor(s[k], off);
        float sc[K_];
        float m = NEGINF;
        #pragma unroll
        for (int k = 0; k < K_; k++) { sc[k] = s[k] * SCALE_; m = fmaxf(m, sc[k]); }
        float p[K_], ssum = 0.f;
        #pragma unroll
        for (int k = 0; k < K_; k++) { p[k] = expf(sc[k] - m); ssum += p[k]; }
        float inv = 1.f / ssum;
        float* zp = z + ((size_t)b*T_ + t)*D_;
        #pragma unroll
        for (int r = 0; r < 8; r++) {
            int e = lane + r*64;
            float a = 0.f;
            #pragma unroll
            for (int k = 0; k < K_; k++) a += p[k] * vgs[k][e];
            zp[e] = a * inv;
        }
    }
}

extern "C" void kernel_launch(void* const* d_in, const int* in_sizes, int n_in,
                              void* d_out, int out_size, void* d_ws, size_t ws_size,
                              hipStream_t stream)
{
    const float* X_write = (const float*)d_in[0];
    const float* X_read  = (const float*)d_in[1];
    const float* slots   = (const float*)d_in[2];
    const float* W0      = (const float*)d_in[3];
    const float* lnw_w   = (const float*)d_in[4];
    const float* lnw_b   = (const float*)d_in[5];
    const float* W_V     = (const float*)d_in[6];
    const float* W_K_slot= (const float*)d_in[7];
    const float* skb     = (const float*)d_in[8];
    const float* Wg      = (const float*)d_in[9];
    const float* Wgb     = (const float*)d_in[10];
    const float* lns_w   = (const float*)d_in[11];
    const float* lns_b   = (const float*)d_in[12];
    const float* WsQ     = (const float*)d_in[13];
    const float* WsK     = (const float*)d_in[14];
    const float* WsV     = (const float*)d_in[15];
    const float* lambda_ = (const float*)d_in[16];
    const float* WQr     = (const float*)d_in[17];
    const float* WKr     = (const float*)d_in[18];
    const float* WVr     = (const float*)d_in[19];
    const float* rc      = (const float*)d_in[20];
    const float* temps   = (const float*)d_in[21];

    const size_t NXD = (size_t)B_*T_*D_;           // 16777216
    unsigned short* Xh  = (unsigned short*)d_ws;
    unsigned short* Xl  = Xh + NXD;
    float* Cf           = (float*)(Xl + NXD);      // f32 XW0, 64MB
    unsigned short* W0h = (unsigned short*)(Cf + NXD);
    unsigned short* W0l = W0h + (size_t)D_*D_;
    float* fscr  = (float*)(W0l + (size_t)D_*D_);
    float* qpart = fscr;                           // B*32*D = 262144
    float* w0p   = qpart + (size_t)B_*32*D_;       // 256
    float* snws  = w0p + 256;                      // 14336
    float* kq    = snws + (size_t)B_*K_*DB_;       // 57344
    float* vg    = kq + (size_t)B_*K_*D_;          // 57344
    float* cv    = vg + (size_t)B_*K_*D_;          // B*64*64 = 65536
    int*   ci    = (int*)(cv + (size_t)B_*64*64);  // 65536
    float* lpP   = (float*)(ci + (size_t)B_*64*64);// 16
    float* lpD   = lpP + 16;                       // 16

    float* z_out     = (float*)d_out;
    float* slots_out = z_out + NXD;
    float* loss_out  = slots_out + (size_t)B_*K_*DB_;
    float* sal       = z_out;    // scratch inside z region; consumed before z_kernel writes

    prep_kernel<<<dim3(4096 + 256 + 512), dim3(256), 0, stream>>>(
        X_write, lnw_w, lnw_b, Xh, Xl, W0, W0h, W0l, X_read, qpart);
    gemm_xw0_mfma<<<dim3(B_*T_/128, D_/128), dim3(256), 0, stream>>>(Xh, Xl, W0h, W0l, Cf);
    sal_mfma<<<dim3(B_, T_/64), dim3(256), 0, stream>>>(Xh, Xl, Cf, sal);
    topk_stage1<<<dim3(B_, 72), dim3(256), 0, stream>>>(sal, cv, ci, qpart, W0, w0p);
    slot_kernel<<<dim3(B_), dim3(1024), 0, stream>>>(Xh, Xl, slots, cv, ci,
        W_V, W_K_slot, skb, Wg, Wgb, lns_w, lns_b, WsQ, WsK, WsV, lambda_, temps,
        snws, slots_out, lpP, lpD);
    kqvg_kernel<<<dim3(B_, K_), dim3(256), 0, stream>>>(snws, WKr, WQr, WVr, rc, w0p,
        lpP, lpD, kq, vg, loss_out);
    z_kernel<<<dim3(B_, T_/64), dim3(256), 0, stream>>>(X_read, kq, vg, z_out);
}